// Round 2
// baseline (2606.057 us; speedup 1.0000x reference)
//
#include <hip/hip_runtime.h>
#include <hip/hip_bf16.h>

// Problem constants
#define B_  2
#define L_  512
#define D_  768
#define H_  12
#define E_  32
#define M_  4
#define P_  256
#define EMB_ 768
#define BS_ 64
#define C_  97
#define N_  (B_*P_)   // 512

typedef __hip_bfloat16 bf16;

// Runtime-flagged load of a "float input tensor": isbf=1 -> bf16, 0 -> float32
__device__ inline float ldIn(const void* p, long idx, int isbf) {
    return isbf ? (float)((const bf16*)p)[idx] : ((const float*)p)[idx];
}

// ---------------- K0: dtype detection ----------------
// If the float inputs are f32 read as bf16, low halfwords have random exponent
// bits -> ~45% of values have exponent >= 140. True bf16 N(0,1): none.
__global__ void dtype_detect(const void* __restrict__ seq, int* __restrict__ flag) {
    __shared__ int cnt;
    if (threadIdx.x == 0) cnt = 0;
    __syncthreads();
    const unsigned short* u = (const unsigned short*)seq;
    int bad = 0;
    for (int i = threadIdx.x; i < 1024; i += 256) {
        unsigned short e = (u[i] >> 7) & 0xFF;
        if (e >= 140) bad++;
    }
    atomicAdd(&cnt, bad);
    __syncthreads();
    if (threadIdx.x == 0) flag[0] = (cnt < 16) ? 1 : 0;   // 1 = bf16 inputs
}

// ---------------- K1: ment_emb gather + ent_emb logsumexp over M ----------------
__global__ void ment_kernel(const void* __restrict__ seq, const int* __restrict__ entity_pos,
                            float* __restrict__ ment_emb, float* __restrict__ ent_emb,
                            const int* __restrict__ dtf) {
    int isbf = dtf[0];
    int be = blockIdx.x;            // b*E+e, 64 blocks
    int b = be >> 5;
    int pos[M_];
    for (int m = 0; m < M_; m++) pos[m] = entity_pos[be*M_+m] + 1;
    for (int d = threadIdx.x; d < D_; d += 256) {
        float x[M_];
        for (int m = 0; m < M_; m++) {
            x[m] = ldIn(seq, ((long)b*L_ + pos[m])*D_ + d, isbf);
            ment_emb[((long)be*M_ + m)*D_ + d] = x[m];
        }
        float mx = fmaxf(fmaxf(x[0],x[1]), fmaxf(x[2],x[3]));
        float s = expf(x[0]-mx)+expf(x[1]-mx)+expf(x[2]-mx)+expf(x[3]-mx);
        ent_emb[(long)be*D_ + d] = mx + logf(s);
    }
}

// ---------------- K2: ent_att = mean over M of gathered attn ----------------
__global__ void entatt_kernel(const void* __restrict__ attn, const int* __restrict__ entity_pos,
                              float* __restrict__ ent_att, const int* __restrict__ dtf) {
    int isbf = dtf[0];
    int beh = blockIdx.x;           // (b*E+e)*H+h, 768 blocks
    int h = beh % H_;
    int be = beh / H_;
    int b = be >> 5;
    int pos[M_];
    for (int m = 0; m < M_; m++) pos[m] = entity_pos[be*M_+m] + 1;
    for (int l = threadIdx.x; l < L_; l += 256) {
        float s = 0.f;
        for (int m = 0; m < M_; m++)
            s += ldIn(attn, (((long)(b*H_ + h))*L_ + pos[m])*L_ + l, isbf);
        ent_att[(long)beh*L_ + l] = 0.25f * s;
    }
}

// ---------------- K3: ht_att = normalize_L( mean_H(ha*ta) ) ----------------
__global__ void htatt_kernel(const float* __restrict__ ent_att, const int* __restrict__ hts,
                             float* __restrict__ ht_att) {
    int bp = blockIdx.x;            // 512 blocks
    int b = bp >> 8;
    int h_e = hts[bp*2+0], t_e = hts[bp*2+1];
    const float* ea_h = ent_att + (long)((b*E_ + h_e)*H_)*L_;
    const float* ea_t = ent_att + (long)((b*E_ + t_e)*H_)*L_;
    __shared__ float red[256];
    float v[2];
    for (int t = 0; t < 2; t++) {
        int l = threadIdx.x + t*256;
        float s = 0.f;
        for (int h = 0; h < H_; h++) s += ea_h[h*L_+l] * ea_t[h*L_+l];
        v[t] = s * (1.0f/H_);
    }
    red[threadIdx.x] = v[0] + v[1];
    __syncthreads();
    for (int off = 128; off > 0; off >>= 1) {
        if (threadIdx.x < off) red[threadIdx.x] += red[threadIdx.x+off];
        __syncthreads();
    }
    float inv = 1.0f / (red[0] + 1e-5f);
    for (int t = 0; t < 2; t++) {
        int l = threadIdx.x + t*256;
        ht_att[(long)bp*L_ + l] = v[t] * inv;
    }
}

// ---------------- K4: rs[b,p,d] = sum_l seq[b,l,d]*ht_att[b,p,l] ----------------
__global__ void rs_kernel(const void* __restrict__ seq, const float* __restrict__ ht_att,
                          float* __restrict__ rs, const int* __restrict__ dtf) {
    int isbf = dtf[0];
    int blk = blockIdx.x;           // 128 blocks: 4 p's each
    int b = blk / 64;
    int p0 = (blk % 64) * 4;
    __shared__ float ht[4][L_];
    for (int t = threadIdx.x; t < 4*L_; t += 256) {
        int pp = t >> 9, l = t & 511;
        ht[pp][l] = ht_att[((long)(b*P_ + p0 + pp))*L_ + l];
    }
    __syncthreads();
    for (int it = 0; it < 3; it++) {
        int d = it*256 + threadIdx.x;
        float acc[4] = {0.f,0.f,0.f,0.f};
        for (int l = 0; l < L_; l++) {
            float s = ldIn(seq, ((long)b*L_ + l)*D_ + d, isbf);
            for (int pp = 0; pp < 4; pp++) acc[pp] += s * ht[pp][l];
        }
        for (int pp = 0; pp < 4; pp++)
            rs[((long)(b*P_ + p0 + pp))*D_ + d] = acc[pp];
    }
}

// ---------------- K5: hcat=[hs,rs], tcat=[ts,rs] ----------------
__global__ void cat_kernel(const float* __restrict__ ent_emb, const float* __restrict__ rs,
                           const int* __restrict__ hts,
                           float* __restrict__ hcat, float* __restrict__ tcat) {
    int n = blockIdx.x;             // 512
    int b = n >> 8;
    int h_e = hts[n*2+0], t_e = hts[n*2+1];
    const float* eh = ent_emb + (long)(b*E_ + h_e)*D_;
    const float* et = ent_emb + (long)(b*E_ + t_e)*D_;
    const float* r  = rs + (long)n*D_;
    for (int k = threadIdx.x; k < D_; k += 256) {
        hcat[(long)n*1536 + k]       = eh[k];
        hcat[(long)n*1536 + 768 + k] = r[k];
        tcat[(long)n*1536 + k]       = et[k];
        tcat[(long)n*1536 + 768 + k] = r[k];
    }
}

// ---------------- Generic tiled GEMM: C = act(A@B + bias), up to 4 problems via z ----------------
// a_in/b_in: 1 if the matrix is a float INPUT tensor (dtype per runtime flag), 0 if ws f32.
// c_out: 1 -> write to d_out with flagged dtype; 0 -> write f32 ws.
struct GemmArgs {
    const void* A[4];
    const void* Bm[4];
    const void* bias[4];
    void* Cc[4];
};

__global__ void gemm_generic(GemmArgs args, int lda, int a_in, int ldb, int b_in,
                             int ldc, int M, int N, int K, int act, int c_out,
                             const int* __restrict__ dtf) {
    int isbf = dtf[0];
    int af = a_in ? isbf : 0;
    int bfm = b_in ? isbf : 0;
    const void* A  = args.A[blockIdx.z];
    const void* Bm = args.Bm[blockIdx.z];
    const void* bias = args.bias[blockIdx.z];
    void* Cc = args.Cc[blockIdx.z];

    __shared__ float As[16][65];
    __shared__ float Bs[16][65];
    int m0 = blockIdx.x * 64, n0 = blockIdx.y * 64;
    int tx = threadIdx.x, ty = threadIdx.y;   // 16x16
    int tid = ty*16 + tx;
    float acc[4][4] = {};
    for (int k0 = 0; k0 < K; k0 += 16) {
        for (int t = 0; t < 4; t++) {
            int idx = tid + t*256;
            int rA = idx >> 4, kA = idx & 15;
            int m = m0 + rA, ka = k0 + kA;
            As[kA][rA] = (m < M && ka < K) ? ldIn(A, (long)m*lda + ka, af) : 0.f;
            int rB = idx & 63, kB = idx >> 6;
            int n = n0 + rB, kb = k0 + kB;
            Bs[kB][rB] = (kb < K && n < N) ? ldIn(Bm, (long)kb*ldb + n, bfm) : 0.f;
        }
        __syncthreads();
        for (int kk = 0; kk < 16; kk++) {
            float a[4], b[4];
            for (int i = 0; i < 4; i++) a[i] = As[kk][ty + 16*i];
            for (int j = 0; j < 4; j++) b[j] = Bs[kk][tx + 16*j];
            for (int i = 0; i < 4; i++)
                for (int j = 0; j < 4; j++) acc[i][j] += a[i]*b[j];
        }
        __syncthreads();
    }
    for (int i = 0; i < 4; i++) {
        int m = m0 + ty + 16*i;
        if (m >= M) continue;
        for (int j = 0; j < 4; j++) {
            int n = n0 + tx + 16*j;
            if (n >= N) continue;
            float v = acc[i][j];
            if (bias) v += ldIn(bias, n, isbf);
            if (act == 1) v = tanhf(v);
            if (c_out) {
                if (isbf) ((bf16*)Cc)[(long)m*ldc + n] = (bf16)v;
                else      ((float*)Cc)[(long)m*ldc + n] = v;
            } else {
                ((float*)Cc)[(long)m*ldc + n] = v;
            }
        }
    }
}

// ---------------- r1 init: r123[:,0:97] = b_rel ----------------
__global__ void r1init_kernel(const void* __restrict__ b_rel, float* __restrict__ r123,
                              const int* __restrict__ dtf) {
    int isbf = dtf[0];
    int idx = blockIdx.x*256 + threadIdx.x;
    if (idx < N_*C_) {
        int nn = idx / C_, c = idx % C_;
        r123[(long)nn*(3*C_) + c] = ldIn(b_rel, c, isbf);
    }
}

// ---------------- r1: bl @ W_rel accumulated via atomics ----------------
// grid: (8 n-tiles, 12 k-blocks, 4 i-chunks); block 256
__global__ void r1_kernel(const float* __restrict__ hz, const float* __restrict__ tz,
                          const void* __restrict__ W_rel, float* __restrict__ r123,
                          const int* __restrict__ dtf) {
    int isbf = dtf[0];
    int n0 = blockIdx.x * 64;
    int kb = blockIdx.y;
    int i0 = blockIdx.z * 16;
    __shared__ float hzL[16][64];
    __shared__ float tzL[64][64];
    int tid = threadIdx.x;
    for (int t = tid; t < 16*64; t += 256) {
        int ii = t >> 6, n = t & 63;
        hzL[ii][n] = hz[(long)(n0+n)*EMB_ + kb*64 + i0 + ii];
    }
    for (int t = tid; t < 64*64; t += 256) {
        int j = t >> 6, n = t & 63;
        tzL[j][n] = tz[(long)(n0+n)*EMB_ + kb*64 + j];
    }
    __syncthreads();
    int n  = tid & 63;
    int cg = tid >> 6;   // 0..3, uniform per wave
    float acc[25];
    for (int u = 0; u < 25; u++) acc[u] = 0.f;
    for (int ii = 0; ii < 16; ii++) {
        float hv = hzL[ii][n];
        long rowbase = (long)((kb*64 + i0 + ii)*64) * C_;
        for (int j = 0; j < 64; j++) {
            float s = hv * tzL[j][n];
            long wb = rowbase + (long)j*C_ + cg;
            #pragma unroll
            for (int u = 0; u < 25; u++) {
                int c = cg + 4*u;
                if (c < C_) acc[u] += s * ldIn(W_rel, wb + 4*u, isbf);
            }
        }
    }
    for (int u = 0; u < 25; u++) {
        int c = cg + 4*u;
        if (c < C_) atomicAdd(&r123[(long)(n0+n)*(3*C_) + c], acc[u]);
    }
}

// ---------------- c2/c3 constants: b_f @ W + b ----------------
__global__ void c23_kernel(const void* __restrict__ b_f,
                           const void* __restrict__ W_unet, const void* __restrict__ b_unet,
                           const void* __restrict__ W_mlp,  const void* __restrict__ b_mlp,
                           float* __restrict__ c23, const int* __restrict__ dtf) {
    int isbf = dtf[0];
    int c = threadIdx.x;
    if (c >= C_) return;
    float s2 = 0.f, s3 = 0.f;
    for (int d = 0; d < D_; d++) {
        float bf = ldIn(b_f, d, isbf);
        s2 += bf * ldIn(W_unet, (long)d*C_ + c, isbf);
        s3 += bf * ldIn(W_mlp,  (long)d*C_ + c, isbf);
    }
    c23[c]      = s2 + ldIn(b_unet, c, isbf);
    c23[C_ + c] = s3 + ldIn(b_mlp,  c, isbf);
}

// ---------------- r2/r3: logsumexp over 16 (i,j) of tanh/gelu ----------------
__global__ void r23_kernel(const float* __restrict__ mu, const float* __restrict__ c23,
                           const int* __restrict__ hts, const int* __restrict__ mention_idx,
                           float* __restrict__ r123) {
    int bp = blockIdx.x;            // 512
    int b = bp >> 8;
    int c = threadIdx.x;
    if (c >= C_) return;
    int h_e = hts[bp*2+0], t_e = hts[bp*2+1];
    const float* mu2h = mu;
    const float* mu2t = mu + 24832;
    const float* mu3h = mu + 49664;
    const float* mu3t = mu + 74496;
    float ah2[4], at2[4], ah3[4], at3[4];
    for (int m = 0; m < 4; m++) {
        int emh = mention_idx[(b*E_ + h_e)*M_ + m];
        int emt = mention_idx[(b*E_ + t_e)*M_ + m];
        ah2[m] = mu2h[(long)(b*128 + emh)*C_ + c];
        ah3[m] = mu3h[(long)(b*128 + emh)*C_ + c];
        at2[m] = mu2t[(long)(b*128 + emt)*C_ + c];
        at3[m] = mu3t[(long)(b*128 + emt)*C_ + c];
    }
    float c2 = c23[c], c3 = c23[C_ + c];
    float v2[16], v3[16];
    int q = 0;
    for (int i = 0; i < 4; i++) {
        for (int j = 0; j < 4; j++, q++) {
            float x2 = ah2[i] + at2[j] + c2;
            v2[q] = tanhf(x2);
            float x3 = ah3[i] + at3[j] + c3;
            float t = tanhf(0.7978845608028654f * (x3 + 0.044715f*x3*x3*x3));
            v3[q] = 0.5f * x3 * (1.0f + t);
        }
    }
    float m2 = v2[0], m3 = v3[0];
    for (q = 1; q < 16; q++) { m2 = fmaxf(m2, v2[q]); m3 = fmaxf(m3, v3[q]); }
    float s2 = 0.f, s3 = 0.f;
    for (q = 0; q < 16; q++) { s2 += expf(v2[q]-m2); s3 += expf(v3[q]-m3); }
    r123[(long)bp*(3*C_) + C_   + c] = m2 + logf(s2);
    r123[(long)bp*(3*C_) + 2*C_ + c] = m3 + logf(s3);
}

extern "C" void kernel_launch(void* const* d_in, const int* in_sizes, int n_in,
                              void* d_out, int out_size, void* d_ws, size_t ws_size,
                              hipStream_t stream) {
    const void* seq        = d_in[0];
    const void* attn       = d_in[1];
    const int*  entity_pos = (const int*)d_in[2];
    const int*  hts        = (const int*)d_in[3];
    const int*  mention_idx= (const int*)d_in[4];
    const void* W_head     = d_in[5];
    const void* b_head     = d_in[6];
    const void* W_tail     = d_in[7];
    const void* b_tail     = d_in[8];
    const void* W_rel      = d_in[9];
    const void* b_rel      = d_in[10];
    const void* W_fh       = d_in[11];
    const void* W_ft       = d_in[12];
    const void* b_f        = d_in[13];
    const void* W_unet     = d_in[14];
    const void* b_unet     = d_in[15];
    const void* W_mlp      = d_in[16];
    const void* b_mlp      = d_in[17];
    const void* W_bil      = d_in[18];
    const void* b_bil      = d_in[19];

    float* w = (float*)d_ws;
    int*   dtf      = (int*)w;          // 64 floats reserved
    float* ment_emb = w + 64;           // 196608
    float* ent_emb  = w + 196672;       // 49152
    float* ent_att  = w + 245824;       // 393216
    float* ht_att   = w + 639040;       // 262144
    float* rs       = w + 901184;       // 393216
    float* hcat     = w + 1294400;      // 786432
    float* tcat     = w + 2080832;      // 786432
    float* hz       = w + 2867264;      // 393216
    float* tz       = w + 3260480;      // 393216
    float* r123     = w + 3653696;      // 148992
    float* mu       = w + 3802688;      // 99328   (4 x 24832)
    float* Ffold    = w + 3902016;      // 297984  (4 x 74496)
    float* c23      = w + 4200000;      // 194

    // 0. dtype detection (bf16 vs f32 float tensors)
    dtype_detect<<<1, 256, 0, stream>>>(seq, dtf);
    // 1. mentions + entity embeddings
    ment_kernel<<<B_*E_, 256, 0, stream>>>(seq, entity_pos, ment_emb, ent_emb, dtf);
    // 2. entity attention
    entatt_kernel<<<B_*E_*H_, 256, 0, stream>>>(attn, entity_pos, ent_att, dtf);
    // 3. ht attention (normalized)
    htatt_kernel<<<N_, 256, 0, stream>>>(ent_att, hts, ht_att);
    // 4. rs
    rs_kernel<<<128, 256, 0, stream>>>(seq, ht_att, rs, dtf);
    // 5. concatenated inputs
    cat_kernel<<<N_, 256, 0, stream>>>(ent_emb, rs, hts, hcat, tcat);

    // 6. hz/tz GEMMs (fused in z)
    {
        GemmArgs ga = {};
        ga.A[0] = hcat;  ga.Bm[0] = W_head; ga.bias[0] = b_head; ga.Cc[0] = hz;
        ga.A[1] = tcat;  ga.Bm[1] = W_tail; ga.bias[1] = b_tail; ga.Cc[1] = tz;
        gemm_generic<<<dim3(8,12,2), dim3(16,16), 0, stream>>>(ga, 1536, 0, 768, 1, 768, N_, 768, 1536, 1, 0, dtf);
    }
    // 7. folded weights F_q = W_f{h,t} @ W_{unet,mlp}  (768x97 each)
    {
        GemmArgs ga = {};
        const void* As[4] = {W_fh, W_ft, W_fh, W_ft};
        const void* Bs[4] = {W_unet, W_unet, W_mlp, W_mlp};
        for (int q = 0; q < 4; q++) {
            ga.A[q] = As[q]; ga.Bm[q] = Bs[q]; ga.bias[q] = nullptr;
            ga.Cc[q] = Ffold + q*74496;
        }
        gemm_generic<<<dim3(12,2,4), dim3(16,16), 0, stream>>>(ga, 768, 1, 97, 1, 97, 768, C_, 768, 0, 0, dtf);
    }
    // 8. mu_q = ment_flat @ F_q   (256x97 each)
    {
        GemmArgs ga = {};
        for (int q = 0; q < 4; q++) {
            ga.A[q] = ment_emb; ga.Bm[q] = Ffold + q*74496; ga.bias[q] = nullptr;
            ga.Cc[q] = mu + q*24832;
        }
        gemm_generic<<<dim3(4,2,4), dim3(16,16), 0, stream>>>(ga, 768, 0, 97, 0, 97, 256, C_, 768, 0, 0, dtf);
    }
    // 9. c2/c3 constants
    c23_kernel<<<1, 128, 0, stream>>>(b_f, W_unet, b_unet, W_mlp, b_mlp, c23, dtf);
    // 10. r1 init with bias
    r1init_kernel<<<(N_*C_ + 255)/256, 256, 0, stream>>>(b_rel, r123, dtf);
    // 11. r1 accumulate
    r1_kernel<<<dim3(8,12,4), 256, 0, stream>>>(hz, tz, W_rel, r123, dtf);
    // 12. r2/r3
    r23_kernel<<<N_, 128, 0, stream>>>(mu, c23, hts, mention_idx, r123);
    // 13. final: out = r123 @ W_bil + b_bil  (dtype per flag)
    {
        GemmArgs ga = {};
        ga.A[0] = r123; ga.Bm[0] = W_bil; ga.bias[0] = b_bil; ga.Cc[0] = d_out;
        gemm_generic<<<dim3(8,2,1), dim3(16,16), 0, stream>>>(ga, 3*C_, 0, 97, 1, 97, N_, C_, 3*C_, 0, 1, dtf);
    }
}

// Round 3
// 1260.654 us; speedup vs baseline: 2.0672x; 2.0672x over previous
//
#include <hip/hip_runtime.h>
#include <hip/hip_bf16.h>

// Problem constants
#define B_  2
#define L_  512
#define D_  768
#define H_  12
#define E_  32
#define M_  4
#define P_  256
#define EMB_ 768
#define BS_ 64
#define C_  97
#define N_  (B_*P_)   // 512

#define KTOT_    49152      // EMB*BS
#define CPAD_    112        // 97 padded to 7*16
#define KSPLIT_  64
#define KCHUNK_  (KTOT_/KSPLIT_)   // 768

typedef __hip_bfloat16 bf16;
typedef __attribute__((ext_vector_type(8))) short bf16x8;
typedef __attribute__((ext_vector_type(4))) float f32x4;

// Runtime-flagged load of a "float input tensor": isbf=1 -> bf16, 0 -> float32
__device__ inline float ldIn(const void* p, long idx, int isbf) {
    return isbf ? (float)((const bf16*)p)[idx] : ((const float*)p)[idx];
}

__device__ inline unsigned short f2bf(float f) {
    bf16 h = (bf16)f;
    return *(unsigned short*)&h;
}

// ---------------- K0: dtype detection ----------------
__global__ void dtype_detect(const void* __restrict__ seq, int* __restrict__ flag) {
    __shared__ int cnt;
    if (threadIdx.x == 0) cnt = 0;
    __syncthreads();
    const unsigned short* u = (const unsigned short*)seq;
    int bad = 0;
    for (int i = threadIdx.x; i < 1024; i += 256) {
        unsigned short e = (u[i] >> 7) & 0xFF;
        if (e >= 140) bad++;
    }
    atomicAdd(&cnt, bad);
    __syncthreads();
    if (threadIdx.x == 0) flag[0] = (cnt < 16) ? 1 : 0;   // 1 = bf16 inputs
}

// ---------------- K1: ment_emb gather + ent_emb logsumexp over M ----------------
__global__ void ment_kernel(const void* __restrict__ seq, const int* __restrict__ entity_pos,
                            float* __restrict__ ment_emb, float* __restrict__ ent_emb,
                            const int* __restrict__ dtf) {
    int isbf = dtf[0];
    int be = blockIdx.x;            // b*E+e, 64 blocks
    int b = be >> 5;
    int pos[M_];
    for (int m = 0; m < M_; m++) pos[m] = entity_pos[be*M_+m] + 1;
    for (int d = threadIdx.x; d < D_; d += 256) {
        float x[M_];
        for (int m = 0; m < M_; m++) {
            x[m] = ldIn(seq, ((long)b*L_ + pos[m])*D_ + d, isbf);
            ment_emb[((long)be*M_ + m)*D_ + d] = x[m];
        }
        float mx = fmaxf(fmaxf(x[0],x[1]), fmaxf(x[2],x[3]));
        float s = expf(x[0]-mx)+expf(x[1]-mx)+expf(x[2]-mx)+expf(x[3]-mx);
        ent_emb[(long)be*D_ + d] = mx + logf(s);
    }
}

// ---------------- K2: ent_att = mean over M of gathered attn ----------------
__global__ void entatt_kernel(const void* __restrict__ attn, const int* __restrict__ entity_pos,
                              float* __restrict__ ent_att, const int* __restrict__ dtf) {
    int isbf = dtf[0];
    int beh = blockIdx.x;           // (b*E+e)*H+h, 768 blocks
    int h = beh % H_;
    int be = beh / H_;
    int b = be >> 5;
    int pos[M_];
    for (int m = 0; m < M_; m++) pos[m] = entity_pos[be*M_+m] + 1;
    for (int l = threadIdx.x; l < L_; l += 256) {
        float s = 0.f;
        for (int m = 0; m < M_; m++)
            s += ldIn(attn, (((long)(b*H_ + h))*L_ + pos[m])*L_ + l, isbf);
        ent_att[(long)beh*L_ + l] = 0.25f * s;
    }
}

// ---------------- K3: ht_att = normalize_L( mean_H(ha*ta) ) ----------------
__global__ void htatt_kernel(const float* __restrict__ ent_att, const int* __restrict__ hts,
                             float* __restrict__ ht_att) {
    int bp = blockIdx.x;            // 512 blocks
    int b = bp >> 8;
    int h_e = hts[bp*2+0], t_e = hts[bp*2+1];
    const float* ea_h = ent_att + (long)((b*E_ + h_e)*H_)*L_;
    const float* ea_t = ent_att + (long)((b*E_ + t_e)*H_)*L_;
    __shared__ float red[256];
    float v[2];
    for (int t = 0; t < 2; t++) {
        int l = threadIdx.x + t*256;
        float s = 0.f;
        for (int h = 0; h < H_; h++) s += ea_h[h*L_+l] * ea_t[h*L_+l];
        v[t] = s * (1.0f/H_);
    }
    red[threadIdx.x] = v[0] + v[1];
    __syncthreads();
    for (int off = 128; off > 0; off >>= 1) {
        if (threadIdx.x < off) red[threadIdx.x] += red[threadIdx.x+off];
        __syncthreads();
    }
    float inv = 1.0f / (red[0] + 1e-5f);
    for (int t = 0; t < 2; t++) {
        int l = threadIdx.x + t*256;
        ht_att[(long)bp*L_ + l] = v[t] * inv;
    }
}

// ---------------- K4: rs[b,p,d] = sum_l seq[b,l,d]*ht_att[b,p,l] ----------------
__global__ void rs_kernel(const void* __restrict__ seq, const float* __restrict__ ht_att,
                          float* __restrict__ rs, const int* __restrict__ dtf) {
    int isbf = dtf[0];
    int blk = blockIdx.x;           // 128 blocks: 4 p's each
    int b = blk / 64;
    int p0 = (blk % 64) * 4;
    __shared__ float ht[4][L_];
    for (int t = threadIdx.x; t < 4*L_; t += 256) {
        int pp = t >> 9, l = t & 511;
        ht[pp][l] = ht_att[((long)(b*P_ + p0 + pp))*L_ + l];
    }
    __syncthreads();
    for (int it = 0; it < 3; it++) {
        int d = it*256 + threadIdx.x;
        float acc[4] = {0.f,0.f,0.f,0.f};
        for (int l = 0; l < L_; l++) {
            float s = ldIn(seq, ((long)b*L_ + l)*D_ + d, isbf);
            for (int pp = 0; pp < 4; pp++) acc[pp] += s * ht[pp][l];
        }
        for (int pp = 0; pp < 4; pp++)
            rs[((long)(b*P_ + p0 + pp))*D_ + d] = acc[pp];
    }
}

// ---------------- K5: hcat=[hs,rs], tcat=[ts,rs] ----------------
__global__ void cat_kernel(const float* __restrict__ ent_emb, const float* __restrict__ rs,
                           const int* __restrict__ hts,
                           float* __restrict__ hcat, float* __restrict__ tcat) {
    int n = blockIdx.x;             // 512
    int b = n >> 8;
    int h_e = hts[n*2+0], t_e = hts[n*2+1];
    const float* eh = ent_emb + (long)(b*E_ + h_e)*D_;
    const float* et = ent_emb + (long)(b*E_ + t_e)*D_;
    const float* r  = rs + (long)n*D_;
    for (int k = threadIdx.x; k < D_; k += 256) {
        hcat[(long)n*1536 + k]       = eh[k];
        hcat[(long)n*1536 + 768 + k] = r[k];
        tcat[(long)n*1536 + k]       = et[k];
        tcat[(long)n*1536 + 768 + k] = r[k];
    }
}

// ---------------- Generic tiled GEMM: C = act(A@B + bias), up to 4 problems via z ----------------
struct GemmArgs {
    const void* A[4];
    const void* Bm[4];
    const void* bias[4];
    void* Cc[4];
};

__global__ void gemm_generic(GemmArgs args, int lda, int a_in, int ldb, int b_in,
                             int ldc, int M, int N, int K, int act, int c_out,
                             const int* __restrict__ dtf) {
    int isbf = dtf[0];
    int af = a_in ? isbf : 0;
    int bfm = b_in ? isbf : 0;
    const void* A  = args.A[blockIdx.z];
    const void* Bm = args.Bm[blockIdx.z];
    const void* bias = args.bias[blockIdx.z];
    void* Cc = args.Cc[blockIdx.z];

    __shared__ float As[16][65];
    __shared__ float Bs[16][65];
    int m0 = blockIdx.x * 64, n0 = blockIdx.y * 64;
    int tx = threadIdx.x, ty = threadIdx.y;   // 16x16
    int tid = ty*16 + tx;
    float acc[4][4] = {};
    for (int k0 = 0; k0 < K; k0 += 16) {
        for (int t = 0; t < 4; t++) {
            int idx = tid + t*256;
            int rA = idx >> 4, kA = idx & 15;
            int m = m0 + rA, ka = k0 + kA;
            As[kA][rA] = (m < M && ka < K) ? ldIn(A, (long)m*lda + ka, af) : 0.f;
            int rB = idx & 63, kB = idx >> 6;
            int n = n0 + rB, kb = k0 + kB;
            Bs[kB][rB] = (kb < K && n < N) ? ldIn(Bm, (long)kb*ldb + n, bfm) : 0.f;
        }
        __syncthreads();
        for (int kk = 0; kk < 16; kk++) {
            float a[4], b[4];
            for (int i = 0; i < 4; i++) a[i] = As[kk][ty + 16*i];
            for (int j = 0; j < 4; j++) b[j] = Bs[kk][tx + 16*j];
            for (int i = 0; i < 4; i++)
                for (int j = 0; j < 4; j++) acc[i][j] += a[i]*b[j];
        }
        __syncthreads();
    }
    for (int i = 0; i < 4; i++) {
        int m = m0 + ty + 16*i;
        if (m >= M) continue;
        for (int j = 0; j < 4; j++) {
            int n = n0 + tx + 16*j;
            if (n >= N) continue;
            float v = acc[i][j];
            if (bias) v += ldIn(bias, n, isbf);
            if (act == 1) v = tanhf(v);
            if (c_out) {
                if (isbf) ((bf16*)Cc)[(long)m*ldc + n] = (bf16)v;
                else      ((float*)Cc)[(long)m*ldc + n] = v;
            } else {
                ((float*)Cc)[(long)m*ldc + n] = v;
            }
        }
    }
}

// ================= r1 via MFMA =================

// ---- bl materialization: BL[n][k] = hz[n, k>>6] * tz[n, (k>>12)*64 + (k&63)], bf16 ----
// grid (512, 24), block 256; each thread writes 8 consecutive k (one uint4)
__global__ void blgen_kernel(const float* __restrict__ hz, const float* __restrict__ tz,
                             unsigned short* __restrict__ BL) {
    int n = blockIdx.x;
    int k0 = (blockIdx.y*256 + threadIdx.x)*8;
    int gi = k0 >> 6;                 // g*64+i  (hz index)
    int g  = k0 >> 12;
    int j  = k0 & 63;                 // multiple of 8
    float hv = hz[(long)n*EMB_ + gi];
    const float4* tp = (const float4*)(tz + (long)n*EMB_ + g*64 + j);
    float4 t0 = tp[0], t1 = tp[1];
    unsigned short o[8];
    o[0]=f2bf(hv*t0.x); o[1]=f2bf(hv*t0.y); o[2]=f2bf(hv*t0.z); o[3]=f2bf(hv*t0.w);
    o[4]=f2bf(hv*t1.x); o[5]=f2bf(hv*t1.y); o[6]=f2bf(hv*t1.z); o[7]=f2bf(hv*t1.w);
    *(uint4*)(BL + (long)n*KTOT_ + k0) = *(uint4*)o;
}

// ---- W_rel -> WBt[c][k] bf16, c padded to 112 (pad rows = 0). LDS transpose. ----
// grid 384 (k-tiles of 128), block 256
__global__ void wconv_kernel(const void* __restrict__ W_rel, unsigned short* __restrict__ WBt,
                             const int* __restrict__ dtf) {
    int isbf = dtf[0];
    __shared__ unsigned short T[CPAD_][136];   // 128 k + pad 8
    int k0 = blockIdx.x * 128;
    int tid = threadIdx.x;
    for (int idx = tid; idx < 128*97; idx += 256) {
        int kk = idx / 97, c = idx % 97;
        T[c][kk] = f2bf(ldIn(W_rel, (long)(k0+kk)*C_ + c, isbf));
    }
    for (int idx = tid; idx < 15*128; idx += 256) {
        T[97 + (idx>>7)][idx & 127] = 0;
    }
    __syncthreads();
    // write 112 rows x 128 k as uint4 (8 ushorts): 1792 chunks
    for (int t = 0; t < 7; t++) {
        int idx = tid + t*256;            // < 1792
        int c = idx >> 4, kc = idx & 15;
        *(uint4*)(WBt + (long)c*KTOT_ + k0 + kc*8) = *(uint4*)&T[c][kc*8];
    }
}

// ---- MFMA GEMM: partial[kz][n][112] = BL[n, kchunk] @ WBt^T[kchunk, c] ----
// grid (8 n-tiles, KSPLIT_), block 256 (4 waves); 12 k-steps of 64
__global__ void r1_mfma_kernel(const unsigned short* __restrict__ BL,
                               const unsigned short* __restrict__ WBt,
                               float* __restrict__ partial) {
    __shared__ unsigned short Al[64][72];     // +8 pad: 2-way bank aliasing only
    __shared__ unsigned short Btl[CPAD_][72];
    int n0 = blockIdx.x * 64;
    int kbase = blockIdx.y * KCHUNK_;
    int tid = threadIdx.x;
    int wave = tid >> 6, lane = tid & 63;
    int lm = lane & 15, lq = lane >> 4;
    f32x4 acc[7] = {};
    for (int ks = 0; ks < KCHUNK_/64; ks++) {
        int k0 = kbase + ks*64;
        __syncthreads();
        // stage A: 64 n x 64 k
        for (int t = 0; t < 2; t++) {
            int idx = tid + t*256;        // 0..511
            int n = idx >> 3, k8 = idx & 7;
            *(uint4*)&Al[n][k8*8] = *(const uint4*)(BL + (long)(n0+n)*KTOT_ + k0 + k8*8);
        }
        // stage B: 112 c x 64 k
        for (int t = 0; t < 4; t++) {
            int idx = tid + t*256;        // need < 896
            if (idx < 896) {
                int c = idx >> 3, k8 = idx & 7;
                *(uint4*)&Btl[c][k8*8] = *(const uint4*)(WBt + (long)c*KTOT_ + k0 + k8*8);
            }
        }
        __syncthreads();
        for (int half = 0; half < 2; half++) {
            bf16x8 afrag = *(bf16x8*)&Al[wave*16 + lm][half*32 + lq*8];
            #pragma unroll
            for (int ct = 0; ct < 7; ct++) {
                bf16x8 bfrag = *(bf16x8*)&Btl[ct*16 + lm][half*32 + lq*8];
                acc[ct] = __builtin_amdgcn_mfma_f32_16x16x32_bf16(afrag, bfrag, acc[ct], 0, 0, 0);
            }
        }
    }
    // C layout: col = lane&15, row = (lane>>4)*4 + reg
    float* dst = partial + ((long)blockIdx.y*512 + n0)*CPAD_;
    for (int ct = 0; ct < 7; ct++) {
        int c = ct*16 + lm;
        for (int r = 0; r < 4; r++) {
            int nl = wave*16 + lq*4 + r;
            dst[(long)nl*CPAD_ + c] = acc[ct][r];
        }
    }
}

// ---- reduce split-K partials + bias -> r123[:, 0:97] ----
__global__ void r1reduce_kernel(const float* __restrict__ partial, const void* __restrict__ b_rel,
                                float* __restrict__ r123, const int* __restrict__ dtf) {
    int n = blockIdx.x;
    int c = threadIdx.x;
    if (c >= C_) return;
    float s = 0.f;
    for (int kz = 0; kz < KSPLIT_; kz++)
        s += partial[((long)kz*512 + n)*CPAD_ + c];
    r123[(long)n*(3*C_) + c] = s + ldIn(b_rel, c, dtf[0]);
}

// ================= fallback r1 (used only if ws too small) =================
__global__ void r1init_kernel(const void* __restrict__ b_rel, float* __restrict__ r123,
                              const int* __restrict__ dtf) {
    int isbf = dtf[0];
    int idx = blockIdx.x*256 + threadIdx.x;
    if (idx < N_*C_) {
        int nn = idx / C_, c = idx % C_;
        r123[(long)nn*(3*C_) + c] = ldIn(b_rel, c, isbf);
    }
}

__global__ void r1_kernel(const float* __restrict__ hz, const float* __restrict__ tz,
                          const void* __restrict__ W_rel, float* __restrict__ r123,
                          const int* __restrict__ dtf) {
    int isbf = dtf[0];
    int n0 = blockIdx.x * 64;
    int kb = blockIdx.y;
    int i0 = blockIdx.z * 16;
    __shared__ float hzL[16][64];
    __shared__ float tzL[64][64];
    int tid = threadIdx.x;
    for (int t = tid; t < 16*64; t += 256) {
        int ii = t >> 6, n = t & 63;
        hzL[ii][n] = hz[(long)(n0+n)*EMB_ + kb*64 + i0 + ii];
    }
    for (int t = tid; t < 64*64; t += 256) {
        int j = t >> 6, n = t & 63;
        tzL[j][n] = tz[(long)(n0+n)*EMB_ + kb*64 + j];
    }
    __syncthreads();
    int n  = tid & 63;
    int cg = tid >> 6;
    float acc[25];
    for (int u = 0; u < 25; u++) acc[u] = 0.f;
    for (int ii = 0; ii < 16; ii++) {
        float hv = hzL[ii][n];
        long rowbase = (long)((kb*64 + i0 + ii)*64) * C_;
        for (int j = 0; j < 64; j++) {
            float s = hv * tzL[j][n];
            long wb = rowbase + (long)j*C_ + cg;
            #pragma unroll
            for (int u = 0; u < 25; u++) {
                int c = cg + 4*u;
                if (c < C_) acc[u] += s * ldIn(W_rel, wb + 4*u, isbf);
            }
        }
    }
    for (int u = 0; u < 25; u++) {
        int c = cg + 4*u;
        if (c < C_) atomicAdd(&r123[(long)(n0+n)*(3*C_) + c], acc[u]);
    }
}

// ---------------- c2/c3 constants: b_f @ W + b ----------------
__global__ void c23_kernel(const void* __restrict__ b_f,
                           const void* __restrict__ W_unet, const void* __restrict__ b_unet,
                           const void* __restrict__ W_mlp,  const void* __restrict__ b_mlp,
                           float* __restrict__ c23, const int* __restrict__ dtf) {
    int isbf = dtf[0];
    int c = threadIdx.x;
    if (c >= C_) return;
    float s2 = 0.f, s3 = 0.f;
    for (int d = 0; d < D_; d++) {
        float bf = ldIn(b_f, d, isbf);
        s2 += bf * ldIn(W_unet, (long)d*C_ + c, isbf);
        s3 += bf * ldIn(W_mlp,  (long)d*C_ + c, isbf);
    }
    c23[c]      = s2 + ldIn(b_unet, c, isbf);
    c23[C_ + c] = s3 + ldIn(b_mlp,  c, isbf);
}

// ---------------- r2/r3: logsumexp over 16 (i,j) of tanh/gelu ----------------
__global__ void r23_kernel(const float* __restrict__ mu, const float* __restrict__ c23,
                           const int* __restrict__ hts, const int* __restrict__ mention_idx,
                           float* __restrict__ r123) {
    int bp = blockIdx.x;            // 512
    int b = bp >> 8;
    int c = threadIdx.x;
    if (c >= C_) return;
    int h_e = hts[bp*2+0], t_e = hts[bp*2+1];
    const float* mu2h = mu;
    const float* mu2t = mu + 24832;
    const float* mu3h = mu + 49664;
    const float* mu3t = mu + 74496;
    float ah2[4], at2[4], ah3[4], at3[4];
    for (int m = 0; m < 4; m++) {
        int emh = mention_idx[(b*E_ + h_e)*M_ + m];
        int emt = mention_idx[(b*E_ + t_e)*M_ + m];
        ah2[m] = mu2h[(long)(b*128 + emh)*C_ + c];
        ah3[m] = mu3h[(long)(b*128 + emh)*C_ + c];
        at2[m] = mu2t[(long)(b*128 + emt)*C_ + c];
        at3[m] = mu3t[(long)(b*128 + emt)*C_ + c];
    }
    float c2 = c23[c], c3 = c23[C_ + c];
    float v2[16], v3[16];
    int q = 0;
    for (int i = 0; i < 4; i++) {
        for (int j = 0; j < 4; j++, q++) {
            float x2 = ah2[i] + at2[j] + c2;
            v2[q] = tanhf(x2);
            float x3 = ah3[i] + at3[j] + c3;
            float t = tanhf(0.7978845608028654f * (x3 + 0.044715f*x3*x3*x3));
            v3[q] = 0.5f * x3 * (1.0f + t);
        }
    }
    float m2 = v2[0], m3 = v3[0];
    for (q = 1; q < 16; q++) { m2 = fmaxf(m2, v2[q]); m3 = fmaxf(m3, v3[q]); }
    float s2 = 0.f, s3 = 0.f;
    for (q = 0; q < 16; q++) { s2 += expf(v2[q]-m2); s3 += expf(v3[q]-m3); }
    r123[(long)bp*(3*C_) + C_   + c] = m2 + logf(s2);
    r123[(long)bp*(3*C_) + 2*C_ + c] = m3 + logf(s3);
}

extern "C" void kernel_launch(void* const* d_in, const int* in_sizes, int n_in,
                              void* d_out, int out_size, void* d_ws, size_t ws_size,
                              hipStream_t stream) {
    const void* seq        = d_in[0];
    const void* attn       = d_in[1];
    const int*  entity_pos = (const int*)d_in[2];
    const int*  hts        = (const int*)d_in[3];
    const int*  mention_idx= (const int*)d_in[4];
    const void* W_head     = d_in[5];
    const void* b_head     = d_in[6];
    const void* W_tail     = d_in[7];
    const void* b_tail     = d_in[8];
    const void* W_rel      = d_in[9];
    const void* b_rel      = d_in[10];
    const void* W_fh       = d_in[11];
    const void* W_ft       = d_in[12];
    const void* b_f        = d_in[13];
    const void* W_unet     = d_in[14];
    const void* b_unet     = d_in[15];
    const void* W_mlp      = d_in[16];
    const void* b_mlp      = d_in[17];
    const void* W_bil      = d_in[18];
    const void* b_bil      = d_in[19];

    float* w = (float*)d_ws;
    int*   dtf      = (int*)w;          // 64 floats reserved
    float* ment_emb = w + 64;           // 196608
    float* ent_emb  = w + 196672;       // 49152
    float* ent_att  = w + 245824;       // 393216
    float* ht_att   = w + 639040;       // 262144
    float* rs       = w + 901184;       // 393216
    float* hcat     = w + 1294400;      // 786432
    float* tcat     = w + 2080832;      // 786432
    float* hz       = w + 2867264;      // 393216
    float* tz       = w + 3260480;      // 393216
    float* r123     = w + 3653696;      // 148992
    float* mu       = w + 3802688;      // 99328   (4 x 24832)
    float* Ffold    = w + 3902016;      // 297984  (4 x 74496)
    float* c23      = w + 4200000;      // 256
    unsigned short* BL  = (unsigned short*)(w + 4200256);   // 512*49152 bf16 = 12582912 floats
    unsigned short* WBt = (unsigned short*)(w + 16783168);  // 112*49152 bf16 = 2752512 floats
    float* partial  = w + 19535680;                          // 64*512*112 = 3670016
    const size_t ws_need = (size_t)(19535680 + (long)KSPLIT_*512*CPAD_) * 4;
    int use_mfma = (ws_size >= ws_need);

    // 0. dtype detection (bf16 vs f32 float tensors)
    dtype_detect<<<1, 256, 0, stream>>>(seq, dtf);
    // W_rel conversion (independent of the main chain)
    if (use_mfma)
        wconv_kernel<<<KTOT_/128, 256, 0, stream>>>(W_rel, WBt, dtf);
    // 1. mentions + entity embeddings
    ment_kernel<<<B_*E_, 256, 0, stream>>>(seq, entity_pos, ment_emb, ent_emb, dtf);
    // 2. entity attention
    entatt_kernel<<<B_*E_*H_, 256, 0, stream>>>(attn, entity_pos, ent_att, dtf);
    // 3. ht attention (normalized)
    htatt_kernel<<<N_, 256, 0, stream>>>(ent_att, hts, ht_att);
    // 4. rs
    rs_kernel<<<128, 256, 0, stream>>>(seq, ht_att, rs, dtf);
    // 5. concatenated inputs
    cat_kernel<<<N_, 256, 0, stream>>>(ent_emb, rs, hts, hcat, tcat);

    // 6. hz/tz GEMMs (fused in z)
    {
        GemmArgs ga = {};
        ga.A[0] = hcat;  ga.Bm[0] = W_head; ga.bias[0] = b_head; ga.Cc[0] = hz;
        ga.A[1] = tcat;  ga.Bm[1] = W_tail; ga.bias[1] = b_tail; ga.Cc[1] = tz;
        gemm_generic<<<dim3(8,12,2), dim3(16,16), 0, stream>>>(ga, 1536, 0, 768, 1, 768, N_, 768, 1536, 1, 0, dtf);
    }
    // 7. folded weights F_q = W_f{h,t} @ W_{unet,mlp}  (768x97 each)
    {
        GemmArgs ga = {};
        const void* As[4] = {W_fh, W_ft, W_fh, W_ft};
        const void* Bs[4] = {W_unet, W_unet, W_mlp, W_mlp};
        for (int q = 0; q < 4; q++) {
            ga.A[q] = As[q]; ga.Bm[q] = Bs[q]; ga.bias[q] = nullptr;
            ga.Cc[q] = Ffold + q*74496;
        }
        gemm_generic<<<dim3(12,2,4), dim3(16,16), 0, stream>>>(ga, 768, 1, 97, 1, 97, 768, C_, 768, 0, 0, dtf);
    }
    // 8. mu_q = ment_flat @ F_q   (256x97 each)
    {
        GemmArgs ga = {};
        for (int q = 0; q < 4; q++) {
            ga.A[q] = ment_emb; ga.Bm[q] = Ffold + q*74496; ga.bias[q] = nullptr;
            ga.Cc[q] = mu + q*24832;
        }
        gemm_generic<<<dim3(4,2,4), dim3(16,16), 0, stream>>>(ga, 768, 0, 97, 0, 97, 256, C_, 768, 0, 0, dtf);
    }
    // 9. c2/c3 constants
    c23_kernel<<<1, 128, 0, stream>>>(b_f, W_unet, b_unet, W_mlp, b_mlp, c23, dtf);

    // 10/11. r1
    if (use_mfma) {
        blgen_kernel<<<dim3(N_, KTOT_/(256*8)), 256, 0, stream>>>(hz, tz, BL);
        r1_mfma_kernel<<<dim3(8, KSPLIT_), 256, 0, stream>>>(BL, WBt, partial);
        r1reduce_kernel<<<N_, 128, 0, stream>>>(partial, b_rel, r123, dtf);
    } else {
        r1init_kernel<<<(N_*C_ + 255)/256, 256, 0, stream>>>(b_rel, r123, dtf);
        r1_kernel<<<dim3(8,12,4), 256, 0, stream>>>(hz, tz, W_rel, r123, dtf);
    }
    // 12. r2/r3
    r23_kernel<<<N_, 128, 0, stream>>>(mu, c23, hts, mention_idx, r123);
    // 13. final: out = r123 @ W_bil + b_bil  (dtype per flag)
    {
        GemmArgs ga = {};
        ga.A[0] = r123; ga.Bm[0] = W_bil; ga.bias[0] = b_bil; ga.Cc[0] = d_out;
        gemm_generic<<<dim3(8,2,1), dim3(16,16), 0, stream>>>(ga, 3*C_, 0, 97, 1, 97, N_, C_, 3*C_, 0, 1, dtf);
    }
}

// Round 4
// 744.485 us; speedup vs baseline: 3.5005x; 1.6933x over previous
//
#include <hip/hip_runtime.h>
#include <hip/hip_bf16.h>

// Problem constants
#define B_  2
#define L_  512
#define D_  768
#define H_  12
#define E_  32
#define M_  4
#define P_  256
#define EMB_ 768
#define BS_ 64
#define C_  97
#define N_  (B_*P_)   // 512

#define KTOT_    49152      // EMB*BS
#define CPAD_    112        // 97 padded to 7*16
#define KSPLIT_  32
#define KCHUNK_  (KTOT_/KSPLIT_)   // 1536

typedef __hip_bfloat16 bf16;
typedef __attribute__((ext_vector_type(8))) short bf16x8;
typedef __attribute__((ext_vector_type(4))) float f32x4;

// Runtime-flagged load of a "float input tensor": isbf=1 -> bf16, 0 -> float32
__device__ inline float ldIn(const void* p, long idx, int isbf) {
    return isbf ? (float)((const bf16*)p)[idx] : ((const float*)p)[idx];
}

__device__ inline unsigned short f2bf(float f) {
    bf16 h = (bf16)f;
    return *(unsigned short*)&h;
}

// ---------------- K0: dtype detection ----------------
__global__ void dtype_detect(const void* __restrict__ seq, int* __restrict__ flag) {
    __shared__ int cnt;
    if (threadIdx.x == 0) cnt = 0;
    __syncthreads();
    const unsigned short* u = (const unsigned short*)seq;
    int bad = 0;
    for (int i = threadIdx.x; i < 1024; i += 256) {
        unsigned short e = (u[i] >> 7) & 0xFF;
        if (e >= 140) bad++;
    }
    atomicAdd(&cnt, bad);
    __syncthreads();
    if (threadIdx.x == 0) flag[0] = (cnt < 16) ? 1 : 0;   // 1 = bf16 inputs
}

// ---------------- K1: ment_emb gather + ent_emb logsumexp over M ----------------
__global__ void ment_kernel(const void* __restrict__ seq, const int* __restrict__ entity_pos,
                            float* __restrict__ ment_emb, float* __restrict__ ent_emb,
                            const int* __restrict__ dtf) {
    int isbf = dtf[0];
    int be = blockIdx.x;            // b*E+e, 64 blocks
    int b = be >> 5;
    int pos[M_];
    for (int m = 0; m < M_; m++) pos[m] = entity_pos[be*M_+m] + 1;
    for (int d = threadIdx.x; d < D_; d += 256) {
        float x[M_];
        for (int m = 0; m < M_; m++) {
            x[m] = ldIn(seq, ((long)b*L_ + pos[m])*D_ + d, isbf);
            ment_emb[((long)be*M_ + m)*D_ + d] = x[m];
        }
        float mx = fmaxf(fmaxf(x[0],x[1]), fmaxf(x[2],x[3]));
        float s = expf(x[0]-mx)+expf(x[1]-mx)+expf(x[2]-mx)+expf(x[3]-mx);
        ent_emb[(long)be*D_ + d] = mx + logf(s);
    }
}

// ---------------- K2: ent_att = mean over M of gathered attn ----------------
__global__ void entatt_kernel(const void* __restrict__ attn, const int* __restrict__ entity_pos,
                              float* __restrict__ ent_att, const int* __restrict__ dtf) {
    int isbf = dtf[0];
    int beh = blockIdx.x;           // (b*E+e)*H+h, 768 blocks
    int h = beh % H_;
    int be = beh / H_;
    int b = be >> 5;
    int pos[M_];
    for (int m = 0; m < M_; m++) pos[m] = entity_pos[be*M_+m] + 1;
    for (int l = threadIdx.x; l < L_; l += 256) {
        float s = 0.f;
        for (int m = 0; m < M_; m++)
            s += ldIn(attn, (((long)(b*H_ + h))*L_ + pos[m])*L_ + l, isbf);
        ent_att[(long)beh*L_ + l] = 0.25f * s;
    }
}

// ---------------- K3: ht_att (bf16 out) = normalize_L( mean_H(ha*ta) ) ----------------
__global__ void htatt_kernel(const float* __restrict__ ent_att, const int* __restrict__ hts,
                             unsigned short* __restrict__ htb) {
    int bp = blockIdx.x;            // 512 blocks
    int b = bp >> 8;
    int h_e = hts[bp*2+0], t_e = hts[bp*2+1];
    const float* ea_h = ent_att + (long)((b*E_ + h_e)*H_)*L_;
    const float* ea_t = ent_att + (long)((b*E_ + t_e)*H_)*L_;
    __shared__ float red[256];
    float v[2];
    for (int t = 0; t < 2; t++) {
        int l = threadIdx.x + t*256;
        float s = 0.f;
        for (int h = 0; h < H_; h++) s += ea_h[h*L_+l] * ea_t[h*L_+l];
        v[t] = s * (1.0f/H_);
    }
    red[threadIdx.x] = v[0] + v[1];
    __syncthreads();
    for (int off = 128; off > 0; off >>= 1) {
        if (threadIdx.x < off) red[threadIdx.x] += red[threadIdx.x+off];
        __syncthreads();
    }
    float inv = 1.0f / (red[0] + 1e-5f);
    for (int t = 0; t < 2; t++) {
        int l = threadIdx.x + t*256;
        htb[(long)bp*L_ + l] = f2bf(v[t] * inv);
    }
}

// ---------------- transpose + bf16 convert: src[K][Nn] (flagged) -> dst[Nn][K] bf16 ----
// grid (K/32, Nn/32), block 256. K, Nn multiples of 32.
__global__ void wtrans_kernel(const void* __restrict__ src, long src_off, int K, int Nn,
                              unsigned short* __restrict__ dst, const int* __restrict__ dtf) {
    int isbf = dtf[0];
    __shared__ float T[32][33];
    int k0 = blockIdx.x*32, n0 = blockIdx.y*32;
    int c = threadIdx.x & 31, r8 = threadIdx.x >> 5;
    for (int rr = 0; rr < 4; rr++) {
        int r = r8 + rr*8;
        T[r][c] = ldIn(src, src_off + (long)(k0+r)*Nn + n0 + c, isbf);
    }
    __syncthreads();
    for (int rr = 0; rr < 4; rr++) {
        int r = r8 + rr*8;
        dst[(long)(n0+r)*K + k0 + c] = f2bf(T[c][r]);
    }
}

// ---------------- catb: hcatb=[hs,rs], tcatb=[ts,rs] in bf16 ----------------
__global__ void catb_kernel(const float* __restrict__ ent_emb, const float* __restrict__ rs,
                            const int* __restrict__ hts,
                            unsigned short* __restrict__ hcatb, unsigned short* __restrict__ tcatb) {
    int n = blockIdx.x;             // 512
    int b = n >> 8;
    int h_e = hts[n*2+0], t_e = hts[n*2+1];
    const float* eh = ent_emb + (long)(b*E_ + h_e)*D_;
    const float* et = ent_emb + (long)(b*E_ + t_e)*D_;
    const float* r  = rs + (long)n*D_;
    for (int k = threadIdx.x; k < D_; k += 256) {
        hcatb[(long)n*1536 + k] = f2bf(eh[k]);
        tcatb[(long)n*1536 + k] = f2bf(et[k]);
        unsigned short rb = f2bf(r[k]);
        hcatb[(long)n*1536 + 768 + k] = rb;
        tcatb[(long)n*1536 + 768 + k] = rb;
    }
}

// ---------------- Generic MFMA GEMM: C[m][n] = act(A[m][:K] . Bt[n][:K] + bias[n]) ----------------
// 64x64 tile per block, 4 waves; K multiple of 64; up to 4 problems via z.
struct MfmaNT {
    const unsigned short* A[4];
    const unsigned short* Bt[4];
    const void* bias[4];
    float* C[4];
};

__global__ void mfma_nt_kernel(MfmaNT args, int K, int ldc, int act, const int* __restrict__ dtf) {
    const unsigned short* A  = args.A[blockIdx.z];
    const unsigned short* Bt = args.Bt[blockIdx.z];
    const void* bias = args.bias[blockIdx.z];
    float* C = args.C[blockIdx.z];
    __shared__ unsigned short Al[64][72];
    __shared__ unsigned short Btl[64][72];
    int m0 = blockIdx.x*64, n0 = blockIdx.y*64;
    int tid = threadIdx.x, wave = tid>>6, lane = tid&63;
    int lm = lane&15, lq = lane>>4;
    f32x4 acc[4] = {};
    for (int k0 = 0; k0 < K; k0 += 64) {
        __syncthreads();
        for (int t = 0; t < 2; t++) {
            int idx = tid + t*256;      // 0..511
            int r = idx>>3, k8 = idx&7;
            *(uint4*)&Al[r][k8*8]  = *(const uint4*)(A  + (long)(m0+r)*K + k0 + k8*8);
            *(uint4*)&Btl[r][k8*8] = *(const uint4*)(Bt + (long)(n0+r)*K + k0 + k8*8);
        }
        __syncthreads();
        for (int half = 0; half < 2; half++) {
            bf16x8 af = *(bf16x8*)&Al[wave*16+lm][half*32+lq*8];
            #pragma unroll
            for (int ct = 0; ct < 4; ct++) {
                bf16x8 bfr = *(bf16x8*)&Btl[ct*16+lm][half*32+lq*8];
                acc[ct] = __builtin_amdgcn_mfma_f32_16x16x32_bf16(af, bfr, acc[ct], 0, 0, 0);
            }
        }
    }
    int isbf = dtf[0];
    for (int ct = 0; ct < 4; ct++) {
        int n = n0 + ct*16 + lm;
        float bia = bias ? ldIn(bias, n, isbf) : 0.f;
        for (int r = 0; r < 4; r++) {
            int m = m0 + wave*16 + lq*4 + r;
            float v = acc[ct][r] + bia;
            if (act == 1) v = tanhf(v);
            C[(long)m*ldc + n] = v;
        }
    }
}

// ---------------- Generic tiled fp32 GEMM (small problems): C = act(A@B + bias) ----------------
struct GemmArgs {
    const void* A[4];
    const void* Bm[4];
    const void* bias[4];
    void* Cc[4];
};

__global__ void gemm_generic(GemmArgs args, int lda, int a_in, int ldb, int b_in,
                             int ldc, int M, int N, int K, int act, int c_out,
                             const int* __restrict__ dtf) {
    int isbf = dtf[0];
    int af = a_in ? isbf : 0;
    int bfm = b_in ? isbf : 0;
    const void* A  = args.A[blockIdx.z];
    const void* Bm = args.Bm[blockIdx.z];
    const void* bias = args.bias[blockIdx.z];
    void* Cc = args.Cc[blockIdx.z];

    __shared__ float As[16][65];
    __shared__ float Bs[16][65];
    int m0 = blockIdx.x * 64, n0 = blockIdx.y * 64;
    int tx = threadIdx.x, ty = threadIdx.y;   // 16x16
    int tid = ty*16 + tx;
    float acc[4][4] = {};
    for (int k0 = 0; k0 < K; k0 += 16) {
        for (int t = 0; t < 4; t++) {
            int idx = tid + t*256;
            int rA = idx >> 4, kA = idx & 15;
            int m = m0 + rA, ka = k0 + kA;
            As[kA][rA] = (m < M && ka < K) ? ldIn(A, (long)m*lda + ka, af) : 0.f;
            int rB = idx & 63, kB = idx >> 6;
            int n = n0 + rB, kb = k0 + kB;
            Bs[kB][rB] = (kb < K && n < N) ? ldIn(Bm, (long)kb*ldb + n, bfm) : 0.f;
        }
        __syncthreads();
        for (int kk = 0; kk < 16; kk++) {
            float a[4], b[4];
            for (int i = 0; i < 4; i++) a[i] = As[kk][ty + 16*i];
            for (int j = 0; j < 4; j++) b[j] = Bs[kk][tx + 16*j];
            for (int i = 0; i < 4; i++)
                for (int j = 0; j < 4; j++) acc[i][j] += a[i]*b[j];
        }
        __syncthreads();
    }
    for (int i = 0; i < 4; i++) {
        int m = m0 + ty + 16*i;
        if (m >= M) continue;
        for (int j = 0; j < 4; j++) {
            int n = n0 + tx + 16*j;
            if (n >= N) continue;
            float v = acc[i][j];
            if (bias) v += ldIn(bias, n, isbf);
            if (act == 1) v = tanhf(v);
            if (c_out) {
                if (isbf) ((bf16*)Cc)[(long)m*ldc + n] = (bf16)v;
                else      ((float*)Cc)[(long)m*ldc + n] = v;
            } else {
                ((float*)Cc)[(long)m*ldc + n] = v;
            }
        }
    }
}

// ================= r1 via MFMA =================

// ---- bl materialization: BL[n][k] = hz[n, k>>6] * tz[n, (k>>12)*64 + (k&63)], bf16 ----
__global__ void blgen_kernel(const float* __restrict__ hz, const float* __restrict__ tz,
                             unsigned short* __restrict__ BL) {
    int n = blockIdx.x;
    int k0 = (blockIdx.y*256 + threadIdx.x)*8;
    int gi = k0 >> 6;
    int g  = k0 >> 12;
    int j  = k0 & 63;
    float hv = hz[(long)n*EMB_ + gi];
    const float4* tp = (const float4*)(tz + (long)n*EMB_ + g*64 + j);
    float4 t0 = tp[0], t1 = tp[1];
    unsigned short o[8];
    o[0]=f2bf(hv*t0.x); o[1]=f2bf(hv*t0.y); o[2]=f2bf(hv*t0.z); o[3]=f2bf(hv*t0.w);
    o[4]=f2bf(hv*t1.x); o[5]=f2bf(hv*t1.y); o[6]=f2bf(hv*t1.z); o[7]=f2bf(hv*t1.w);
    *(uint4*)(BL + (long)n*KTOT_ + k0) = *(uint4*)o;
}

// ---- W_rel -> WBt[c][k] bf16, c padded to 112 (pad rows = 0). LDS transpose. ----
__global__ void wconv_kernel(const void* __restrict__ W_rel, unsigned short* __restrict__ WBt,
                             const int* __restrict__ dtf) {
    int isbf = dtf[0];
    __shared__ unsigned short T[CPAD_][136];
    int k0 = blockIdx.x * 128;
    int tid = threadIdx.x;
    for (int idx = tid; idx < 128*97; idx += 256) {
        int kk = idx / 97, c = idx % 97;
        T[c][kk] = f2bf(ldIn(W_rel, (long)(k0+kk)*C_ + c, isbf));
    }
    for (int idx = tid; idx < 15*128; idx += 256) {
        T[97 + (idx>>7)][idx & 127] = 0;
    }
    __syncthreads();
    for (int t = 0; t < 7; t++) {
        int idx = tid + t*256;            // < 1792
        int c = idx >> 4, kc = idx & 15;
        *(uint4*)(WBt + (long)c*KTOT_ + k0 + kc*8) = *(uint4*)&T[c][kc*8];
    }
}

// ---- MFMA GEMM: partial[kz][n][112] = BL[n, kchunk] @ WBt^T ----
__global__ void r1_mfma_kernel(const unsigned short* __restrict__ BL,
                               const unsigned short* __restrict__ WBt,
                               float* __restrict__ partial) {
    __shared__ unsigned short Al[64][72];
    __shared__ unsigned short Btl[CPAD_][72];
    int n0 = blockIdx.x * 64;
    int kbase = blockIdx.y * KCHUNK_;
    int tid = threadIdx.x;
    int wave = tid >> 6, lane = tid & 63;
    int lm = lane & 15, lq = lane >> 4;
    f32x4 acc[7] = {};
    for (int ks = 0; ks < KCHUNK_/64; ks++) {
        int k0 = kbase + ks*64;
        __syncthreads();
        for (int t = 0; t < 2; t++) {
            int idx = tid + t*256;
            int n = idx >> 3, k8 = idx & 7;
            *(uint4*)&Al[n][k8*8] = *(const uint4*)(BL + (long)(n0+n)*KTOT_ + k0 + k8*8);
        }
        for (int t = 0; t < 4; t++) {
            int idx = tid + t*256;
            if (idx < 896) {
                int c = idx >> 3, k8 = idx & 7;
                *(uint4*)&Btl[c][k8*8] = *(const uint4*)(WBt + (long)c*KTOT_ + k0 + k8*8);
            }
        }
        __syncthreads();
        for (int half = 0; half < 2; half++) {
            bf16x8 afrag = *(bf16x8*)&Al[wave*16 + lm][half*32 + lq*8];
            #pragma unroll
            for (int ct = 0; ct < 7; ct++) {
                bf16x8 bfrag = *(bf16x8*)&Btl[ct*16 + lm][half*32 + lq*8];
                acc[ct] = __builtin_amdgcn_mfma_f32_16x16x32_bf16(afrag, bfrag, acc[ct], 0, 0, 0);
            }
        }
    }
    float* dst = partial + ((long)blockIdx.y*512 + n0)*CPAD_;
    for (int ct = 0; ct < 7; ct++) {
        int c = ct*16 + lm;
        for (int r = 0; r < 4; r++) {
            int nl = wave*16 + lq*4 + r;
            dst[(long)nl*CPAD_ + c] = acc[ct][r];
        }
    }
}

// ---- reduce split-K partials + bias -> r123[:, 0:97] ----
__global__ void r1reduce_kernel(const float* __restrict__ partial, const void* __restrict__ b_rel,
                                float* __restrict__ r123, const int* __restrict__ dtf) {
    int n = blockIdx.x;
    int c = threadIdx.x;
    if (c >= C_) return;
    float s = 0.f;
    for (int kz = 0; kz < KSPLIT_; kz++)
        s += partial[((long)kz*512 + n)*CPAD_ + c];
    r123[(long)n*(3*C_) + c] = s + ldIn(b_rel, c, dtf[0]);
}

// ---------------- c2/c3 constants: b_f @ W + b ----------------
__global__ void c23_kernel(const void* __restrict__ b_f,
                           const void* __restrict__ W_unet, const void* __restrict__ b_unet,
                           const void* __restrict__ W_mlp,  const void* __restrict__ b_mlp,
                           float* __restrict__ c23, const int* __restrict__ dtf) {
    int isbf = dtf[0];
    int c = threadIdx.x;
    if (c >= C_) return;
    float s2 = 0.f, s3 = 0.f;
    for (int d = 0; d < D_; d++) {
        float bf = ldIn(b_f, d, isbf);
        s2 += bf * ldIn(W_unet, (long)d*C_ + c, isbf);
        s3 += bf * ldIn(W_mlp,  (long)d*C_ + c, isbf);
    }
    c23[c]      = s2 + ldIn(b_unet, c, isbf);
    c23[C_ + c] = s3 + ldIn(b_mlp,  c, isbf);
}

// ---------------- r2/r3: logsumexp over 16 (i,j) of tanh/gelu ----------------
__global__ void r23_kernel(const float* __restrict__ mu, const float* __restrict__ c23,
                           const int* __restrict__ hts, const int* __restrict__ mention_idx,
                           float* __restrict__ r123) {
    int bp = blockIdx.x;            // 512
    int b = bp >> 8;
    int c = threadIdx.x;
    if (c >= C_) return;
    int h_e = hts[bp*2+0], t_e = hts[bp*2+1];
    const float* mu2h = mu;
    const float* mu2t = mu + 24832;
    const float* mu3h = mu + 49664;
    const float* mu3t = mu + 74496;
    float ah2[4], at2[4], ah3[4], at3[4];
    for (int m = 0; m < 4; m++) {
        int emh = mention_idx[(b*E_ + h_e)*M_ + m];
        int emt = mention_idx[(b*E_ + t_e)*M_ + m];
        ah2[m] = mu2h[(long)(b*128 + emh)*C_ + c];
        ah3[m] = mu3h[(long)(b*128 + emh)*C_ + c];
        at2[m] = mu2t[(long)(b*128 + emt)*C_ + c];
        at3[m] = mu3t[(long)(b*128 + emt)*C_ + c];
    }
    float c2 = c23[c], c3 = c23[C_ + c];
    float v2[16], v3[16];
    int q = 0;
    for (int i = 0; i < 4; i++) {
        for (int j = 0; j < 4; j++, q++) {
            float x2 = ah2[i] + at2[j] + c2;
            v2[q] = tanhf(x2);
            float x3 = ah3[i] + at3[j] + c3;
            float t = tanhf(0.7978845608028654f * (x3 + 0.044715f*x3*x3*x3));
            v3[q] = 0.5f * x3 * (1.0f + t);
        }
    }
    float m2 = v2[0], m3 = v3[0];
    for (q = 1; q < 16; q++) { m2 = fmaxf(m2, v2[q]); m3 = fmaxf(m3, v3[q]); }
    float s2 = 0.f, s3 = 0.f;
    for (q = 0; q < 16; q++) { s2 += expf(v2[q]-m2); s3 += expf(v3[q]-m3); }
    r123[(long)bp*(3*C_) + C_   + c] = m2 + logf(s2);
    r123[(long)bp*(3*C_) + 2*C_ + c] = m3 + logf(s3);
}

extern "C" void kernel_launch(void* const* d_in, const int* in_sizes, int n_in,
                              void* d_out, int out_size, void* d_ws, size_t ws_size,
                              hipStream_t stream) {
    const void* seq        = d_in[0];
    const void* attn       = d_in[1];
    const int*  entity_pos = (const int*)d_in[2];
    const int*  hts        = (const int*)d_in[3];
    const int*  mention_idx= (const int*)d_in[4];
    const void* W_head     = d_in[5];
    const void* b_head     = d_in[6];
    const void* W_tail     = d_in[7];
    const void* b_tail     = d_in[8];
    const void* W_rel      = d_in[9];
    const void* b_rel      = d_in[10];
    const void* W_fh       = d_in[11];
    const void* W_ft       = d_in[12];
    const void* b_f        = d_in[13];
    const void* W_unet     = d_in[14];
    const void* b_unet     = d_in[15];
    const void* W_mlp      = d_in[16];
    const void* b_mlp      = d_in[17];
    const void* W_bil      = d_in[18];
    const void* b_bil      = d_in[19];

    float* w = (float*)d_ws;
    int*   dtf      = (int*)w;                              // 64
    float* ment_emb = w + 64;                               // 196608
    float* ent_emb  = w + 196672;                           // 49152
    float* ent_att  = w + 245824;                           // 393216
    unsigned short* htb = (unsigned short*)(w + 639040);    // 512*512 bf16 = 65536 fl
    float* rs       = w + 704576;                           // 393216
    float* hz       = w + 1097792;                          // 393216
    float* tz       = w + 1491008;                          // 393216
    float* r123     = w + 1884224;                          // 148992
    float* mu       = w + 2033216;                          // 99328
    float* Ffold    = w + 2132544;                          // 297984
    float* c23      = w + 2430528;                          // 256
    unsigned short* seqT  = (unsigned short*)(w + 2430784); // 2*768*512 bf16 = 393216 fl
    unsigned short* WhT   = (unsigned short*)(w + 2824000); // 768*1536 bf16 = 589824 fl
    unsigned short* WtT   = (unsigned short*)(w + 3413824); // 589824 fl
    unsigned short* hcatb = (unsigned short*)(w + 4003648); // 512*1536 bf16 = 393216 fl
    unsigned short* tcatb = (unsigned short*)(w + 4396864); // 393216 fl
    unsigned short* BL    = (unsigned short*)(w + 4790080); // 512*49152 bf16 = 12582912 fl
    unsigned short* WBt   = (unsigned short*)(w + 17372992);// 112*49152 bf16 = 2752512 fl
    float* partial  = w + 20125504;                         // 32*512*112 = 1835008 fl -> end 21960512

    // 0. dtype detection (bf16 vs f32 float tensors)
    dtype_detect<<<1, 256, 0, stream>>>(seq, dtf);
    // weight preprocessing (independent of the activation chain)
    wconv_kernel<<<KTOT_/128, 256, 0, stream>>>(W_rel, WBt, dtf);
    wtrans_kernel<<<dim3(1536/32, 768/32), 256, 0, stream>>>(W_head, 0, 1536, 768, WhT, dtf);
    wtrans_kernel<<<dim3(1536/32, 768/32), 256, 0, stream>>>(W_tail, 0, 1536, 768, WtT, dtf);
    wtrans_kernel<<<dim3(512/32, 768/32), 256, 0, stream>>>(seq, 0,        512, 768, seqT,          dtf);
    wtrans_kernel<<<dim3(512/32, 768/32), 256, 0, stream>>>(seq, 393216,   512, 768, seqT + 393216, dtf);
    // 1. mentions + entity embeddings
    ment_kernel<<<B_*E_, 256, 0, stream>>>(seq, entity_pos, ment_emb, ent_emb, dtf);
    // 2. entity attention
    entatt_kernel<<<B_*E_*H_, 256, 0, stream>>>(attn, entity_pos, ent_att, dtf);
    // 3. ht attention (normalized, bf16)
    htatt_kernel<<<N_, 256, 0, stream>>>(ent_att, hts, htb);
    // 4. rs = ht_att @ seq  (MFMA, per-batch via z)
    {
        MfmaNT ga = {};
        for (int z = 0; z < 2; z++) {
            ga.A[z]  = htb + (long)z*256*512;
            ga.Bt[z] = seqT + (long)z*393216;
            ga.bias[z] = nullptr;
            ga.C[z]  = rs + (long)z*256*768;
        }
        mfma_nt_kernel<<<dim3(4, 12, 2), 256, 0, stream>>>(ga, 512, 768, 0, dtf);
    }
    // 5. concatenated inputs (bf16)
    catb_kernel<<<N_, 256, 0, stream>>>(ent_emb, rs, hts, hcatb, tcatb);
    // 6. hz/tz = tanh(cat @ W + b)  (MFMA, fused in z)
    {
        MfmaNT ga = {};
        ga.A[0] = hcatb; ga.Bt[0] = WhT; ga.bias[0] = b_head; ga.C[0] = hz;
        ga.A[1] = tcatb; ga.Bt[1] = WtT; ga.bias[1] = b_tail; ga.C[1] = tz;
        mfma_nt_kernel<<<dim3(8, 12, 2), 256, 0, stream>>>(ga, 1536, 768, 1, dtf);
    }
    // 7. folded weights F_q = W_f{h,t} @ W_{unet,mlp}  (768x97 each)
    {
        GemmArgs ga = {};
        const void* As[4] = {W_fh, W_ft, W_fh, W_ft};
        const void* Bs[4] = {W_unet, W_unet, W_mlp, W_mlp};
        for (int q = 0; q < 4; q++) {
            ga.A[q] = As[q]; ga.Bm[q] = Bs[q]; ga.bias[q] = nullptr;
            ga.Cc[q] = Ffold + q*74496;
        }
        gemm_generic<<<dim3(12,2,4), dim3(16,16), 0, stream>>>(ga, 768, 1, 97, 1, 97, 768, C_, 768, 0, 0, dtf);
    }
    // 8. mu_q = ment_flat @ F_q   (256x97 each)
    {
        GemmArgs ga = {};
        for (int q = 0; q < 4; q++) {
            ga.A[q] = ment_emb; ga.Bm[q] = Ffold + q*74496; ga.bias[q] = nullptr;
            ga.Cc[q] = mu + q*24832;
        }
        gemm_generic<<<dim3(4,2,4), dim3(16,16), 0, stream>>>(ga, 768, 0, 97, 0, 97, 256, C_, 768, 0, 0, dtf);
    }
    // 9. c2/c3 constants
    c23_kernel<<<1, 128, 0, stream>>>(b_f, W_unet, b_unet, W_mlp, b_mlp, c23, dtf);
    // 10. r1 via MFMA
    blgen_kernel<<<dim3(N_, KTOT_/(256*8)), 256, 0, stream>>>(hz, tz, BL);
    r1_mfma_kernel<<<dim3(8, KSPLIT_), 256, 0, stream>>>(BL, WBt, partial);
    r1reduce_kernel<<<N_, 128, 0, stream>>>(partial, b_rel, r123, dtf);
    // 12. r2/r3
    r23_kernel<<<N_, 128, 0, stream>>>(mu, c23, hts, mention_idx, r123);
    // 13. final: out = r123 @ W_bil + b_bil  (dtype per flag)
    {
        GemmArgs ga = {};
        ga.A[0] = r123; ga.Bm[0] = W_bil; ga.bias[0] = b_bil; ga.Cc[0] = d_out;
        gemm_generic<<<dim3(8,2,1), dim3(16,16), 0, stream>>>(ga, 3*C_, 0, 97, 1, 97, N_, C_, 3*C_, 0, 1, dtf);
    }
}

// Round 5
// 430.818 us; speedup vs baseline: 6.0491x; 1.7281x over previous
//
#include <hip/hip_runtime.h>
#include <hip/hip_bf16.h>

// Problem constants
#define B_  2
#define L_  512
#define D_  768
#define H_  12
#define E_  32
#define M_  4
#define P_  256
#define EMB_ 768
#define BS_ 64
#define C_  97
#define N_  (B_*P_)   // 512

#define KTOT_    49152      // EMB*BS
#define CPAD_    112        // 97 padded to 7*16
#define KSPLIT_  32
#define KCHUNK_  (KTOT_/KSPLIT_)   // 1536

typedef __hip_bfloat16 bf16;
typedef __attribute__((ext_vector_type(8))) short bf16x8;
typedef __attribute__((ext_vector_type(4))) float f32x4;

__device__ inline float ldIn(const void* p, long idx, int isbf) {
    return isbf ? (float)((const bf16*)p)[idx] : ((const float*)p)[idx];
}

__device__ inline unsigned short f2bf(float f) {
    bf16 h = (bf16)f;
    return *(unsigned short*)&h;
}

// ---------------- K0: dtype detection ----------------
__global__ void dtype_detect(const void* __restrict__ seq, int* __restrict__ flag) {
    __shared__ int cnt;
    if (threadIdx.x == 0) cnt = 0;
    __syncthreads();
    const unsigned short* u = (const unsigned short*)seq;
    int bad = 0;
    for (int i = threadIdx.x; i < 1024; i += 256) {
        unsigned short e = (u[i] >> 7) & 0xFF;
        if (e >= 140) bad++;
    }
    atomicAdd(&cnt, bad);
    __syncthreads();
    if (threadIdx.x == 0) flag[0] = (cnt < 16) ? 1 : 0;   // 1 = bf16 inputs
}

// ---------------- K1: mentb (bf16) gather + ent_emb logsumexp over M ----------------
__global__ void ment_kernel(const void* __restrict__ seq, const int* __restrict__ entity_pos,
                            unsigned short* __restrict__ mentb, float* __restrict__ ent_emb,
                            const int* __restrict__ dtf) {
    int isbf = dtf[0];
    int be = blockIdx.x;            // b*E+e, 64 blocks
    int b = be >> 5;
    int pos[M_];
    for (int m = 0; m < M_; m++) pos[m] = entity_pos[be*M_+m] + 1;
    for (int d = threadIdx.x; d < D_; d += 256) {
        float x[M_];
        for (int m = 0; m < M_; m++) {
            x[m] = ldIn(seq, ((long)b*L_ + pos[m])*D_ + d, isbf);
            mentb[((long)be*M_ + m)*D_ + d] = f2bf(x[m]);
        }
        float mx = fmaxf(fmaxf(x[0],x[1]), fmaxf(x[2],x[3]));
        float s = expf(x[0]-mx)+expf(x[1]-mx)+expf(x[2]-mx)+expf(x[3]-mx);
        ent_emb[(long)be*D_ + d] = mx + logf(s);
    }
}

// ---------------- K2: ent_att = mean over M of gathered attn ----------------
__global__ void entatt_kernel(const void* __restrict__ attn, const int* __restrict__ entity_pos,
                              float* __restrict__ ent_att, const int* __restrict__ dtf) {
    int isbf = dtf[0];
    int beh = blockIdx.x;           // (b*E+e)*H+h, 768 blocks
    int h = beh % H_;
    int be = beh / H_;
    int b = be >> 5;
    int pos[M_];
    for (int m = 0; m < M_; m++) pos[m] = entity_pos[be*M_+m] + 1;
    for (int l = threadIdx.x; l < L_; l += 256) {
        float s = 0.f;
        for (int m = 0; m < M_; m++)
            s += ldIn(attn, (((long)(b*H_ + h))*L_ + pos[m])*L_ + l, isbf);
        ent_att[(long)beh*L_ + l] = 0.25f * s;
    }
}

// ---------------- K3: ht_att (bf16) = normalize_L( mean_H(ha*ta) ) ----------------
__global__ void htatt_kernel(const float* __restrict__ ent_att, const int* __restrict__ hts,
                             unsigned short* __restrict__ htb) {
    int bp = blockIdx.x;            // 512 blocks
    int b = bp >> 8;
    int h_e = hts[bp*2+0], t_e = hts[bp*2+1];
    const float* ea_h = ent_att + (long)((b*E_ + h_e)*H_)*L_;
    const float* ea_t = ent_att + (long)((b*E_ + t_e)*H_)*L_;
    __shared__ float red[256];
    float v[2];
    for (int t = 0; t < 2; t++) {
        int l = threadIdx.x + t*256;
        float s = 0.f;
        for (int h = 0; h < H_; h++) s += ea_h[h*L_+l] * ea_t[h*L_+l];
        v[t] = s * (1.0f/H_);
    }
    red[threadIdx.x] = v[0] + v[1];
    __syncthreads();
    for (int off = 128; off > 0; off >>= 1) {
        if (threadIdx.x < off) red[threadIdx.x] += red[threadIdx.x+off];
        __syncthreads();
    }
    float inv = 1.0f / (red[0] + 1e-5f);
    for (int t = 0; t < 2; t++) {
        int l = threadIdx.x + t*256;
        htb[(long)bp*L_ + l] = f2bf(v[t] * inv);
    }
}

// ---------------- transpose + bf16 convert: src[K][Ncols] -> dst[Npad][K] bf16 (zero pad) ----
// grid (K/32, Npad/32), block 256.
__global__ void wtrans_kernel(const void* __restrict__ src, long src_off, int K, int Ncols,
                              unsigned short* __restrict__ dst, const int* __restrict__ dtf) {
    int isbf = dtf[0];
    __shared__ float T[32][33];
    int k0 = blockIdx.x*32, n0 = blockIdx.y*32;
    int c = threadIdx.x & 31, r8 = threadIdx.x >> 5;
    for (int rr = 0; rr < 4; rr++) {
        int r = r8 + rr*8;
        int n = n0 + c;
        T[r][c] = (n < Ncols) ? ldIn(src, src_off + (long)(k0+r)*Ncols + n, isbf) : 0.f;
    }
    __syncthreads();
    for (int rr = 0; rr < 4; rr++) {
        int r = r8 + rr*8;
        dst[(long)(n0+r)*K + k0 + c] = f2bf(T[c][r]);
    }
}

// ---------------- catb: hcatb=[hs,rs], tcatb=[ts,rs] in bf16 ----------------
__global__ void catb_kernel(const float* __restrict__ ent_emb, const float* __restrict__ rs,
                            const int* __restrict__ hts,
                            unsigned short* __restrict__ hcatb, unsigned short* __restrict__ tcatb) {
    int n = blockIdx.x;             // 512
    int b = n >> 8;
    int h_e = hts[n*2+0], t_e = hts[n*2+1];
    const float* eh = ent_emb + (long)(b*E_ + h_e)*D_;
    const float* et = ent_emb + (long)(b*E_ + t_e)*D_;
    const float* r  = rs + (long)n*D_;
    for (int k = threadIdx.x; k < D_; k += 256) {
        hcatb[(long)n*1536 + k] = f2bf(eh[k]);
        tcatb[(long)n*1536 + k] = f2bf(et[k]);
        unsigned short rb = f2bf(r[k]);
        hcatb[(long)n*1536 + 768 + k] = rb;
        tcatb[(long)n*1536 + 768 + k] = rb;
    }
}

// ---------------- Generic MFMA GEMM: C[m][n] = act(A[m][:K] . Bt[n][:K] + bias[n]) ----------------
struct MfmaNT {
    const unsigned short* A[4];
    const unsigned short* Bt[4];
    const void* bias[4];
    void* C[4];
};

__global__ void mfma_nt_kernel(MfmaNT args, int K, int ldc, int act, int obf,
                               const int* __restrict__ dtf) {
    const unsigned short* A  = args.A[blockIdx.z];
    const unsigned short* Bt = args.Bt[blockIdx.z];
    const void* bias = args.bias[blockIdx.z];
    void* C = args.C[blockIdx.z];
    __shared__ unsigned short Al[64][72];
    __shared__ unsigned short Btl[64][72];
    int m0 = blockIdx.x*64, n0 = blockIdx.y*64;
    int tid = threadIdx.x, wave = tid>>6, lane = tid&63;
    int lm = lane&15, lq = lane>>4;
    f32x4 acc[4] = {};
    for (int k0 = 0; k0 < K; k0 += 64) {
        __syncthreads();
        for (int t = 0; t < 2; t++) {
            int idx = tid + t*256;
            int r = idx>>3, k8 = idx&7;
            *(uint4*)&Al[r][k8*8]  = *(const uint4*)(A  + (long)(m0+r)*K + k0 + k8*8);
            *(uint4*)&Btl[r][k8*8] = *(const uint4*)(Bt + (long)(n0+r)*K + k0 + k8*8);
        }
        __syncthreads();
        for (int half = 0; half < 2; half++) {
            bf16x8 af = *(bf16x8*)&Al[wave*16+lm][half*32+lq*8];
            #pragma unroll
            for (int ct = 0; ct < 4; ct++) {
                bf16x8 bfr = *(bf16x8*)&Btl[ct*16+lm][half*32+lq*8];
                acc[ct] = __builtin_amdgcn_mfma_f32_16x16x32_bf16(af, bfr, acc[ct], 0, 0, 0);
            }
        }
    }
    int isbf = dtf[0];
    for (int ct = 0; ct < 4; ct++) {
        int n = n0 + ct*16 + lm;
        float bia = bias ? ldIn(bias, n, isbf) : 0.f;
        for (int r = 0; r < 4; r++) {
            int m = m0 + wave*16 + lq*4 + r;
            float v = acc[ct][r] + bia;
            if (act == 1) v = tanhf(v);
            if (obf) ((unsigned short*)C)[(long)m*ldc + n] = f2bf(v);
            else     ((float*)C)[(long)m*ldc + n] = v;
        }
    }
}

// ---------------- Small fp32 GEMM (final projection only) ----------------
struct GemmArgs {
    const void* A[4];
    const void* Bm[4];
    const void* bias[4];
    void* Cc[4];
};

__global__ void gemm_generic(GemmArgs args, int lda, int a_in, int ldb, int b_in,
                             int ldc, int M, int N, int K, int act, int c_out,
                             const int* __restrict__ dtf) {
    int isbf = dtf[0];
    int af = a_in ? isbf : 0;
    int bfm = b_in ? isbf : 0;
    const void* A  = args.A[blockIdx.z];
    const void* Bm = args.Bm[blockIdx.z];
    const void* bias = args.bias[blockIdx.z];
    void* Cc = args.Cc[blockIdx.z];

    __shared__ float As[16][65];
    __shared__ float Bs[16][65];
    int m0 = blockIdx.x * 64, n0 = blockIdx.y * 64;
    int tx = threadIdx.x, ty = threadIdx.y;   // 16x16
    int tid = ty*16 + tx;
    float acc[4][4] = {};
    for (int k0 = 0; k0 < K; k0 += 16) {
        for (int t = 0; t < 4; t++) {
            int idx = tid + t*256;
            int rA = idx >> 4, kA = idx & 15;
            int m = m0 + rA, ka = k0 + kA;
            As[kA][rA] = (m < M && ka < K) ? ldIn(A, (long)m*lda + ka, af) : 0.f;
            int rB = idx & 63, kB = idx >> 6;
            int n = n0 + rB, kb = k0 + kB;
            Bs[kB][rB] = (kb < K && n < N) ? ldIn(Bm, (long)kb*ldb + n, bfm) : 0.f;
        }
        __syncthreads();
        for (int kk = 0; kk < 16; kk++) {
            float a[4], b[4];
            for (int i = 0; i < 4; i++) a[i] = As[kk][ty + 16*i];
            for (int j = 0; j < 4; j++) b[j] = Bs[kk][tx + 16*j];
            for (int i = 0; i < 4; i++)
                for (int j = 0; j < 4; j++) acc[i][j] += a[i]*b[j];
        }
        __syncthreads();
    }
    for (int i = 0; i < 4; i++) {
        int m = m0 + ty + 16*i;
        if (m >= M) continue;
        for (int j = 0; j < 4; j++) {
            int n = n0 + tx + 16*j;
            if (n >= N) continue;
            float v = acc[i][j];
            if (bias) v += ldIn(bias, n, isbf);
            if (act == 1) v = tanhf(v);
            if (c_out) {
                if (isbf) ((bf16*)Cc)[(long)m*ldc + n] = (bf16)v;
                else      ((float*)Cc)[(long)m*ldc + n] = v;
            } else {
                ((float*)Cc)[(long)m*ldc + n] = v;
            }
        }
    }
}

// ================= r1 via MFMA =================

__global__ void blgen_kernel(const float* __restrict__ hz, const float* __restrict__ tz,
                             unsigned short* __restrict__ BL) {
    int n = blockIdx.x;
    int k0 = (blockIdx.y*256 + threadIdx.x)*8;
    int gi = k0 >> 6;
    int g  = k0 >> 12;
    int j  = k0 & 63;
    float hv = hz[(long)n*EMB_ + gi];
    const float4* tp = (const float4*)(tz + (long)n*EMB_ + g*64 + j);
    float4 t0 = tp[0], t1 = tp[1];
    unsigned short o[8];
    o[0]=f2bf(hv*t0.x); o[1]=f2bf(hv*t0.y); o[2]=f2bf(hv*t0.z); o[3]=f2bf(hv*t0.w);
    o[4]=f2bf(hv*t1.x); o[5]=f2bf(hv*t1.y); o[6]=f2bf(hv*t1.z); o[7]=f2bf(hv*t1.w);
    *(uint4*)(BL + (long)n*KTOT_ + k0) = *(uint4*)o;
}

__global__ void wconv_kernel(const void* __restrict__ W_rel, unsigned short* __restrict__ WBt,
                             const int* __restrict__ dtf) {
    int isbf = dtf[0];
    __shared__ unsigned short T[CPAD_][136];
    int k0 = blockIdx.x * 128;
    int tid = threadIdx.x;
    for (int idx = tid; idx < 128*97; idx += 256) {
        int kk = idx / 97, c = idx % 97;
        T[c][kk] = f2bf(ldIn(W_rel, (long)(k0+kk)*C_ + c, isbf));
    }
    for (int idx = tid; idx < 15*128; idx += 256) {
        T[97 + (idx>>7)][idx & 127] = 0;
    }
    __syncthreads();
    for (int t = 0; t < 7; t++) {
        int idx = tid + t*256;
        int c = idx >> 4, kc = idx & 15;
        *(uint4*)(WBt + (long)c*KTOT_ + k0 + kc*8) = *(uint4*)&T[c][kc*8];
    }
}

__global__ void r1_mfma_kernel(const unsigned short* __restrict__ BL,
                               const unsigned short* __restrict__ WBt,
                               float* __restrict__ partial) {
    __shared__ unsigned short Al[64][72];
    __shared__ unsigned short Btl[CPAD_][72];
    int n0 = blockIdx.x * 64;
    int kbase = blockIdx.y * KCHUNK_;
    int tid = threadIdx.x;
    int wave = tid >> 6, lane = tid & 63;
    int lm = lane & 15, lq = lane >> 4;
    f32x4 acc[7] = {};
    for (int ks = 0; ks < KCHUNK_/64; ks++) {
        int k0 = kbase + ks*64;
        __syncthreads();
        for (int t = 0; t < 2; t++) {
            int idx = tid + t*256;
            int n = idx >> 3, k8 = idx & 7;
            *(uint4*)&Al[n][k8*8] = *(const uint4*)(BL + (long)(n0+n)*KTOT_ + k0 + k8*8);
        }
        for (int t = 0; t < 4; t++) {
            int idx = tid + t*256;
            if (idx < 896) {
                int c = idx >> 3, k8 = idx & 7;
                *(uint4*)&Btl[c][k8*8] = *(const uint4*)(WBt + (long)c*KTOT_ + k0 + k8*8);
            }
        }
        __syncthreads();
        for (int half = 0; half < 2; half++) {
            bf16x8 afrag = *(bf16x8*)&Al[wave*16 + lm][half*32 + lq*8];
            #pragma unroll
            for (int ct = 0; ct < 7; ct++) {
                bf16x8 bfrag = *(bf16x8*)&Btl[ct*16 + lm][half*32 + lq*8];
                acc[ct] = __builtin_amdgcn_mfma_f32_16x16x32_bf16(afrag, bfrag, acc[ct], 0, 0, 0);
            }
        }
    }
    float* dst = partial + ((long)blockIdx.y*512 + n0)*CPAD_;
    for (int ct = 0; ct < 7; ct++) {
        int c = ct*16 + lm;
        for (int r = 0; r < 4; r++) {
            int nl = wave*16 + lq*4 + r;
            dst[(long)nl*CPAD_ + c] = acc[ct][r];
        }
    }
}

__global__ void r1reduce_kernel(const float* __restrict__ partial, const void* __restrict__ b_rel,
                                float* __restrict__ r123, const int* __restrict__ dtf) {
    int n = blockIdx.x;
    int c = threadIdx.x;
    if (c >= C_) return;
    float s = 0.f;
    for (int kz = 0; kz < KSPLIT_; kz++)
        s += partial[((long)kz*512 + n)*CPAD_ + c];
    r123[(long)n*(3*C_) + c] = s + ldIn(b_rel, c, dtf[0]);
}

// ---------------- c2/c3 constants (parallel): grid C_, block 256 ----------------
__global__ void c23p_kernel(const void* __restrict__ b_f,
                            const void* __restrict__ W_unet, const void* __restrict__ b_unet,
                            const void* __restrict__ W_mlp,  const void* __restrict__ b_mlp,
                            float* __restrict__ c23, const int* __restrict__ dtf) {
    int isbf = dtf[0];
    int c = blockIdx.x;
    __shared__ float red2[256], red3[256];
    float s2 = 0.f, s3 = 0.f;
    for (int d = threadIdx.x; d < D_; d += 256) {
        float bf = ldIn(b_f, d, isbf);
        s2 += bf * ldIn(W_unet, (long)d*C_ + c, isbf);
        s3 += bf * ldIn(W_mlp,  (long)d*C_ + c, isbf);
    }
    red2[threadIdx.x] = s2; red3[threadIdx.x] = s3;
    __syncthreads();
    for (int off = 128; off > 0; off >>= 1) {
        if (threadIdx.x < off) {
            red2[threadIdx.x] += red2[threadIdx.x+off];
            red3[threadIdx.x] += red3[threadIdx.x+off];
        }
        __syncthreads();
    }
    if (threadIdx.x == 0) {
        c23[c]      = red2[0] + ldIn(b_unet, c, isbf);
        c23[C_ + c] = red3[0] + ldIn(b_mlp,  c, isbf);
    }
}

// ---------------- r2/r3: logsumexp over 16 (i,j) of tanh/gelu (mu ld=128) ----------------
__global__ void r23_kernel(const float* __restrict__ mu, const float* __restrict__ c23,
                           const int* __restrict__ hts, const int* __restrict__ mention_idx,
                           float* __restrict__ r123) {
    int bp = blockIdx.x;            // 512
    int b = bp >> 8;
    int c = threadIdx.x;
    if (c >= C_) return;
    int h_e = hts[bp*2+0], t_e = hts[bp*2+1];
    const float* mu2h = mu;                 // T_h @ W_unet
    const float* mu2t = mu + 32768;         // T_t @ W_unet
    const float* mu3h = mu + 65536;         // T_h @ W_mlp
    const float* mu3t = mu + 98304;         // T_t @ W_mlp
    float ah2[4], at2[4], ah3[4], at3[4];
    for (int m = 0; m < 4; m++) {
        int emh = mention_idx[(b*E_ + h_e)*M_ + m];
        int emt = mention_idx[(b*E_ + t_e)*M_ + m];
        ah2[m] = mu2h[(long)(b*128 + emh)*128 + c];
        ah3[m] = mu3h[(long)(b*128 + emh)*128 + c];
        at2[m] = mu2t[(long)(b*128 + emt)*128 + c];
        at3[m] = mu3t[(long)(b*128 + emt)*128 + c];
    }
    float c2 = c23[c], c3 = c23[C_ + c];
    float v2[16], v3[16];
    int q = 0;
    for (int i = 0; i < 4; i++) {
        for (int j = 0; j < 4; j++, q++) {
            float x2 = ah2[i] + at2[j] + c2;
            v2[q] = tanhf(x2);
            float x3 = ah3[i] + at3[j] + c3;
            float t = tanhf(0.7978845608028654f * (x3 + 0.044715f*x3*x3*x3));
            v3[q] = 0.5f * x3 * (1.0f + t);
        }
    }
    float m2 = v2[0], m3 = v3[0];
    for (q = 1; q < 16; q++) { m2 = fmaxf(m2, v2[q]); m3 = fmaxf(m3, v3[q]); }
    float s2 = 0.f, s3 = 0.f;
    for (q = 0; q < 16; q++) { s2 += expf(v2[q]-m2); s3 += expf(v3[q]-m3); }
    r123[(long)bp*(3*C_) + C_   + c] = m2 + logf(s2);
    r123[(long)bp*(3*C_) + 2*C_ + c] = m3 + logf(s3);
}

extern "C" void kernel_launch(void* const* d_in, const int* in_sizes, int n_in,
                              void* d_out, int out_size, void* d_ws, size_t ws_size,
                              hipStream_t stream) {
    const void* seq        = d_in[0];
    const void* attn       = d_in[1];
    const int*  entity_pos = (const int*)d_in[2];
    const int*  hts        = (const int*)d_in[3];
    const int*  mention_idx= (const int*)d_in[4];
    const void* W_head     = d_in[5];
    const void* b_head     = d_in[6];
    const void* W_tail     = d_in[7];
    const void* b_tail     = d_in[8];
    const void* W_rel      = d_in[9];
    const void* b_rel      = d_in[10];
    const void* W_fh       = d_in[11];
    const void* W_ft       = d_in[12];
    const void* b_f        = d_in[13];
    const void* W_unet     = d_in[14];
    const void* b_unet     = d_in[15];
    const void* W_mlp      = d_in[16];
    const void* b_mlp      = d_in[17];
    const void* W_bil      = d_in[18];
    const void* b_bil      = d_in[19];

    float* w = (float*)d_ws;
    int*   dtf      = (int*)w;                               // 64
    unsigned short* mentb = (unsigned short*)(w + 64);       // 256*768 sh = 98304 fl
    float* ent_emb  = w + 98368;                             // 49152
    float* ent_att  = w + 147520;                            // 393216
    unsigned short* htb = (unsigned short*)(w + 540736);     // 512*512 sh = 131072 fl
    float* rs       = w + 671808;                            // 393216
    float* hz       = w + 1065024;                           // 393216
    float* tz       = w + 1458240;                           // 393216
    float* r123     = w + 1851456;                           // 148992
    float* mu       = w + 2000448;                           // 4*256*128 = 131072
    float* c23      = w + 2131520;                           // 256
    unsigned short* seqT  = (unsigned short*)(w + 2131776);  // 2*768*512 sh = 393216 fl
    unsigned short* WhT   = (unsigned short*)(w + 2524992);  // 768*1536 sh = 589824 fl
    unsigned short* WtT   = (unsigned short*)(w + 3114816);  // 589824 fl
    unsigned short* WfhT  = (unsigned short*)(w + 3704640);  // 768*768 sh = 294912 fl
    unsigned short* WftT  = (unsigned short*)(w + 3999552);  // 294912 fl
    unsigned short* WunetT= (unsigned short*)(w + 4294464);  // 128*768 sh = 49152 fl
    unsigned short* WmlpT = (unsigned short*)(w + 4343616);  // 49152 fl
    unsigned short* Tbh   = (unsigned short*)(w + 4392768);  // 256*768 sh = 98304 fl
    unsigned short* Tbt   = (unsigned short*)(w + 4491072);  // 98304 fl
    unsigned short* hcatb = (unsigned short*)(w + 4589376);  // 512*1536 sh = 393216 fl
    unsigned short* tcatb = (unsigned short*)(w + 4982592);  // 393216 fl
    unsigned short* BL    = (unsigned short*)(w + 5375808);  // 512*49152 sh = 12582912 fl
    unsigned short* WBt   = (unsigned short*)(w + 17958720); // 112*49152 sh = 2752512 fl
    float* partial  = w + 20711232;                          // 32*512*112 = 1835008 -> end 22546240

    // 0. dtype detection
    dtype_detect<<<1, 256, 0, stream>>>(seq, dtf);
    // weight preprocessing (independent of activation chain)
    wconv_kernel<<<KTOT_/128, 256, 0, stream>>>(W_rel, WBt, dtf);
    wtrans_kernel<<<dim3(1536/32, 768/32), 256, 0, stream>>>(W_head, 0, 1536, 768, WhT, dtf);
    wtrans_kernel<<<dim3(1536/32, 768/32), 256, 0, stream>>>(W_tail, 0, 1536, 768, WtT, dtf);
    wtrans_kernel<<<dim3(768/32, 768/32), 256, 0, stream>>>(W_fh, 0, 768, 768, WfhT, dtf);
    wtrans_kernel<<<dim3(768/32, 768/32), 256, 0, stream>>>(W_ft, 0, 768, 768, WftT, dtf);
    wtrans_kernel<<<dim3(768/32, 128/32), 256, 0, stream>>>(W_unet, 0, 768, 97, WunetT, dtf);
    wtrans_kernel<<<dim3(768/32, 128/32), 256, 0, stream>>>(W_mlp,  0, 768, 97, WmlpT, dtf);
    wtrans_kernel<<<dim3(512/32, 768/32), 256, 0, stream>>>(seq, 0,      512, 768, seqT,          dtf);
    wtrans_kernel<<<dim3(512/32, 768/32), 256, 0, stream>>>(seq, 393216, 512, 768, seqT + 393216, dtf);
    // 1. mentions + entity embeddings
    ment_kernel<<<B_*E_, 256, 0, stream>>>(seq, entity_pos, mentb, ent_emb, dtf);
    // 2. entity attention
    entatt_kernel<<<B_*E_*H_, 256, 0, stream>>>(attn, entity_pos, ent_att, dtf);
    // 3. ht attention (normalized, bf16)
    htatt_kernel<<<N_, 256, 0, stream>>>(ent_att, hts, htb);
    // 4. rs = ht_att @ seq  (MFMA, per-batch via z)
    {
        MfmaNT ga = {};
        for (int z = 0; z < 2; z++) {
            ga.A[z]  = htb + (long)z*256*512;
            ga.Bt[z] = seqT + (long)z*393216;
            ga.bias[z] = nullptr;
            ga.C[z]  = rs + (long)z*256*768;
        }
        mfma_nt_kernel<<<dim3(4, 12, 2), 256, 0, stream>>>(ga, 512, 768, 0, 0, dtf);
    }
    // 5. concatenated inputs (bf16)
    catb_kernel<<<N_, 256, 0, stream>>>(ent_emb, rs, hts, hcatb, tcatb);
    // 6. hz/tz = tanh(cat @ W + b)  (MFMA, fused in z)
    {
        MfmaNT ga = {};
        ga.A[0] = hcatb; ga.Bt[0] = WhT; ga.bias[0] = b_head; ga.C[0] = hz;
        ga.A[1] = tcatb; ga.Bt[1] = WtT; ga.bias[1] = b_tail; ga.C[1] = tz;
        mfma_nt_kernel<<<dim3(8, 12, 2), 256, 0, stream>>>(ga, 1536, 768, 1, 0, dtf);
    }
    // 7. T_{h,t} = ment_flat @ W_f{h,t}  (MFMA, bf16 out)
    {
        MfmaNT ga = {};
        ga.A[0] = mentb; ga.Bt[0] = WfhT; ga.bias[0] = nullptr; ga.C[0] = Tbh;
        ga.A[1] = mentb; ga.Bt[1] = WftT; ga.bias[1] = nullptr; ga.C[1] = Tbt;
        mfma_nt_kernel<<<dim3(4, 12, 2), 256, 0, stream>>>(ga, 768, 768, 0, 1, dtf);
    }
    // 8. mu_q = T @ W_{unet,mlp}  (MFMA, N padded to 128)
    {
        MfmaNT ga = {};
        const unsigned short* As[4] = {Tbh, Tbt, Tbh, Tbt};
        const unsigned short* Bs[4] = {WunetT, WunetT, WmlpT, WmlpT};
        for (int q = 0; q < 4; q++) {
            ga.A[q] = As[q]; ga.Bt[q] = Bs[q]; ga.bias[q] = nullptr;
            ga.C[q] = mu + q*32768;
        }
        mfma_nt_kernel<<<dim3(4, 2, 4), 256, 0, stream>>>(ga, 768, 128, 0, 0, dtf);
    }
    // 9. c2/c3 constants (parallel)
    c23p_kernel<<<C_, 256, 0, stream>>>(b_f, W_unet, b_unet, W_mlp, b_mlp, c23, dtf);
    // 10. r1 via MFMA
    blgen_kernel<<<dim3(N_, KTOT_/(256*8)), 256, 0, stream>>>(hz, tz, BL);
    r1_mfma_kernel<<<dim3(8, KSPLIT_), 256, 0, stream>>>(BL, WBt, partial);
    r1reduce_kernel<<<N_, 128, 0, stream>>>(partial, b_rel, r123, dtf);
    // 12. r2/r3
    r23_kernel<<<N_, 128, 0, stream>>>(mu, c23, hts, mention_idx, r123);
    // 13. final: out = r123 @ W_bil + b_bil
    {
        GemmArgs ga = {};
        ga.A[0] = r123; ga.Bm[0] = W_bil; ga.bias[0] = b_bil; ga.Cc[0] = d_out;
        gemm_generic<<<dim3(8,2,1), dim3(16,16), 0, stream>>>(ga, 3*C_, 0, 97, 1, 97, N_, C_, 3*C_, 0, 1, dtf);
    }
}

// Round 6
// 345.345 us; speedup vs baseline: 7.5462x; 1.2475x over previous
//
#include <hip/hip_runtime.h>
#include <hip/hip_bf16.h>

// Problem constants
#define B_  2
#define L_  512
#define D_  768
#define H_  12
#define E_  32
#define M_  4
#define P_  256
#define EMB_ 768
#define BS_ 64
#define C_  97
#define N_  (B_*P_)   // 512

#define KTOT_    49152      // EMB*BS
#define CPAD_    112        // 97 padded to 7*16
#define KSPLIT_  64
#define KCHUNK_  (KTOT_/KSPLIT_)   // 768, 12 ks-steps of 64

typedef __hip_bfloat16 bf16;
typedef __attribute__((ext_vector_type(8))) short bf16x8;
typedef __attribute__((ext_vector_type(4))) float f32x4;

__device__ inline float ldIn(const void* p, long idx, int isbf) {
    return isbf ? (float)((const bf16*)p)[idx] : ((const float*)p)[idx];
}

__device__ inline unsigned short f2bf(float f) {
    bf16 h = (bf16)f;
    return *(unsigned short*)&h;
}

__device__ inline float bf2f(unsigned short u) {
    bf16 h = *(bf16*)&u;
    return (float)h;
}

// ---------------- K0: dtype detection ----------------
__global__ void dtype_detect(const void* __restrict__ seq, int* __restrict__ flag) {
    __shared__ int cnt;
    if (threadIdx.x == 0) cnt = 0;
    __syncthreads();
    const unsigned short* u = (const unsigned short*)seq;
    int bad = 0;
    for (int i = threadIdx.x; i < 1024; i += 256) {
        unsigned short e = (u[i] >> 7) & 0xFF;
        if (e >= 140) bad++;
    }
    atomicAdd(&cnt, bad);
    __syncthreads();
    if (threadIdx.x == 0) flag[0] = (cnt < 16) ? 1 : 0;   // 1 = bf16 inputs
}

// ---------------- K1: mentb (bf16) gather + ent_emb logsumexp over M ----------------
__global__ void ment_kernel(const void* __restrict__ seq, const int* __restrict__ entity_pos,
                            unsigned short* __restrict__ mentb, float* __restrict__ ent_emb,
                            const int* __restrict__ dtf) {
    int isbf = dtf[0];
    int be = blockIdx.x;            // b*E+e, 64 blocks
    int b = be >> 5;
    int pos[M_];
    for (int m = 0; m < M_; m++) pos[m] = entity_pos[be*M_+m] + 1;
    for (int d = threadIdx.x; d < D_; d += 256) {
        float x[M_];
        for (int m = 0; m < M_; m++) {
            x[m] = ldIn(seq, ((long)b*L_ + pos[m])*D_ + d, isbf);
            mentb[((long)be*M_ + m)*D_ + d] = f2bf(x[m]);
        }
        float mx = fmaxf(fmaxf(x[0],x[1]), fmaxf(x[2],x[3]));
        float s = expf(x[0]-mx)+expf(x[1]-mx)+expf(x[2]-mx)+expf(x[3]-mx);
        ent_emb[(long)be*D_ + d] = mx + logf(s);
    }
}

// ---------------- K2: ent_att = mean over M of gathered attn ----------------
__global__ void entatt_kernel(const void* __restrict__ attn, const int* __restrict__ entity_pos,
                              float* __restrict__ ent_att, const int* __restrict__ dtf) {
    int isbf = dtf[0];
    int beh = blockIdx.x;           // (b*E+e)*H+h, 768 blocks
    int h = beh % H_;
    int be = beh / H_;
    int b = be >> 5;
    int pos[M_];
    for (int m = 0; m < M_; m++) pos[m] = entity_pos[be*M_+m] + 1;
    for (int l = threadIdx.x; l < L_; l += 256) {
        float s = 0.f;
        for (int m = 0; m < M_; m++)
            s += ldIn(attn, (((long)(b*H_ + h))*L_ + pos[m])*L_ + l, isbf);
        ent_att[(long)beh*L_ + l] = 0.25f * s;
    }
}

// ---------------- K3: ht_att (bf16) = normalize_L( mean_H(ha*ta) ) ----------------
__global__ void htatt_kernel(const float* __restrict__ ent_att, const int* __restrict__ hts,
                             unsigned short* __restrict__ htb) {
    int bp = blockIdx.x;            // 512 blocks
    int b = bp >> 8;
    int h_e = hts[bp*2+0], t_e = hts[bp*2+1];
    const float* ea_h = ent_att + (long)((b*E_ + h_e)*H_)*L_;
    const float* ea_t = ent_att + (long)((b*E_ + t_e)*H_)*L_;
    __shared__ float red[256];
    float v[2];
    for (int t = 0; t < 2; t++) {
        int l = threadIdx.x + t*256;
        float s = 0.f;
        for (int h = 0; h < H_; h++) s += ea_h[h*L_+l] * ea_t[h*L_+l];
        v[t] = s * (1.0f/H_);
    }
    red[threadIdx.x] = v[0] + v[1];
    __syncthreads();
    for (int off = 128; off > 0; off >>= 1) {
        if (threadIdx.x < off) red[threadIdx.x] += red[threadIdx.x+off];
        __syncthreads();
    }
    float inv = 1.0f / (red[0] + 1e-5f);
    for (int t = 0; t < 2; t++) {
        int l = threadIdx.x + t*256;
        htb[(long)bp*L_ + l] = f2bf(v[t] * inv);
    }
}

// ---------------- batched transpose + bf16 convert: src[K][Ncols] -> dst[Npad][K] bf16 ----
struct WT8 {
    const void* src[8];
    long off[8];
    int K[8];
    int Ncols[8];
    int Npad[8];
    unsigned short* dst[8];
};

__global__ void wtrans8_kernel(WT8 a, const int* __restrict__ dtf) {
    int z = blockIdx.z;
    int K = a.K[z], Ncols = a.Ncols[z], Npad = a.Npad[z];
    int k0 = blockIdx.x*32, n0 = blockIdx.y*32;
    if (k0 >= K || n0 >= Npad) return;
    const void* src = a.src[z];
    long off = a.off[z];
    unsigned short* dst = a.dst[z];
    int isbf = dtf[0];
    __shared__ float T[32][33];
    int c = threadIdx.x & 31, r8 = threadIdx.x >> 5;
    for (int rr = 0; rr < 4; rr++) {
        int r = r8 + rr*8;
        int n = n0 + c;
        T[r][c] = (n < Ncols) ? ldIn(src, off + (long)(k0+r)*Ncols + n, isbf) : 0.f;
    }
    __syncthreads();
    for (int rr = 0; rr < 4; rr++) {
        int r = r8 + rr*8;
        dst[(long)(n0+r)*K + k0 + c] = f2bf(T[c][r]);
    }
}

// ---------------- catb: hcatb=[hs,rs], tcatb=[ts,rs] in bf16 ----------------
__global__ void catb_kernel(const float* __restrict__ ent_emb, const float* __restrict__ rs,
                            const int* __restrict__ hts,
                            unsigned short* __restrict__ hcatb, unsigned short* __restrict__ tcatb) {
    int n = blockIdx.x;             // 512
    int b = n >> 8;
    int h_e = hts[n*2+0], t_e = hts[n*2+1];
    const float* eh = ent_emb + (long)(b*E_ + h_e)*D_;
    const float* et = ent_emb + (long)(b*E_ + t_e)*D_;
    const float* r  = rs + (long)n*D_;
    for (int k = threadIdx.x; k < D_; k += 256) {
        hcatb[(long)n*1536 + k] = f2bf(eh[k]);
        tcatb[(long)n*1536 + k] = f2bf(et[k]);
        unsigned short rb = f2bf(r[k]);
        hcatb[(long)n*1536 + 768 + k] = rb;
        tcatb[(long)n*1536 + 768 + k] = rb;
    }
}

// ---------------- Generic MFMA GEMM: C[m][n] = act(A[m][:K] . Bt[n][:K] + bias[n]) ----------------
struct MfmaNT {
    const unsigned short* A[4];
    const unsigned short* Bt[4];
    const void* bias[4];
    void* C[4];
};

__global__ void mfma_nt_kernel(MfmaNT args, int K, int ldc, int act, int obf,
                               const int* __restrict__ dtf) {
    const unsigned short* A  = args.A[blockIdx.z];
    const unsigned short* Bt = args.Bt[blockIdx.z];
    const void* bias = args.bias[blockIdx.z];
    void* C = args.C[blockIdx.z];
    __shared__ unsigned short Al[64][72];
    __shared__ unsigned short Btl[64][72];
    int m0 = blockIdx.x*64, n0 = blockIdx.y*64;
    int tid = threadIdx.x, wave = tid>>6, lane = tid&63;
    int lm = lane&15, lq = lane>>4;
    f32x4 acc[4] = {};
    for (int k0 = 0; k0 < K; k0 += 64) {
        __syncthreads();
        for (int t = 0; t < 2; t++) {
            int idx = tid + t*256;
            int r = idx>>3, k8 = idx&7;
            *(uint4*)&Al[r][k8*8]  = *(const uint4*)(A  + (long)(m0+r)*K + k0 + k8*8);
            *(uint4*)&Btl[r][k8*8] = *(const uint4*)(Bt + (long)(n0+r)*K + k0 + k8*8);
        }
        __syncthreads();
        for (int half = 0; half < 2; half++) {
            bf16x8 af = *(bf16x8*)&Al[wave*16+lm][half*32+lq*8];
            #pragma unroll
            for (int ct = 0; ct < 4; ct++) {
                bf16x8 bfr = *(bf16x8*)&Btl[ct*16+lm][half*32+lq*8];
                acc[ct] = __builtin_amdgcn_mfma_f32_16x16x32_bf16(af, bfr, acc[ct], 0, 0, 0);
            }
        }
    }
    int isbf = dtf[0];
    for (int ct = 0; ct < 4; ct++) {
        int n = n0 + ct*16 + lm;
        float bia = bias ? ldIn(bias, n, isbf) : 0.f;
        for (int r = 0; r < 4; r++) {
            int m = m0 + wave*16 + lq*4 + r;
            float v = acc[ct][r] + bia;
            if (act == 1) v = tanhf(v);
            if (obf) ((unsigned short*)C)[(long)m*ldc + n] = f2bf(v);
            else     ((float*)C)[(long)m*ldc + n] = v;
        }
    }
}

// ================= r1 via MFMA with on-the-fly A generation =================
// BL[n][k] = hz[n][k>>6] * tz[n][(k>>12)*64 + (k&63)]; each 64-k tile is rank-1.
// grid (8 n-tiles, KSPLIT_), block 256.
__global__ void wconv_kernel(const void* __restrict__ W_rel, unsigned short* __restrict__ WBt,
                             const int* __restrict__ dtf) {
    int isbf = dtf[0];
    __shared__ unsigned short T[CPAD_][136];
    int k0 = blockIdx.x * 128;
    int tid = threadIdx.x;
    for (int idx = tid; idx < 128*97; idx += 256) {
        int kk = idx / 97, c = idx % 97;
        T[c][kk] = f2bf(ldIn(W_rel, (long)(k0+kk)*C_ + c, isbf));
    }
    for (int idx = tid; idx < 15*128; idx += 256) {
        T[97 + (idx>>7)][idx & 127] = 0;
    }
    __syncthreads();
    for (int t = 0; t < 7; t++) {
        int idx = tid + t*256;
        int c = idx >> 4, kc = idx & 15;
        *(uint4*)(WBt + (long)c*KTOT_ + k0 + kc*8) = *(uint4*)&T[c][kc*8];
    }
}

__global__ void r1_mfma_kernel(const float* __restrict__ hz, const float* __restrict__ tz,
                               const unsigned short* __restrict__ WBt,
                               float* __restrict__ partial) {
    __shared__ float hzL[64][13];             // hz[n0+n][gi0+ks], ks<12
    __shared__ unsigned short tzbL[64][136];  // two g-rows of tz (bf16)
    __shared__ unsigned short Btl[CPAD_][72];
    int n0 = blockIdx.x * 64;
    int kz = blockIdx.y;
    int kbase = kz * KCHUNK_;
    int gi0 = kbase >> 6;                     // = kz*12
    int g0 = kbase >> 12;
    int g1 = min(g0 + 1, EMB_/64 - 1);        // clamp (unused rows read in-range)
    int tid = threadIdx.x;
    int wave = tid >> 6, lane = tid & 63;
    int lm = lane & 15, lq = lane >> 4;

    // stage hz slice: 64 n x 12 gi
    for (int t = 0; t < 4; t++) {
        int id = tid + t*256;                 // < 1024
        int n = id >> 4, q = id & 15;
        if (q < 12) hzL[n][q] = hz[(long)(n0+n)*EMB_ + gi0 + q];
    }
    // stage tz rows g0,g1: 64 n x 128 cols (f32 -> bf16)
    for (int t = 0; t < 8; t++) {
        int id = tid + t*256;                 // < 2048 float4s
        int n = id >> 5, c4 = (id & 31) * 4;
        int gcol = (c4 < 64) ? (g0*64 + c4) : (g1*64 + c4 - 64);
        float4 v = *(const float4*)(tz + (long)(n0+n)*EMB_ + gcol);
        unsigned short o[4] = {f2bf(v.x), f2bf(v.y), f2bf(v.z), f2bf(v.w)};
        *(uint2*)&tzbL[n][c4] = *(uint2*)o;
    }

    f32x4 acc[7] = {};
    for (int ks = 0; ks < KCHUNK_/64; ks++) {
        int k0 = kbase + ks*64;
        int gsel = ((k0 >> 12) > g0) ? 64 : 0;
        __syncthreads();
        // stage B: 112 c x 64 k
        for (int t = 0; t < 4; t++) {
            int idx = tid + t*256;
            if (idx < 896) {
                int c = idx >> 3, k8 = idx & 7;
                *(uint4*)&Btl[c][k8*8] = *(const uint4*)(WBt + (long)c*KTOT_ + k0 + k8*8);
            }
        }
        __syncthreads();
        float hv = hzL[wave*16 + lm][ks];
        for (int half = 0; half < 2; half++) {
            bf16x8 tzf = *(bf16x8*)&tzbL[wave*16 + lm][gsel + half*32 + lq*8];
            unsigned short o[8];
            #pragma unroll
            for (int e = 0; e < 8; e++)
                o[e] = f2bf(bf2f(((unsigned short*)&tzf)[e]) * hv);
            bf16x8 afrag = *(bf16x8*)o;
            #pragma unroll
            for (int ct = 0; ct < 7; ct++) {
                bf16x8 bfrag = *(bf16x8*)&Btl[ct*16 + lm][half*32 + lq*8];
                acc[ct] = __builtin_amdgcn_mfma_f32_16x16x32_bf16(afrag, bfrag, acc[ct], 0, 0, 0);
            }
        }
    }
    float* dst = partial + ((long)kz*512 + n0)*CPAD_;
    for (int ct = 0; ct < 7; ct++) {
        int c = ct*16 + lm;
        for (int r = 0; r < 4; r++) {
            int nl = wave*16 + lq*4 + r;
            dst[(long)nl*CPAD_ + c] = acc[ct][r];
        }
    }
}

// ---------------- c2/c3 constants (parallel): grid C_, block 256 ----------------
__global__ void c23p_kernel(const void* __restrict__ b_f,
                            const void* __restrict__ W_unet, const void* __restrict__ b_unet,
                            const void* __restrict__ W_mlp,  const void* __restrict__ b_mlp,
                            float* __restrict__ c23, const int* __restrict__ dtf) {
    int isbf = dtf[0];
    int c = blockIdx.x;
    __shared__ float red2[256], red3[256];
    float s2 = 0.f, s3 = 0.f;
    for (int d = threadIdx.x; d < D_; d += 256) {
        float bf = ldIn(b_f, d, isbf);
        s2 += bf * ldIn(W_unet, (long)d*C_ + c, isbf);
        s3 += bf * ldIn(W_mlp,  (long)d*C_ + c, isbf);
    }
    red2[threadIdx.x] = s2; red3[threadIdx.x] = s3;
    __syncthreads();
    for (int off = 128; off > 0; off >>= 1) {
        if (threadIdx.x < off) {
            red2[threadIdx.x] += red2[threadIdx.x+off];
            red3[threadIdx.x] += red3[threadIdx.x+off];
        }
        __syncthreads();
    }
    if (threadIdx.x == 0) {
        c23[c]      = red2[0] + ldIn(b_unet, c, isbf);
        c23[C_ + c] = red3[0] + ldIn(b_mlp,  c, isbf);
    }
}

// ---------------- fused: r1 split-K reduce + r2/r3 LSE + final projection ----------------
// grid 512 (one per row n), block 128 (c = tid)
__global__ void r23out_kernel(const float* __restrict__ partial, const void* __restrict__ b_rel,
                              const float* __restrict__ mu, const float* __restrict__ c23,
                              const int* __restrict__ hts, const int* __restrict__ mention_idx,
                              const void* __restrict__ W_bil, const void* __restrict__ b_bil,
                              void* __restrict__ out, const int* __restrict__ dtf) {
    int bp = blockIdx.x;
    int b = bp >> 8;
    int c = threadIdx.x;
    int isbf = dtf[0];
    __shared__ float row[292];
    if (c < C_) {
        // r1: reduce split-K partials
        float r1v = 0.f;
        for (int kz = 0; kz < KSPLIT_; kz++)
            r1v += partial[((long)kz*512 + bp)*CPAD_ + c];
        r1v += ldIn(b_rel, c, isbf);
        // r2/r3
        int h_e = hts[bp*2+0], t_e = hts[bp*2+1];
        const float* mu2h = mu;
        const float* mu2t = mu + 32768;
        const float* mu3h = mu + 65536;
        const float* mu3t = mu + 98304;
        float ah2[4], at2[4], ah3[4], at3[4];
        for (int m = 0; m < 4; m++) {
            int emh = mention_idx[(b*E_ + h_e)*M_ + m];
            int emt = mention_idx[(b*E_ + t_e)*M_ + m];
            ah2[m] = mu2h[(long)(b*128 + emh)*128 + c];
            ah3[m] = mu3h[(long)(b*128 + emh)*128 + c];
            at2[m] = mu2t[(long)(b*128 + emt)*128 + c];
            at3[m] = mu3t[(long)(b*128 + emt)*128 + c];
        }
        float c2 = c23[c], c3 = c23[C_ + c];
        float v2[16], v3[16];
        int q = 0;
        for (int i = 0; i < 4; i++) {
            for (int j = 0; j < 4; j++, q++) {
                float x2 = ah2[i] + at2[j] + c2;
                v2[q] = tanhf(x2);
                float x3 = ah3[i] + at3[j] + c3;
                float t = tanhf(0.7978845608028654f * (x3 + 0.044715f*x3*x3*x3));
                v3[q] = 0.5f * x3 * (1.0f + t);
            }
        }
        float m2 = v2[0], m3 = v3[0];
        for (q = 1; q < 16; q++) { m2 = fmaxf(m2, v2[q]); m3 = fmaxf(m3, v3[q]); }
        float s2 = 0.f, s3 = 0.f;
        for (q = 0; q < 16; q++) { s2 += expf(v2[q]-m2); s3 += expf(v3[q]-m3); }
        row[c]        = r1v;
        row[C_ + c]   = m2 + logf(s2);
        row[2*C_ + c] = m3 + logf(s3);
    }
    __syncthreads();
    if (c >= C_) return;
    // out[bp][c] = row . W_bil[:,c] + b_bil[c]
    float a0 = 0.f, a1 = 0.f, a2 = 0.f, a3 = 0.f;
    for (int k = 0; k < 288; k += 4) {
        a0 += row[k+0] * ldIn(W_bil, (long)(k+0)*C_ + c, isbf);
        a1 += row[k+1] * ldIn(W_bil, (long)(k+1)*C_ + c, isbf);
        a2 += row[k+2] * ldIn(W_bil, (long)(k+2)*C_ + c, isbf);
        a3 += row[k+3] * ldIn(W_bil, (long)(k+3)*C_ + c, isbf);
    }
    a0 += row[288] * ldIn(W_bil, (long)288*C_ + c, isbf);
    a1 += row[289] * ldIn(W_bil, (long)289*C_ + c, isbf);
    a2 += row[290] * ldIn(W_bil, (long)290*C_ + c, isbf);
    float v = a0 + a1 + a2 + a3 + ldIn(b_bil, c, isbf);
    if (isbf) ((bf16*)out)[(long)bp*C_ + c] = (bf16)v;
    else      ((float*)out)[(long)bp*C_ + c] = v;
}

extern "C" void kernel_launch(void* const* d_in, const int* in_sizes, int n_in,
                              void* d_out, int out_size, void* d_ws, size_t ws_size,
                              hipStream_t stream) {
    const void* seq        = d_in[0];
    const void* attn       = d_in[1];
    const int*  entity_pos = (const int*)d_in[2];
    const int*  hts        = (const int*)d_in[3];
    const int*  mention_idx= (const int*)d_in[4];
    const void* W_head     = d_in[5];
    const void* b_head     = d_in[6];
    const void* W_tail     = d_in[7];
    const void* b_tail     = d_in[8];
    const void* W_rel      = d_in[9];
    const void* b_rel      = d_in[10];
    const void* W_fh       = d_in[11];
    const void* W_ft       = d_in[12];
    const void* b_f        = d_in[13];
    const void* W_unet     = d_in[14];
    const void* b_unet     = d_in[15];
    const void* W_mlp      = d_in[16];
    const void* b_mlp      = d_in[17];
    const void* W_bil      = d_in[18];
    const void* b_bil      = d_in[19];

    float* w = (float*)d_ws;
    int*   dtf      = (int*)w;                               // 64
    unsigned short* mentb = (unsigned short*)(w + 64);       // 98304 fl
    float* ent_emb  = w + 98368;                             // 49152
    float* ent_att  = w + 147520;                            // 393216
    unsigned short* htb = (unsigned short*)(w + 540736);     // 131072 fl
    float* rs       = w + 671808;                            // 393216
    float* hz       = w + 1065024;                           // 393216
    float* tz       = w + 1458240;                           // 393216
    float* mu       = w + 1851456;                           // 131072
    float* c23      = w + 1982528;                           // 256
    unsigned short* seqT  = (unsigned short*)(w + 1982784);  // 393216 fl
    unsigned short* WhT   = (unsigned short*)(w + 2376000);  // 589824 fl
    unsigned short* WtT   = (unsigned short*)(w + 2965824);  // 589824 fl
    unsigned short* WfhT  = (unsigned short*)(w + 3555648);  // 294912 fl
    unsigned short* WftT  = (unsigned short*)(w + 3850560);  // 294912 fl
    unsigned short* WunetT= (unsigned short*)(w + 4145472);  // 49152 fl
    unsigned short* WmlpT = (unsigned short*)(w + 4194624);  // 49152 fl
    unsigned short* Tbh   = (unsigned short*)(w + 4243776);  // 98304 fl
    unsigned short* Tbt   = (unsigned short*)(w + 4342080);  // 98304 fl
    unsigned short* hcatb = (unsigned short*)(w + 4440384);  // 393216 fl
    unsigned short* tcatb = (unsigned short*)(w + 4833600);  // 393216 fl
    unsigned short* WBt   = (unsigned short*)(w + 5226816);  // 2752512 fl
    float* partial  = w + 7979328;                           // 64*512*112 = 3670016 -> end 11649344

    // 0. dtype detection
    dtype_detect<<<1, 256, 0, stream>>>(seq, dtf);
    // weight preprocessing
    wconv_kernel<<<KTOT_/128, 256, 0, stream>>>(W_rel, WBt, dtf);
    {
        WT8 a = {};
        // z: 0 WhT, 1 WtT, 2 WfhT, 3 WftT, 4 WunetT, 5 WmlpT, 6 seqT b0, 7 seqT b1
        const void* srcs[8] = {W_head, W_tail, W_fh, W_ft, W_unet, W_mlp, seq, seq};
        long offs[8]   = {0,0,0,0,0,0,0,393216};
        int Ks[8]      = {1536,1536,768,768,768,768,512,512};
        int Ncols8[8]  = {768,768,768,768,97,97,768,768};
        int Npads[8]   = {768,768,768,768,128,128,768,768};
        unsigned short* dsts[8] = {WhT, WtT, WfhT, WftT, WunetT, WmlpT, seqT, seqT+393216};
        for (int z = 0; z < 8; z++) {
            a.src[z]=srcs[z]; a.off[z]=offs[z]; a.K[z]=Ks[z];
            a.Ncols[z]=Ncols8[z]; a.Npad[z]=Npads[z]; a.dst[z]=dsts[z];
        }
        wtrans8_kernel<<<dim3(48, 24, 8), 256, 0, stream>>>(a, dtf);
    }
    // 1. mentions + entity embeddings
    ment_kernel<<<B_*E_, 256, 0, stream>>>(seq, entity_pos, mentb, ent_emb, dtf);
    // 2. entity attention
    entatt_kernel<<<B_*E_*H_, 256, 0, stream>>>(attn, entity_pos, ent_att, dtf);
    // 3. ht attention (normalized, bf16)
    htatt_kernel<<<N_, 256, 0, stream>>>(ent_att, hts, htb);
    // 4. rs = ht_att @ seq  (MFMA, per-batch via z)
    {
        MfmaNT ga = {};
        for (int z = 0; z < 2; z++) {
            ga.A[z]  = htb + (long)z*256*512;
            ga.Bt[z] = seqT + (long)z*393216;
            ga.bias[z] = nullptr;
            ga.C[z]  = rs + (long)z*256*768;
        }
        mfma_nt_kernel<<<dim3(4, 12, 2), 256, 0, stream>>>(ga, 512, 768, 0, 0, dtf);
    }
    // 5. concatenated inputs (bf16)
    catb_kernel<<<N_, 256, 0, stream>>>(ent_emb, rs, hts, hcatb, tcatb);
    // 6. hz/tz = tanh(cat @ W + b)  (MFMA)
    {
        MfmaNT ga = {};
        ga.A[0] = hcatb; ga.Bt[0] = WhT; ga.bias[0] = b_head; ga.C[0] = hz;
        ga.A[1] = tcatb; ga.Bt[1] = WtT; ga.bias[1] = b_tail; ga.C[1] = tz;
        mfma_nt_kernel<<<dim3(8, 12, 2), 256, 0, stream>>>(ga, 1536, 768, 1, 0, dtf);
    }
    // 7. T_{h,t} = ment_flat @ W_f{h,t}  (MFMA, bf16 out)
    {
        MfmaNT ga = {};
        ga.A[0] = mentb; ga.Bt[0] = WfhT; ga.bias[0] = nullptr; ga.C[0] = Tbh;
        ga.A[1] = mentb; ga.Bt[1] = WftT; ga.bias[1] = nullptr; ga.C[1] = Tbt;
        mfma_nt_kernel<<<dim3(4, 12, 2), 256, 0, stream>>>(ga, 768, 768, 0, 1, dtf);
    }
    // 8. mu_q = T @ W_{unet,mlp}  (MFMA, N padded to 128)
    {
        MfmaNT ga = {};
        const unsigned short* As[4] = {Tbh, Tbt, Tbh, Tbt};
        const unsigned short* Bs[4] = {WunetT, WunetT, WmlpT, WmlpT};
        for (int q = 0; q < 4; q++) {
            ga.A[q] = As[q]; ga.Bt[q] = Bs[q]; ga.bias[q] = nullptr;
            ga.C[q] = mu + q*32768;
        }
        mfma_nt_kernel<<<dim3(4, 2, 4), 256, 0, stream>>>(ga, 768, 128, 0, 0, dtf);
    }
    // 9. c2/c3 constants
    c23p_kernel<<<C_, 256, 0, stream>>>(b_f, W_unet, b_unet, W_mlp, b_mlp, c23, dtf);
    // 10. r1 partials via MFMA (A generated on the fly from hz/tz)
    r1_mfma_kernel<<<dim3(8, KSPLIT_), 256, 0, stream>>>(hz, tz, WBt, partial);
    // 11. fused reduce + r2/r3 + final projection
    r23out_kernel<<<N_, 128, 0, stream>>>(partial, b_rel, mu, c23, hts, mention_idx,
                                          W_bil, b_bil, d_out, dtf);
}

// Round 7
// 325.522 us; speedup vs baseline: 8.0058x; 1.0609x over previous
//
#include <hip/hip_runtime.h>
#include <hip/hip_bf16.h>

// Problem constants
#define B_  2
#define L_  512
#define D_  768
#define H_  12
#define E_  32
#define M_  4
#define P_  256
#define EMB_ 768
#define BS_ 64
#define C_  97
#define N_  (B_*P_)   // 512

#define KTOT_    49152      // EMB*BS
#define CPAD_    112        // 97 padded to 7*16
#define KSPLIT_  64
#define KCHUNK_  (KTOT_/KSPLIT_)   // 768, 12 ks-steps of 64

typedef __hip_bfloat16 bf16;
typedef __attribute__((ext_vector_type(8))) short bf16x8;
typedef __attribute__((ext_vector_type(4))) float f32x4;

__device__ inline float ldIn(const void* p, long idx, int isbf) {
    return isbf ? (float)((const bf16*)p)[idx] : ((const float*)p)[idx];
}

__device__ inline unsigned short f2bf(float f) {
    bf16 h = (bf16)f;
    return *(unsigned short*)&h;
}

__device__ inline float bf2f(unsigned short u) {
    bf16 h = *(bf16*)&u;
    return (float)h;
}

// ---------------- K0: dtype detection ----------------
__global__ void dtype_detect(const void* __restrict__ seq, int* __restrict__ flag) {
    __shared__ int cnt;
    if (threadIdx.x == 0) cnt = 0;
    __syncthreads();
    const unsigned short* u = (const unsigned short*)seq;
    int bad = 0;
    for (int i = threadIdx.x; i < 1024; i += 256) {
        unsigned short e = (u[i] >> 7) & 0xFF;
        if (e >= 140) bad++;
    }
    atomicAdd(&cnt, bad);
    __syncthreads();
    if (threadIdx.x == 0) flag[0] = (cnt < 16) ? 1 : 0;   // 1 = bf16 inputs
}

// ---------------- K1: mentb (bf16) gather + ent_emb logsumexp over M ----------------
__global__ void ment_kernel(const void* __restrict__ seq, const int* __restrict__ entity_pos,
                            unsigned short* __restrict__ mentb, float* __restrict__ ent_emb,
                            const int* __restrict__ dtf) {
    int isbf = dtf[0];
    int be = blockIdx.x;            // b*E+e, 64 blocks
    int b = be >> 5;
    int pos[M_];
    for (int m = 0; m < M_; m++) pos[m] = entity_pos[be*M_+m] + 1;
    for (int d = threadIdx.x; d < D_; d += 256) {
        float x[M_];
        for (int m = 0; m < M_; m++) {
            x[m] = ldIn(seq, ((long)b*L_ + pos[m])*D_ + d, isbf);
            mentb[((long)be*M_ + m)*D_ + d] = f2bf(x[m]);
        }
        float mx = fmaxf(fmaxf(x[0],x[1]), fmaxf(x[2],x[3]));
        float s = expf(x[0]-mx)+expf(x[1]-mx)+expf(x[2]-mx)+expf(x[3]-mx);
        ent_emb[(long)be*D_ + d] = mx + logf(s);
    }
}

// ---------------- K2: ent_att = mean over M of gathered attn ----------------
__global__ void entatt_kernel(const void* __restrict__ attn, const int* __restrict__ entity_pos,
                              float* __restrict__ ent_att, const int* __restrict__ dtf) {
    int isbf = dtf[0];
    int beh = blockIdx.x;           // (b*E+e)*H+h, 768 blocks
    int h = beh % H_;
    int be = beh / H_;
    int b = be >> 5;
    int pos[M_];
    for (int m = 0; m < M_; m++) pos[m] = entity_pos[be*M_+m] + 1;
    for (int l = threadIdx.x; l < L_; l += 256) {
        float s = 0.f;
        for (int m = 0; m < M_; m++)
            s += ldIn(attn, (((long)(b*H_ + h))*L_ + pos[m])*L_ + l, isbf);
        ent_att[(long)beh*L_ + l] = 0.25f * s;
    }
}

// ---------------- K3: ht_att (bf16) = normalize_L( mean_H(ha*ta) ) ----------------
__global__ void htatt_kernel(const float* __restrict__ ent_att, const int* __restrict__ hts,
                             unsigned short* __restrict__ htb) {
    int bp = blockIdx.x;            // 512 blocks
    int b = bp >> 8;
    int h_e = hts[bp*2+0], t_e = hts[bp*2+1];
    const float* ea_h = ent_att + (long)((b*E_ + h_e)*H_)*L_;
    const float* ea_t = ent_att + (long)((b*E_ + t_e)*H_)*L_;
    __shared__ float red[256];
    float v[2];
    for (int t = 0; t < 2; t++) {
        int l = threadIdx.x + t*256;
        float s = 0.f;
        for (int h = 0; h < H_; h++) s += ea_h[h*L_+l] * ea_t[h*L_+l];
        v[t] = s * (1.0f/H_);
    }
    red[threadIdx.x] = v[0] + v[1];
    __syncthreads();
    for (int off = 128; off > 0; off >>= 1) {
        if (threadIdx.x < off) red[threadIdx.x] += red[threadIdx.x+off];
        __syncthreads();
    }
    float inv = 1.0f / (red[0] + 1e-5f);
    for (int t = 0; t < 2; t++) {
        int l = threadIdx.x + t*256;
        htb[(long)bp*L_ + l] = f2bf(v[t] * inv);
    }
}

// ---------------- batched transpose + bf16 convert: src[K][Ncols] -> dst[Npad][K] bf16 ----
struct WT8 {
    const void* src[8];
    long off[8];
    int K[8];
    int Ncols[8];
    int Npad[8];
    unsigned short* dst[8];
};

__global__ void wtrans8_kernel(WT8 a, const int* __restrict__ dtf) {
    int z = blockIdx.z;
    int K = a.K[z], Ncols = a.Ncols[z], Npad = a.Npad[z];
    int k0 = blockIdx.x*32, n0 = blockIdx.y*32;
    if (k0 >= K || n0 >= Npad) return;
    const void* src = a.src[z];
    long off = a.off[z];
    unsigned short* dst = a.dst[z];
    int isbf = dtf[0];
    __shared__ float T[32][33];
    int c = threadIdx.x & 31, r8 = threadIdx.x >> 5;
    for (int rr = 0; rr < 4; rr++) {
        int r = r8 + rr*8;
        int n = n0 + c;
        T[r][c] = (n < Ncols) ? ldIn(src, off + (long)(k0+r)*Ncols + n, isbf) : 0.f;
    }
    __syncthreads();
    for (int rr = 0; rr < 4; rr++) {
        int r = r8 + rr*8;
        dst[(long)(n0+r)*K + k0 + c] = f2bf(T[c][r]);
    }
}

// ---------------- W_bil -> f32 copy (dtype-normalized) ----------------
__global__ void wbilf_kernel(const void* __restrict__ W_bil, float* __restrict__ W_bilF,
                             const int* __restrict__ dtf) {
    int isbf = dtf[0];
    int idx = blockIdx.x*256 + threadIdx.x;
    if (idx < 291*C_) W_bilF[idx] = ldIn(W_bil, idx, isbf);
}

// ---------------- catb: hcatb=[hs,rs], tcatb=[ts,rs] in bf16 ----------------
__global__ void catb_kernel(const float* __restrict__ ent_emb, const float* __restrict__ rs,
                            const int* __restrict__ hts,
                            unsigned short* __restrict__ hcatb, unsigned short* __restrict__ tcatb) {
    int n = blockIdx.x;             // 512
    int b = n >> 8;
    int h_e = hts[n*2+0], t_e = hts[n*2+1];
    const float* eh = ent_emb + (long)(b*E_ + h_e)*D_;
    const float* et = ent_emb + (long)(b*E_ + t_e)*D_;
    const float* r  = rs + (long)n*D_;
    for (int k = threadIdx.x; k < D_; k += 256) {
        hcatb[(long)n*1536 + k] = f2bf(eh[k]);
        tcatb[(long)n*1536 + k] = f2bf(et[k]);
        unsigned short rb = f2bf(r[k]);
        hcatb[(long)n*1536 + 768 + k] = rb;
        tcatb[(long)n*1536 + 768 + k] = rb;
    }
}

// ---------------- Generic MFMA GEMM: C[m][n] = act(A[m][:K] . Bt[n][:K] + bias[n]) ----------------
struct MfmaNT {
    const unsigned short* A[4];
    const unsigned short* Bt[4];
    const void* bias[4];
    void* C[4];
};

__global__ void mfma_nt_kernel(MfmaNT args, int K, int ldc, int act, int obf,
                               const int* __restrict__ dtf) {
    const unsigned short* A  = args.A[blockIdx.z];
    const unsigned short* Bt = args.Bt[blockIdx.z];
    const void* bias = args.bias[blockIdx.z];
    void* C = args.C[blockIdx.z];
    __shared__ unsigned short Al[64][72];
    __shared__ unsigned short Btl[64][72];
    int m0 = blockIdx.x*64, n0 = blockIdx.y*64;
    int tid = threadIdx.x, wave = tid>>6, lane = tid&63;
    int lm = lane&15, lq = lane>>4;
    f32x4 acc[4] = {};
    for (int k0 = 0; k0 < K; k0 += 64) {
        __syncthreads();
        for (int t = 0; t < 2; t++) {
            int idx = tid + t*256;
            int r = idx>>3, k8 = idx&7;
            *(uint4*)&Al[r][k8*8]  = *(const uint4*)(A  + (long)(m0+r)*K + k0 + k8*8);
            *(uint4*)&Btl[r][k8*8] = *(const uint4*)(Bt + (long)(n0+r)*K + k0 + k8*8);
        }
        __syncthreads();
        for (int half = 0; half < 2; half++) {
            bf16x8 af = *(bf16x8*)&Al[wave*16+lm][half*32+lq*8];
            #pragma unroll
            for (int ct = 0; ct < 4; ct++) {
                bf16x8 bfr = *(bf16x8*)&Btl[ct*16+lm][half*32+lq*8];
                acc[ct] = __builtin_amdgcn_mfma_f32_16x16x32_bf16(af, bfr, acc[ct], 0, 0, 0);
            }
        }
    }
    int isbf = dtf[0];
    for (int ct = 0; ct < 4; ct++) {
        int n = n0 + ct*16 + lm;
        float bia = bias ? ldIn(bias, n, isbf) : 0.f;
        for (int r = 0; r < 4; r++) {
            int m = m0 + wave*16 + lq*4 + r;
            float v = acc[ct][r] + bia;
            if (act == 1) v = tanhf(v);
            if (obf) ((unsigned short*)C)[(long)m*ldc + n] = f2bf(v);
            else     ((float*)C)[(long)m*ldc + n] = v;
        }
    }
}

// ================= r1 via MFMA with on-the-fly A generation =================
__global__ void wconv_kernel(const void* __restrict__ W_rel, unsigned short* __restrict__ WBt,
                             const int* __restrict__ dtf) {
    int isbf = dtf[0];
    __shared__ unsigned short T[CPAD_][136];
    int k0 = blockIdx.x * 128;
    int tid = threadIdx.x;
    for (int idx = tid; idx < 128*97; idx += 256) {
        int kk = idx / 97, c = idx % 97;
        T[c][kk] = f2bf(ldIn(W_rel, (long)(k0+kk)*C_ + c, isbf));
    }
    for (int idx = tid; idx < 15*128; idx += 256) {
        T[97 + (idx>>7)][idx & 127] = 0;
    }
    __syncthreads();
    for (int t = 0; t < 7; t++) {
        int idx = tid + t*256;
        int c = idx >> 4, kc = idx & 15;
        *(uint4*)(WBt + (long)c*KTOT_ + k0 + kc*8) = *(uint4*)&T[c][kc*8];
    }
}

// partial layout: [n][kz][c]  (contiguous 64*112 per row n -> streaming reduce)
__global__ void r1_mfma_kernel(const float* __restrict__ hz, const float* __restrict__ tz,
                               const unsigned short* __restrict__ WBt,
                               float* __restrict__ partial) {
    __shared__ float hzL[64][13];
    __shared__ unsigned short tzbL[64][136];
    __shared__ unsigned short Btl[CPAD_][72];
    int n0 = blockIdx.x * 64;
    int kz = blockIdx.y;
    int kbase = kz * KCHUNK_;
    int gi0 = kbase >> 6;
    int g0 = kbase >> 12;
    int g1 = min(g0 + 1, EMB_/64 - 1);
    int tid = threadIdx.x;
    int wave = tid >> 6, lane = tid & 63;
    int lm = lane & 15, lq = lane >> 4;

    for (int t = 0; t < 4; t++) {
        int id = tid + t*256;
        int n = id >> 4, q = id & 15;
        if (q < 12) hzL[n][q] = hz[(long)(n0+n)*EMB_ + gi0 + q];
    }
    for (int t = 0; t < 8; t++) {
        int id = tid + t*256;
        int n = id >> 5, c4 = (id & 31) * 4;
        int gcol = (c4 < 64) ? (g0*64 + c4) : (g1*64 + c4 - 64);
        float4 v = *(const float4*)(tz + (long)(n0+n)*EMB_ + gcol);
        unsigned short o[4] = {f2bf(v.x), f2bf(v.y), f2bf(v.z), f2bf(v.w)};
        *(uint2*)&tzbL[n][c4] = *(uint2*)o;
    }

    f32x4 acc[7] = {};
    for (int ks = 0; ks < KCHUNK_/64; ks++) {
        int k0 = kbase + ks*64;
        int gsel = ((k0 >> 12) > g0) ? 64 : 0;
        __syncthreads();
        for (int t = 0; t < 4; t++) {
            int idx = tid + t*256;
            if (idx < 896) {
                int c = idx >> 3, k8 = idx & 7;
                *(uint4*)&Btl[c][k8*8] = *(const uint4*)(WBt + (long)c*KTOT_ + k0 + k8*8);
            }
        }
        __syncthreads();
        float hv = hzL[wave*16 + lm][ks];
        for (int half = 0; half < 2; half++) {
            bf16x8 tzf = *(bf16x8*)&tzbL[wave*16 + lm][gsel + half*32 + lq*8];
            unsigned short o[8];
            #pragma unroll
            for (int e = 0; e < 8; e++)
                o[e] = f2bf(bf2f(((unsigned short*)&tzf)[e]) * hv);
            bf16x8 afrag = *(bf16x8*)o;
            #pragma unroll
            for (int ct = 0; ct < 7; ct++) {
                bf16x8 bfrag = *(bf16x8*)&Btl[ct*16 + lm][half*32 + lq*8];
                acc[ct] = __builtin_amdgcn_mfma_f32_16x16x32_bf16(afrag, bfrag, acc[ct], 0, 0, 0);
            }
        }
    }
    for (int ct = 0; ct < 7; ct++) {
        int c = ct*16 + lm;
        for (int r = 0; r < 4; r++) {
            int nl = wave*16 + lq*4 + r;
            partial[((long)(n0+nl)*KSPLIT_ + kz)*CPAD_ + c] = acc[ct][r];
        }
    }
}

// ---------------- c2/c3 constants (parallel): grid C_, block 256 ----------------
__global__ void c23p_kernel(const void* __restrict__ b_f,
                            const void* __restrict__ W_unet, const void* __restrict__ b_unet,
                            const void* __restrict__ W_mlp,  const void* __restrict__ b_mlp,
                            float* __restrict__ c23, const int* __restrict__ dtf) {
    int isbf = dtf[0];
    int c = blockIdx.x;
    __shared__ float red2[256], red3[256];
    float s2 = 0.f, s3 = 0.f;
    for (int d = threadIdx.x; d < D_; d += 256) {
        float bf = ldIn(b_f, d, isbf);
        s2 += bf * ldIn(W_unet, (long)d*C_ + c, isbf);
        s3 += bf * ldIn(W_mlp,  (long)d*C_ + c, isbf);
    }
    red2[threadIdx.x] = s2; red3[threadIdx.x] = s3;
    __syncthreads();
    for (int off = 128; off > 0; off >>= 1) {
        if (threadIdx.x < off) {
            red2[threadIdx.x] += red2[threadIdx.x+off];
            red3[threadIdx.x] += red3[threadIdx.x+off];
        }
        __syncthreads();
    }
    if (threadIdx.x == 0) {
        c23[c]      = red2[0] + ldIn(b_unet, c, isbf);
        c23[C_ + c] = red3[0] + ldIn(b_mlp,  c, isbf);
    }
}

// ---------------- fused: r1 streaming reduce + r2/r3 LSE + final projection ----------------
// grid 512 (one per row n), block 128 (c = tid)
__global__ void r23out_kernel(const float* __restrict__ partial, const void* __restrict__ b_rel,
                              const float* __restrict__ mu, const float* __restrict__ c23,
                              const int* __restrict__ hts, const int* __restrict__ mention_idx,
                              const float* __restrict__ W_bilF, const void* __restrict__ b_bil,
                              void* __restrict__ out, const int* __restrict__ dtf) {
    int bp = blockIdx.x;
    int b = bp >> 8;
    int c = threadIdx.x;
    int isbf = dtf[0];
    __shared__ float row[292];
    if (c < C_) {
        // r1: streaming reduce over contiguous [kz][c] block for this row
        const float* pr = partial + (long)bp*KSPLIT_*CPAD_;
        float r1v = 0.f;
        #pragma unroll 8
        for (int kz = 0; kz < KSPLIT_; kz++)
            r1v += pr[kz*CPAD_ + c];
        r1v += ldIn(b_rel, c, isbf);
        // r2/r3
        int h_e = hts[bp*2+0], t_e = hts[bp*2+1];
        const float* mu2h = mu;
        const float* mu2t = mu + 32768;
        const float* mu3h = mu + 65536;
        const float* mu3t = mu + 98304;
        float ah2[4], at2[4], ah3[4], at3[4];
        for (int m = 0; m < 4; m++) {
            int emh = mention_idx[(b*E_ + h_e)*M_ + m];
            int emt = mention_idx[(b*E_ + t_e)*M_ + m];
            ah2[m] = mu2h[(long)(b*128 + emh)*128 + c];
            ah3[m] = mu3h[(long)(b*128 + emh)*128 + c];
            at2[m] = mu2t[(long)(b*128 + emt)*128 + c];
            at3[m] = mu3t[(long)(b*128 + emt)*128 + c];
        }
        float c2 = c23[c], c3 = c23[C_ + c];
        float v2[16], v3[16];
        int q = 0;
        for (int i = 0; i < 4; i++) {
            for (int j = 0; j < 4; j++, q++) {
                float x2 = ah2[i] + at2[j] + c2;
                v2[q] = tanhf(x2);
                float x3 = ah3[i] + at3[j] + c3;
                float t = tanhf(0.7978845608028654f * (x3 + 0.044715f*x3*x3*x3));
                v3[q] = 0.5f * x3 * (1.0f + t);
            }
        }
        float m2 = v2[0], m3 = v3[0];
        for (q = 1; q < 16; q++) { m2 = fmaxf(m2, v2[q]); m3 = fmaxf(m3, v3[q]); }
        float s2 = 0.f, s3 = 0.f;
        for (q = 0; q < 16; q++) { s2 += expf(v2[q]-m2); s3 += expf(v3[q]-m3); }
        row[c]        = r1v;
        row[C_ + c]   = m2 + logf(s2);
        row[2*C_ + c] = m3 + logf(s3);
    }
    __syncthreads();
    if (c >= C_) return;
    // out[bp][c] = row . W_bilF[:,c] + b_bil[c]   (f32 typed, coalesced)
    float a0 = 0.f, a1 = 0.f, a2 = 0.f, a3 = 0.f;
    #pragma unroll 4
    for (int k = 0; k < 288; k += 4) {
        a0 += row[k+0] * W_bilF[(k+0)*C_ + c];
        a1 += row[k+1] * W_bilF[(k+1)*C_ + c];
        a2 += row[k+2] * W_bilF[(k+2)*C_ + c];
        a3 += row[k+3] * W_bilF[(k+3)*C_ + c];
    }
    a0 += row[288] * W_bilF[288*C_ + c];
    a1 += row[289] * W_bilF[289*C_ + c];
    a2 += row[290] * W_bilF[290*C_ + c];
    float v = a0 + a1 + a2 + a3 + ldIn(b_bil, c, isbf);
    if (isbf) ((bf16*)out)[(long)bp*C_ + c] = (bf16)v;
    else      ((float*)out)[(long)bp*C_ + c] = v;
}

extern "C" void kernel_launch(void* const* d_in, const int* in_sizes, int n_in,
                              void* d_out, int out_size, void* d_ws, size_t ws_size,
                              hipStream_t stream) {
    const void* seq        = d_in[0];
    const void* attn       = d_in[1];
    const int*  entity_pos = (const int*)d_in[2];
    const int*  hts        = (const int*)d_in[3];
    const int*  mention_idx= (const int*)d_in[4];
    const void* W_head     = d_in[5];
    const void* b_head     = d_in[6];
    const void* W_tail     = d_in[7];
    const void* b_tail     = d_in[8];
    const void* W_rel      = d_in[9];
    const void* b_rel      = d_in[10];
    const void* W_fh       = d_in[11];
    const void* W_ft       = d_in[12];
    const void* b_f        = d_in[13];
    const void* W_unet     = d_in[14];
    const void* b_unet     = d_in[15];
    const void* W_mlp      = d_in[16];
    const void* b_mlp      = d_in[17];
    const void* W_bil      = d_in[18];
    const void* b_bil      = d_in[19];

    float* w = (float*)d_ws;
    int*   dtf      = (int*)w;                               // 64
    unsigned short* mentb = (unsigned short*)(w + 64);       // 98304 fl
    float* ent_emb  = w + 98368;                             // 49152
    float* ent_att  = w + 147520;                            // 393216
    unsigned short* htb = (unsigned short*)(w + 540736);     // 131072 fl
    float* rs       = w + 671808;                            // 393216
    float* hz       = w + 1065024;                           // 393216
    float* tz       = w + 1458240;                           // 393216
    float* mu       = w + 1851456;                           // 131072
    float* c23      = w + 1982528;                           // 256
    unsigned short* seqT  = (unsigned short*)(w + 1982784);  // 393216 fl
    unsigned short* WhT   = (unsigned short*)(w + 2376000);  // 589824 fl
    unsigned short* WtT   = (unsigned short*)(w + 2965824);  // 589824 fl
    unsigned short* WfhT  = (unsigned short*)(w + 3555648);  // 294912 fl
    unsigned short* WftT  = (unsigned short*)(w + 3850560);  // 294912 fl
    unsigned short* WunetT= (unsigned short*)(w + 4145472);  // 49152 fl
    unsigned short* WmlpT = (unsigned short*)(w + 4194624);  // 49152 fl
    unsigned short* Tbh   = (unsigned short*)(w + 4243776);  // 98304 fl
    unsigned short* Tbt   = (unsigned short*)(w + 4342080);  // 98304 fl
    unsigned short* hcatb = (unsigned short*)(w + 4440384);  // 393216 fl
    unsigned short* tcatb = (unsigned short*)(w + 4833600);  // 393216 fl
    unsigned short* WBt   = (unsigned short*)(w + 5226816);  // 2752512 fl
    float* partial  = w + 7979328;                           // 64*512*112 = 3670016 fl
    float* W_bilF   = w + 11649344;                          // 291*97 = 28227 fl -> end 11677571

    // 0. dtype detection
    dtype_detect<<<1, 256, 0, stream>>>(seq, dtf);
    // weight preprocessing
    wconv_kernel<<<KTOT_/128, 256, 0, stream>>>(W_rel, WBt, dtf);
    {
        WT8 a = {};
        const void* srcs[8] = {W_head, W_tail, W_fh, W_ft, W_unet, W_mlp, seq, seq};
        long offs[8]   = {0,0,0,0,0,0,0,393216};
        int Ks[8]      = {1536,1536,768,768,768,768,512,512};
        int Ncols8[8]  = {768,768,768,768,97,97,768,768};
        int Npads[8]   = {768,768,768,768,128,128,768,768};
        unsigned short* dsts[8] = {WhT, WtT, WfhT, WftT, WunetT, WmlpT, seqT, seqT+393216};
        for (int z = 0; z < 8; z++) {
            a.src[z]=srcs[z]; a.off[z]=offs[z]; a.K[z]=Ks[z];
            a.Ncols[z]=Ncols8[z]; a.Npad[z]=Npads[z]; a.dst[z]=dsts[z];
        }
        wtrans8_kernel<<<dim3(48, 24, 8), 256, 0, stream>>>(a, dtf);
    }
    wbilf_kernel<<<(291*C_ + 255)/256, 256, 0, stream>>>(W_bil, W_bilF, dtf);
    // 1. mentions + entity embeddings
    ment_kernel<<<B_*E_, 256, 0, stream>>>(seq, entity_pos, mentb, ent_emb, dtf);
    // 2. entity attention
    entatt_kernel<<<B_*E_*H_, 256, 0, stream>>>(attn, entity_pos, ent_att, dtf);
    // 3. ht attention (normalized, bf16)
    htatt_kernel<<<N_, 256, 0, stream>>>(ent_att, hts, htb);
    // 4. rs = ht_att @ seq  (MFMA, per-batch via z)
    {
        MfmaNT ga = {};
        for (int z = 0; z < 2; z++) {
            ga.A[z]  = htb + (long)z*256*512;
            ga.Bt[z] = seqT + (long)z*393216;
            ga.bias[z] = nullptr;
            ga.C[z]  = rs + (long)z*256*768;
        }
        mfma_nt_kernel<<<dim3(4, 12, 2), 256, 0, stream>>>(ga, 512, 768, 0, 0, dtf);
    }
    // 5. concatenated inputs (bf16)
    catb_kernel<<<N_, 256, 0, stream>>>(ent_emb, rs, hts, hcatb, tcatb);
    // 6. hz/tz = tanh(cat @ W + b)  (MFMA)
    {
        MfmaNT ga = {};
        ga.A[0] = hcatb; ga.Bt[0] = WhT; ga.bias[0] = b_head; ga.C[0] = hz;
        ga.A[1] = tcatb; ga.Bt[1] = WtT; ga.bias[1] = b_tail; ga.C[1] = tz;
        mfma_nt_kernel<<<dim3(8, 12, 2), 256, 0, stream>>>(ga, 1536, 768, 1, 0, dtf);
    }
    // 7. T_{h,t} = ment_flat @ W_f{h,t}  (MFMA, bf16 out)
    {
        MfmaNT ga = {};
        ga.A[0] = mentb; ga.Bt[0] = WfhT; ga.bias[0] = nullptr; ga.C[0] = Tbh;
        ga.A[1] = mentb; ga.Bt[1] = WftT; ga.bias[1] = nullptr; ga.C[1] = Tbt;
        mfma_nt_kernel<<<dim3(4, 12, 2), 256, 0, stream>>>(ga, 768, 768, 0, 1, dtf);
    }
    // 8. mu_q = T @ W_{unet,mlp}  (MFMA, N padded to 128)
    {
        MfmaNT ga = {};
        const unsigned short* As[4] = {Tbh, Tbt, Tbh, Tbt};
        const unsigned short* Bs[4] = {WunetT, WunetT, WmlpT, WmlpT};
        for (int q = 0; q < 4; q++) {
            ga.A[q] = As[q]; ga.Bt[q] = Bs[q]; ga.bias[q] = nullptr;
            ga.C[q] = mu + q*32768;
        }
        mfma_nt_kernel<<<dim3(4, 2, 4), 256, 0, stream>>>(ga, 768, 128, 0, 0, dtf);
    }
    // 9. c2/c3 constants
    c23p_kernel<<<C_, 256, 0, stream>>>(b_f, W_unet, b_unet, W_mlp, b_mlp, c23, dtf);
    // 10. r1 partials via MFMA (A generated on the fly; partial [n][kz][c])
    r1_mfma_kernel<<<dim3(8, KSPLIT_), 256, 0, stream>>>(hz, tz, WBt, partial);
    // 11. fused reduce + r2/r3 + final projection
    r23out_kernel<<<N_, 128, 0, stream>>>(partial, b_rel, mu, c23, hts, mention_idx,
                                          W_bilF, b_bil, d_out, dtf);
}

// Round 8
// 276.733 us; speedup vs baseline: 9.4172x; 1.1763x over previous
//
#include <hip/hip_runtime.h>
#include <hip/hip_bf16.h>

// Problem constants
#define B_  2
#define L_  512
#define D_  768
#define H_  12
#define E_  32
#define M_  4
#define P_  256
#define EMB_ 768
#define BS_ 64
#define C_  97
#define N_  (B_*P_)   // 512

#define KTOT_    49152      // EMB*BS
#define CPAD_    112        // 97 padded to 7*16
#define KSPLIT_  64
#define KCHUNK_  (KTOT_/KSPLIT_)   // 768, 12 ks-steps of 64

typedef __hip_bfloat16 bf16;
typedef __attribute__((ext_vector_type(8))) short bf16x8;
typedef __attribute__((ext_vector_type(4))) float f32x4;

__device__ inline float ldIn(const void* p, long idx, int isbf) {
    return isbf ? (float)((const bf16*)p)[idx] : ((const float*)p)[idx];
}

__device__ inline unsigned short f2bf(float f) {
    bf16 h = (bf16)f;
    return *(unsigned short*)&h;
}

__device__ inline float bf2f(unsigned short u) {
    bf16 h = *(bf16*)&u;
    return (float)h;
}

// ---------------- K0: dtype detection ----------------
__global__ void dtype_detect(const void* __restrict__ seq, int* __restrict__ flag) {
    __shared__ int cnt;
    if (threadIdx.x == 0) cnt = 0;
    __syncthreads();
    const unsigned short* u = (const unsigned short*)seq;
    int bad = 0;
    for (int i = threadIdx.x; i < 1024; i += 256) {
        unsigned short e = (u[i] >> 7) & 0xFF;
        if (e >= 140) bad++;
    }
    atomicAdd(&cnt, bad);
    __syncthreads();
    if (threadIdx.x == 0) flag[0] = (cnt < 16) ? 1 : 0;   // 1 = bf16 inputs
}

// ---------------- prep: z<8 transposes, z=8 W_bil->f32, z=9 c2/c3, z=10 W_rel conv ----------------
struct PrepArgs {
    const void* src[8];
    long off[8];
    int K[8];
    int Ncols[8];
    int Npad[8];
    unsigned short* dst[8];
    const void* W_bil;  float* W_bilF;
    const void* b_f; const void* W_unet; const void* b_unet;
    const void* W_mlp; const void* b_mlp; float* c23;
    const void* W_rel; unsigned short* WBt;
};

__global__ void prep_kernel(PrepArgs a, const int* __restrict__ dtf) {
    int isbf = dtf[0];
    int z = blockIdx.z;
    __shared__ float T[32][33];
    __shared__ unsigned short TW[CPAD_][136];
    __shared__ float red2[256], red3[256];
    if (z < 8) {
        int K = a.K[z], Ncols = a.Ncols[z], Npad = a.Npad[z];
        int k0 = blockIdx.x*32, n0 = blockIdx.y*32;
        if (k0 >= K || n0 >= Npad) return;
        const void* src = a.src[z];
        long off = a.off[z];
        unsigned short* dst = a.dst[z];
        int c = threadIdx.x & 31, r8 = threadIdx.x >> 5;
        for (int rr = 0; rr < 4; rr++) {
            int r = r8 + rr*8;
            int n = n0 + c;
            T[r][c] = (n < Ncols) ? ldIn(src, off + (long)(k0+r)*Ncols + n, isbf) : 0.f;
        }
        __syncthreads();
        for (int rr = 0; rr < 4; rr++) {
            int r = r8 + rr*8;
            dst[(long)(n0+r)*K + k0 + c] = f2bf(T[c][r]);
        }
    } else if (z == 8) {
        int lin = blockIdx.y*48 + blockIdx.x;
        int idx = lin*256 + threadIdx.x;
        if (idx < 291*C_) a.W_bilF[idx] = ldIn(a.W_bil, idx, isbf);
    } else if (z == 9) {
        int c = blockIdx.y*48 + blockIdx.x;
        if (c >= C_) return;
        float s2 = 0.f, s3 = 0.f;
        for (int d = threadIdx.x; d < D_; d += 256) {
            float bf = ldIn(a.b_f, d, isbf);
            s2 += bf * ldIn(a.W_unet, (long)d*C_ + c, isbf);
            s3 += bf * ldIn(a.W_mlp,  (long)d*C_ + c, isbf);
        }
        red2[threadIdx.x] = s2; red3[threadIdx.x] = s3;
        __syncthreads();
        for (int off = 128; off > 0; off >>= 1) {
            if (threadIdx.x < off) {
                red2[threadIdx.x] += red2[threadIdx.x+off];
                red3[threadIdx.x] += red3[threadIdx.x+off];
            }
            __syncthreads();
        }
        if (threadIdx.x == 0) {
            a.c23[c]      = red2[0] + ldIn(a.b_unet, c, isbf);
            a.c23[C_ + c] = red3[0] + ldIn(a.b_mlp,  c, isbf);
        }
    } else {
        // W_rel -> WBt[c][k] bf16, c padded to 112
        int lin = blockIdx.y*48 + blockIdx.x;
        if (lin >= KTOT_/128) return;
        int k0 = lin * 128;
        int tid = threadIdx.x;
        for (int idx = tid; idx < 128*97; idx += 256) {
            int kk = idx / 97, c = idx % 97;
            TW[c][kk] = f2bf(ldIn(a.W_rel, (long)(k0+kk)*C_ + c, isbf));
        }
        for (int idx = tid; idx < 15*128; idx += 256) {
            TW[97 + (idx>>7)][idx & 127] = 0;
        }
        __syncthreads();
        for (int t = 0; t < 7; t++) {
            int idx = tid + t*256;
            int c = idx >> 4, kc = idx & 15;
            *(uint4*)(a.WBt + (long)c*KTOT_ + k0 + kc*8) = *(uint4*)&TW[c][kc*8];
        }
    }
}

// ---------------- gather: bx<768 entatt, else ment ----------------
__global__ void gather_kernel(const void* __restrict__ seq, const void* __restrict__ attn,
                              const int* __restrict__ entity_pos,
                              unsigned short* __restrict__ mentb, float* __restrict__ ent_emb,
                              float* __restrict__ ent_att, const int* __restrict__ dtf) {
    int isbf = dtf[0];
    if (blockIdx.x < 768) {
        int beh = blockIdx.x;
        int h = beh % H_;
        int be = beh / H_;
        int b = be >> 5;
        int pos[M_];
        for (int m = 0; m < M_; m++) pos[m] = entity_pos[be*M_+m] + 1;
        for (int l = threadIdx.x; l < L_; l += 256) {
            float s = 0.f;
            for (int m = 0; m < M_; m++)
                s += ldIn(attn, (((long)(b*H_ + h))*L_ + pos[m])*L_ + l, isbf);
            ent_att[(long)beh*L_ + l] = 0.25f * s;
        }
    } else {
        int be = blockIdx.x - 768;     // 0..63
        int b = be >> 5;
        int pos[M_];
        for (int m = 0; m < M_; m++) pos[m] = entity_pos[be*M_+m] + 1;
        for (int d = threadIdx.x; d < D_; d += 256) {
            float x[M_];
            for (int m = 0; m < M_; m++) {
                x[m] = ldIn(seq, ((long)b*L_ + pos[m])*D_ + d, isbf);
                mentb[((long)be*M_ + m)*D_ + d] = f2bf(x[m]);
            }
            float mx = fmaxf(fmaxf(x[0],x[1]), fmaxf(x[2],x[3]));
            float s = expf(x[0]-mx)+expf(x[1]-mx)+expf(x[2]-mx)+expf(x[3]-mx);
            ent_emb[(long)be*D_ + d] = mx + logf(s);
        }
    }
}

// ---------------- K3: ht_att (bf16) = normalize_L( mean_H(ha*ta) ) ----------------
__global__ void htatt_kernel(const float* __restrict__ ent_att, const int* __restrict__ hts,
                             unsigned short* __restrict__ htb) {
    int bp = blockIdx.x;            // 512 blocks
    int b = bp >> 8;
    int h_e = hts[bp*2+0], t_e = hts[bp*2+1];
    const float* ea_h = ent_att + (long)((b*E_ + h_e)*H_)*L_;
    const float* ea_t = ent_att + (long)((b*E_ + t_e)*H_)*L_;
    __shared__ float red[256];
    float v[2];
    for (int t = 0; t < 2; t++) {
        int l = threadIdx.x + t*256;
        float s = 0.f;
        for (int h = 0; h < H_; h++) s += ea_h[h*L_+l] * ea_t[h*L_+l];
        v[t] = s * (1.0f/H_);
    }
    red[threadIdx.x] = v[0] + v[1];
    __syncthreads();
    for (int off = 128; off > 0; off >>= 1) {
        if (threadIdx.x < off) red[threadIdx.x] += red[threadIdx.x+off];
        __syncthreads();
    }
    float inv = 1.0f / (red[0] + 1e-5f);
    for (int t = 0; t < 2; t++) {
        int l = threadIdx.x + t*256;
        htb[(long)bp*L_ + l] = f2bf(v[t] * inv);
    }
}

// ---------------- catb: hcatb=[hs,rs], tcatb=[ts,rs] in bf16 ----------------
__global__ void catb_kernel(const float* __restrict__ ent_emb, const float* __restrict__ rs,
                            const int* __restrict__ hts,
                            unsigned short* __restrict__ hcatb, unsigned short* __restrict__ tcatb) {
    int n = blockIdx.x;             // 512
    int b = n >> 8;
    int h_e = hts[n*2+0], t_e = hts[n*2+1];
    const float* eh = ent_emb + (long)(b*E_ + h_e)*D_;
    const float* et = ent_emb + (long)(b*E_ + t_e)*D_;
    const float* r  = rs + (long)n*D_;
    for (int k = threadIdx.x; k < D_; k += 256) {
        hcatb[(long)n*1536 + k] = f2bf(eh[k]);
        tcatb[(long)n*1536 + k] = f2bf(et[k]);
        unsigned short rb = f2bf(r[k]);
        hcatb[(long)n*1536 + 768 + k] = rb;
        tcatb[(long)n*1536 + 768 + k] = rb;
    }
}

// ---------------- Generic MFMA GEMM (double-buffered): per-z jobs ----------------
struct MfmaJob {
    const unsigned short* A[4];
    const unsigned short* Bt[4];
    const void* bias[4];
    void* C[4];
    int K[4];
    int ldc[4];
    int act[4];
    int obf[4];
};

__global__ void mfma_nt2_kernel(MfmaJob args, const int* __restrict__ dtf) {
    int z = blockIdx.z;
    const unsigned short* A  = args.A[z];
    const unsigned short* Bt = args.Bt[z];
    const void* bias = args.bias[z];
    void* C = args.C[z];
    int K = args.K[z], ldc = args.ldc[z], act = args.act[z], obf = args.obf[z];
    __shared__ unsigned short Al[2][64][72];
    __shared__ unsigned short Btl[2][64][72];
    int m0 = blockIdx.x*64, n0 = blockIdx.y*64;
    int tid = threadIdx.x, wave = tid>>6, lane = tid&63;
    int lm = lane&15, lq = lane>>4;
    int rr = tid >> 3;                // 0..31
    int kc = (tid & 7) * 8;           // col offset in ushorts
    uint4 ra0, ra1, rb0, rb1;

    // prologue: load tile 0 and stage
    ra0 = *(const uint4*)(A  + (long)(m0+rr)*K + kc);
    ra1 = *(const uint4*)(A  + (long)(m0+32+rr)*K + kc);
    rb0 = *(const uint4*)(Bt + (long)(n0+rr)*K + kc);
    rb1 = *(const uint4*)(Bt + (long)(n0+32+rr)*K + kc);
    *(uint4*)&Al[0][rr][kc]     = ra0;
    *(uint4*)&Al[0][32+rr][kc]  = ra1;
    *(uint4*)&Btl[0][rr][kc]    = rb0;
    *(uint4*)&Btl[0][32+rr][kc] = rb1;

    int nst = K >> 6;
    f32x4 acc[4] = {};
    for (int ks = 0; ks < nst; ks++) {
        __syncthreads();
        if (ks+1 < nst) {
            int k0 = (ks+1) << 6;
            ra0 = *(const uint4*)(A  + (long)(m0+rr)*K + k0 + kc);
            ra1 = *(const uint4*)(A  + (long)(m0+32+rr)*K + k0 + kc);
            rb0 = *(const uint4*)(Bt + (long)(n0+rr)*K + k0 + kc);
            rb1 = *(const uint4*)(Bt + (long)(n0+32+rr)*K + k0 + kc);
        }
        int cb = ks & 1;
        for (int half = 0; half < 2; half++) {
            bf16x8 af = *(bf16x8*)&Al[cb][wave*16+lm][half*32+lq*8];
            #pragma unroll
            for (int ct = 0; ct < 4; ct++) {
                bf16x8 bfr = *(bf16x8*)&Btl[cb][ct*16+lm][half*32+lq*8];
                acc[ct] = __builtin_amdgcn_mfma_f32_16x16x32_bf16(af, bfr, acc[ct], 0, 0, 0);
            }
        }
        if (ks+1 < nst) {
            int nb = (ks+1) & 1;
            *(uint4*)&Al[nb][rr][kc]     = ra0;
            *(uint4*)&Al[nb][32+rr][kc]  = ra1;
            *(uint4*)&Btl[nb][rr][kc]    = rb0;
            *(uint4*)&Btl[nb][32+rr][kc] = rb1;
        }
    }
    int isbf = dtf[0];
    for (int ct = 0; ct < 4; ct++) {
        int n = n0 + ct*16 + lm;
        float bia = bias ? ldIn(bias, n, isbf) : 0.f;
        for (int r = 0; r < 4; r++) {
            int m = m0 + wave*16 + lq*4 + r;
            float v = acc[ct][r] + bia;
            if (act == 1) v = tanhf(v);
            if (obf) ((unsigned short*)C)[(long)m*ldc + n] = f2bf(v);
            else     ((float*)C)[(long)m*ldc + n] = v;
        }
    }
}

// ================= r1 via MFMA, on-the-fly A, double-buffered B =================
// partial layout: [n][kz][c]
__global__ void r1_mfma_kernel(const float* __restrict__ hz, const float* __restrict__ tz,
                               const unsigned short* __restrict__ WBt,
                               float* __restrict__ partial) {
    __shared__ float hzL[64][13];
    __shared__ unsigned short tzbL[64][136];
    __shared__ unsigned short Btl[2][CPAD_][72];
    int n0 = blockIdx.x * 64;
    int kz = blockIdx.y;
    int kbase = kz * KCHUNK_;
    int gi0 = kbase >> 6;
    int g0 = kbase >> 12;
    int g1 = min(g0 + 1, EMB_/64 - 1);
    int tid = threadIdx.x;
    int wave = tid >> 6, lane = tid & 63;
    int lm = lane & 15, lq = lane >> 4;

    for (int t = 0; t < 4; t++) {
        int id = tid + t*256;
        int n = id >> 4, q = id & 15;
        if (q < 12) hzL[n][q] = hz[(long)(n0+n)*EMB_ + gi0 + q];
    }
    for (int t = 0; t < 8; t++) {
        int id = tid + t*256;
        int n = id >> 5, c4 = (id & 31) * 4;
        int gcol = (c4 < 64) ? (g0*64 + c4) : (g1*64 + c4 - 64);
        float4 v = *(const float4*)(tz + (long)(n0+n)*EMB_ + gcol);
        unsigned short o[4] = {f2bf(v.x), f2bf(v.y), f2bf(v.z), f2bf(v.w)};
        *(uint2*)&tzbL[n][c4] = *(uint2*)o;
    }
    // prologue B tile
    uint4 rb[4];
    #pragma unroll
    for (int t = 0; t < 4; t++) {
        int idx = tid + t*256;
        if (idx < 896) {
            int c = idx >> 3, k8 = (idx & 7)*8;
            rb[t] = *(const uint4*)(WBt + (long)c*KTOT_ + kbase + k8);
        }
    }
    #pragma unroll
    for (int t = 0; t < 4; t++) {
        int idx = tid + t*256;
        if (idx < 896) {
            int c = idx >> 3, k8 = (idx & 7)*8;
            *(uint4*)&Btl[0][c][k8] = rb[t];
        }
    }

    f32x4 acc[7] = {};
    for (int ks = 0; ks < KCHUNK_/64; ks++) {
        __syncthreads();
        if (ks+1 < KCHUNK_/64) {
            int k0 = kbase + (ks+1)*64;
            #pragma unroll
            for (int t = 0; t < 4; t++) {
                int idx = tid + t*256;
                if (idx < 896) {
                    int c = idx >> 3, k8 = (idx & 7)*8;
                    rb[t] = *(const uint4*)(WBt + (long)c*KTOT_ + k0 + k8);
                }
            }
        }
        int cb = ks & 1;
        int k0 = kbase + ks*64;
        int gsel = ((k0 >> 12) > g0) ? 64 : 0;
        float hv = hzL[wave*16 + lm][ks];
        for (int half = 0; half < 2; half++) {
            bf16x8 tzf = *(bf16x8*)&tzbL[wave*16 + lm][gsel + half*32 + lq*8];
            unsigned short o[8];
            #pragma unroll
            for (int e = 0; e < 8; e++)
                o[e] = f2bf(bf2f(((unsigned short*)&tzf)[e]) * hv);
            bf16x8 afrag = *(bf16x8*)o;
            #pragma unroll
            for (int ct = 0; ct < 7; ct++) {
                bf16x8 bfrag = *(bf16x8*)&Btl[cb][ct*16 + lm][half*32 + lq*8];
                acc[ct] = __builtin_amdgcn_mfma_f32_16x16x32_bf16(afrag, bfrag, acc[ct], 0, 0, 0);
            }
        }
        if (ks+1 < KCHUNK_/64) {
            int nb = (ks+1) & 1;
            #pragma unroll
            for (int t = 0; t < 4; t++) {
                int idx = tid + t*256;
                if (idx < 896) {
                    int c = idx >> 3, k8 = (idx & 7)*8;
                    *(uint4*)&Btl[nb][c][k8] = rb[t];
                }
            }
        }
    }
    for (int ct = 0; ct < 7; ct++) {
        int c = ct*16 + lm;
        for (int r = 0; r < 4; r++) {
            int nl = wave*16 + lq*4 + r;
            partial[((long)(n0+nl)*KSPLIT_ + kz)*CPAD_ + c] = acc[ct][r];
        }
    }
}

// ---------------- fused: r1 streaming reduce + r2/r3 LSE + final projection ----------------
__global__ void r23out_kernel(const float* __restrict__ partial, const void* __restrict__ b_rel,
                              const float* __restrict__ mu, const float* __restrict__ c23,
                              const int* __restrict__ hts, const int* __restrict__ mention_idx,
                              const float* __restrict__ W_bilF, const void* __restrict__ b_bil,
                              void* __restrict__ out, const int* __restrict__ dtf) {
    int bp = blockIdx.x;
    int b = bp >> 8;
    int c = threadIdx.x;
    int isbf = dtf[0];
    __shared__ float row[292];
    if (c < C_) {
        const float* pr = partial + (long)bp*KSPLIT_*CPAD_;
        float r1v = 0.f;
        #pragma unroll 8
        for (int kz = 0; kz < KSPLIT_; kz++)
            r1v += pr[kz*CPAD_ + c];
        r1v += ldIn(b_rel, c, isbf);
        int h_e = hts[bp*2+0], t_e = hts[bp*2+1];
        const float* mu2h = mu;
        const float* mu2t = mu + 32768;
        const float* mu3h = mu + 65536;
        const float* mu3t = mu + 98304;
        float ah2[4], at2[4], ah3[4], at3[4];
        for (int m = 0; m < 4; m++) {
            int emh = mention_idx[(b*E_ + h_e)*M_ + m];
            int emt = mention_idx[(b*E_ + t_e)*M_ + m];
            ah2[m] = mu2h[(long)(b*128 + emh)*128 + c];
            ah3[m] = mu3h[(long)(b*128 + emh)*128 + c];
            at2[m] = mu2t[(long)(b*128 + emt)*128 + c];
            at3[m] = mu3t[(long)(b*128 + emt)*128 + c];
        }
        float c2 = c23[c], c3 = c23[C_ + c];
        float v2[16], v3[16];
        int q = 0;
        for (int i = 0; i < 4; i++) {
            for (int j = 0; j < 4; j++, q++) {
                float x2 = ah2[i] + at2[j] + c2;
                v2[q] = tanhf(x2);
                float x3 = ah3[i] + at3[j] + c3;
                float t = tanhf(0.7978845608028654f * (x3 + 0.044715f*x3*x3*x3));
                v3[q] = 0.5f * x3 * (1.0f + t);
            }
        }
        float m2 = v2[0], m3 = v3[0];
        for (q = 1; q < 16; q++) { m2 = fmaxf(m2, v2[q]); m3 = fmaxf(m3, v3[q]); }
        float s2 = 0.f, s3 = 0.f;
        for (q = 0; q < 16; q++) { s2 += expf(v2[q]-m2); s3 += expf(v3[q]-m3); }
        row[c]        = r1v;
        row[C_ + c]   = m2 + logf(s2);
        row[2*C_ + c] = m3 + logf(s3);
    }
    __syncthreads();
    if (c >= C_) return;
    float a0 = 0.f, a1 = 0.f, a2 = 0.f, a3 = 0.f;
    #pragma unroll 4
    for (int k = 0; k < 288; k += 4) {
        a0 += row[k+0] * W_bilF[(k+0)*C_ + c];
        a1 += row[k+1] * W_bilF[(k+1)*C_ + c];
        a2 += row[k+2] * W_bilF[(k+2)*C_ + c];
        a3 += row[k+3] * W_bilF[(k+3)*C_ + c];
    }
    a0 += row[288] * W_bilF[288*C_ + c];
    a1 += row[289] * W_bilF[289*C_ + c];
    a2 += row[290] * W_bilF[290*C_ + c];
    float v = a0 + a1 + a2 + a3 + ldIn(b_bil, c, isbf);
    if (isbf) ((bf16*)out)[(long)bp*C_ + c] = (bf16)v;
    else      ((float*)out)[(long)bp*C_ + c] = v;
}

extern "C" void kernel_launch(void* const* d_in, const int* in_sizes, int n_in,
                              void* d_out, int out_size, void* d_ws, size_t ws_size,
                              hipStream_t stream) {
    const void* seq        = d_in[0];
    const void* attn       = d_in[1];
    const int*  entity_pos = (const int*)d_in[2];
    const int*  hts        = (const int*)d_in[3];
    const int*  mention_idx= (const int*)d_in[4];
    const void* W_head     = d_in[5];
    const void* b_head     = d_in[6];
    const void* W_tail     = d_in[7];
    const void* b_tail     = d_in[8];
    const void* W_rel      = d_in[9];
    const void* b_rel      = d_in[10];
    const void* W_fh       = d_in[11];
    const void* W_ft       = d_in[12];
    const void* b_f        = d_in[13];
    const void* W_unet     = d_in[14];
    const void* b_unet     = d_in[15];
    const void* W_mlp      = d_in[16];
    const void* b_mlp      = d_in[17];
    const void* W_bil      = d_in[18];
    const void* b_bil      = d_in[19];

    float* w = (float*)d_ws;
    int*   dtf      = (int*)w;                               // 64
    unsigned short* mentb = (unsigned short*)(w + 64);       // 98304 fl
    float* ent_emb  = w + 98368;                             // 49152
    float* ent_att  = w + 147520;                            // 393216
    unsigned short* htb = (unsigned short*)(w + 540736);     // 131072 fl
    float* rs       = w + 671808;                            // 393216
    float* hz       = w + 1065024;                           // 393216
    float* tz       = w + 1458240;                           // 393216
    float* mu       = w + 1851456;                           // 131072
    float* c23      = w + 1982528;                           // 256
    unsigned short* seqT  = (unsigned short*)(w + 1982784);  // 393216 fl
    unsigned short* WhT   = (unsigned short*)(w + 2376000);  // 589824 fl
    unsigned short* WtT   = (unsigned short*)(w + 2965824);  // 589824 fl
    unsigned short* WfhT  = (unsigned short*)(w + 3555648);  // 294912 fl
    unsigned short* WftT  = (unsigned short*)(w + 3850560);  // 294912 fl
    unsigned short* WunetT= (unsigned short*)(w + 4145472);  // 49152 fl
    unsigned short* WmlpT = (unsigned short*)(w + 4194624);  // 49152 fl
    unsigned short* Tbh   = (unsigned short*)(w + 4243776);  // 98304 fl
    unsigned short* Tbt   = (unsigned short*)(w + 4342080);  // 98304 fl
    unsigned short* hcatb = (unsigned short*)(w + 4440384);  // 393216 fl
    unsigned short* tcatb = (unsigned short*)(w + 4833600);  // 393216 fl
    unsigned short* WBt   = (unsigned short*)(w + 5226816);  // 2752512 fl
    float* partial  = w + 7979328;                           // 3670016 fl
    float* W_bilF   = w + 11649344;                          // 28227 fl

    // 0. dtype detection
    dtype_detect<<<1, 256, 0, stream>>>(seq, dtf);
    // 1. prep: transposes + W_bilF + c23 + W_rel conv
    {
        PrepArgs a = {};
        const void* srcs[8] = {W_head, W_tail, W_fh, W_ft, W_unet, W_mlp, seq, seq};
        long offs[8]   = {0,0,0,0,0,0,0,393216};
        int Ks[8]      = {1536,1536,768,768,768,768,512,512};
        int Ncols8[8]  = {768,768,768,768,97,97,768,768};
        int Npads[8]   = {768,768,768,768,128,128,768,768};
        unsigned short* dsts[8] = {WhT, WtT, WfhT, WftT, WunetT, WmlpT, seqT, seqT+393216};
        for (int z = 0; z < 8; z++) {
            a.src[z]=srcs[z]; a.off[z]=offs[z]; a.K[z]=Ks[z];
            a.Ncols[z]=Ncols8[z]; a.Npad[z]=Npads[z]; a.dst[z]=dsts[z];
        }
        a.W_bil = W_bil; a.W_bilF = W_bilF;
        a.b_f = b_f; a.W_unet = W_unet; a.b_unet = b_unet;
        a.W_mlp = W_mlp; a.b_mlp = b_mlp; a.c23 = c23;
        a.W_rel = W_rel; a.WBt = WBt;
        prep_kernel<<<dim3(48, 24, 11), 256, 0, stream>>>(a, dtf);
    }
    // 2. gather: entatt + ment
    gather_kernel<<<768 + 64, 256, 0, stream>>>(seq, attn, entity_pos, mentb, ent_emb, ent_att, dtf);
    // 3. ht attention (normalized, bf16)
    htatt_kernel<<<N_, 256, 0, stream>>>(ent_att, hts, htb);
    // 4. gemmA: rs (z=0,1) + T_{h,t} (z=2,3)
    {
        MfmaJob ga = {};
        for (int z = 0; z < 2; z++) {
            ga.A[z] = htb + (long)z*256*512; ga.Bt[z] = seqT + (long)z*393216;
            ga.bias[z] = nullptr; ga.C[z] = rs + (long)z*256*768;
            ga.K[z] = 512; ga.ldc[z] = 768; ga.act[z] = 0; ga.obf[z] = 0;
        }
        ga.A[2] = mentb; ga.Bt[2] = WfhT; ga.bias[2] = nullptr; ga.C[2] = Tbh;
        ga.K[2] = 768; ga.ldc[2] = 768; ga.act[2] = 0; ga.obf[2] = 1;
        ga.A[3] = mentb; ga.Bt[3] = WftT; ga.bias[3] = nullptr; ga.C[3] = Tbt;
        ga.K[3] = 768; ga.ldc[3] = 768; ga.act[3] = 0; ga.obf[3] = 1;
        mfma_nt2_kernel<<<dim3(4, 12, 4), 256, 0, stream>>>(ga, dtf);
    }
    // 5. concatenated inputs (bf16)
    catb_kernel<<<N_, 256, 0, stream>>>(ent_emb, rs, hts, hcatb, tcatb);
    // 6. gemmB: hz/tz = tanh(cat @ W + b)
    {
        MfmaJob ga = {};
        ga.A[0] = hcatb; ga.Bt[0] = WhT; ga.bias[0] = b_head; ga.C[0] = hz;
        ga.A[1] = tcatb; ga.Bt[1] = WtT; ga.bias[1] = b_tail; ga.C[1] = tz;
        for (int z = 0; z < 2; z++) { ga.K[z] = 1536; ga.ldc[z] = 768; ga.act[z] = 1; ga.obf[z] = 0; }
        mfma_nt2_kernel<<<dim3(8, 12, 2), 256, 0, stream>>>(ga, dtf);
    }
    // 7. gemmC: mu_q = T @ W_{unet,mlp}
    {
        MfmaJob ga = {};
        const unsigned short* As[4] = {Tbh, Tbt, Tbh, Tbt};
        const unsigned short* Bs[4] = {WunetT, WunetT, WmlpT, WmlpT};
        for (int q = 0; q < 4; q++) {
            ga.A[q] = As[q]; ga.Bt[q] = Bs[q]; ga.bias[q] = nullptr;
            ga.C[q] = mu + q*32768;
            ga.K[q] = 768; ga.ldc[q] = 128; ga.act[q] = 0; ga.obf[q] = 0;
        }
        mfma_nt2_kernel<<<dim3(4, 2, 4), 256, 0, stream>>>(ga, dtf);
    }
    // 8. r1 partials via MFMA (A on the fly; partial [n][kz][c]; dbuf B)
    r1_mfma_kernel<<<dim3(8, KSPLIT_), 256, 0, stream>>>(hz, tz, WBt, partial);
    // 9. fused reduce + r2/r3 + final projection
    r23out_kernel<<<N_, 128, 0, stream>>>(partial, b_rel, mu, c23, hts, mention_idx,
                                          W_bilF, b_bil, d_out, dtf);
}

// Round 9
// 265.953 us; speedup vs baseline: 9.7989x; 1.0405x over previous
//
#include <hip/hip_runtime.h>
#include <hip/hip_bf16.h>

// Problem constants
#define B_  2
#define L_  512
#define D_  768
#define H_  12
#define E_  32
#define M_  4
#define P_  256
#define EMB_ 768
#define BS_ 64
#define C_  97
#define N_  (B_*P_)   // 512

#define KTOT_    49152      // EMB*BS
#define CPAD_    112        // 97 padded to 7*16
#define KSPLIT_  64
#define KCHUNK_  (KTOT_/KSPLIT_)   // 768, 12 ks-steps of 64

typedef __hip_bfloat16 bf16;
typedef __attribute__((ext_vector_type(8))) short bf16x8;
typedef __attribute__((ext_vector_type(4))) float f32x4;

__device__ inline float ldIn(const void* p, long idx, int isbf) {
    return isbf ? (float)((const bf16*)p)[idx] : ((const float*)p)[idx];
}

__device__ inline unsigned short f2bf(float f) {
    bf16 h = (bf16)f;
    return *(unsigned short*)&h;
}

__device__ inline float bf2f(unsigned short u) {
    bf16 h = *(bf16*)&u;
    return (float)h;
}

// ---------------- K0: dtype detection + c23 zero-init ----------------
__global__ void dtype_detect(const void* __restrict__ seq, int* __restrict__ flag,
                             float* __restrict__ c23) {
    __shared__ int cnt;
    if (threadIdx.x == 0) cnt = 0;
    if (threadIdx.x < 2*C_) c23[threadIdx.x] = 0.f;
    __syncthreads();
    const unsigned short* u = (const unsigned short*)seq;
    int bad = 0;
    for (int i = threadIdx.x; i < 1024; i += 256) {
        unsigned short e = (u[i] >> 7) & 0xFF;
        if (e >= 140) bad++;
    }
    atomicAdd(&cnt, bad);
    __syncthreads();
    if (threadIdx.x == 0) flag[0] = (cnt < 16) ? 1 : 0;   // 1 = bf16 inputs
}

// ---------------- prep: z<8 transposes (32k x 64n), z=8 W_bil->f32, z=9 c23, z=10 W_rel conv ----
struct PrepArgs {
    const void* src[8];
    long off[8];
    int K[8];
    int Ncols[8];
    int Npad[8];
    unsigned short* dst[8];
    const void* W_bil;  float* W_bilF;
    const void* b_f; const void* W_unet; const void* b_unet;
    const void* W_mlp; const void* b_mlp; float* c23;
    const void* W_rel; unsigned short* WBt;
};

union PrepSm {
    float T[32][65];                 // 8320 B
    unsigned short TW[CPAD_][72];    // 16128 B
};

__global__ void prep_kernel(PrepArgs a, const int* __restrict__ dtf) {
    int isbf = dtf[0];
    int z = blockIdx.z;
    __shared__ PrepSm sm;
    int tid = threadIdx.x;
    if (z < 8) {
        int K = a.K[z], Ncols = a.Ncols[z], Npad = a.Npad[z];
        int k0 = blockIdx.x*32, n0 = blockIdx.y*64;
        if (k0 >= K || n0 >= Npad) return;
        const void* src = a.src[z];
        long off = a.off[z];
        unsigned short* dst = a.dst[z];
        // read: 64 consecutive cols per row (coalesced 128/256 B)
        int c64 = tid & 63, r4 = tid >> 6;
        for (int p = 0; p < 8; p++) {
            int r = r4 + p*4;
            int n = n0 + c64;
            sm.T[r][c64] = (n < Ncols) ? ldIn(src, off + (long)(k0+r)*Ncols + n, isbf) : 0.f;
        }
        __syncthreads();
        // write: 32 consecutive k per n (coalesced)
        int cc = tid & 31, n8 = tid >> 5;
        for (int p = 0; p < 8; p++) {
            int nn = n8 + p*8;
            dst[(long)(n0+nn)*K + k0 + cc] = f2bf(sm.T[cc][nn]);
        }
    } else if (z == 8) {
        int lin = blockIdx.y*48 + blockIdx.x;
        int idx = lin*256 + tid;
        if (idx < 291*C_) a.W_bilF[idx] = ldIn(a.W_bil, idx, isbf);
    } else if (z == 9) {
        // c23 partial: 8 blocks x 96 d-rows, coalesced over c, atomic accumulate
        int lin = blockIdx.y*48 + blockIdx.x;
        if (lin >= 8) return;
        int c = tid;
        if (c >= C_) return;
        float s2 = 0.f, s3 = 0.f;
        int d0 = lin*96;
        for (int i = 0; i < 96; i++) {
            int d = d0 + i;
            float bf = ldIn(a.b_f, d, isbf);
            s2 += bf * ldIn(a.W_unet, (long)d*C_ + c, isbf);
            s3 += bf * ldIn(a.W_mlp,  (long)d*C_ + c, isbf);
        }
        if (lin == 0) {
            s2 += ldIn(a.b_unet, c, isbf);
            s3 += ldIn(a.b_mlp,  c, isbf);
        }
        atomicAdd(&a.c23[c], s2);
        atomicAdd(&a.c23[C_ + c], s3);
    } else {
        // W_rel -> WBt[c][k] bf16, c padded to 112; 64-k tiles
        int lin = blockIdx.y*48 + blockIdx.x;
        if (lin >= KTOT_/64) return;
        int k0 = lin * 64;
        for (int idx = tid; idx < 64*97; idx += 256) {
            int kk = idx / 97, c = idx % 97;
            sm.TW[c][kk] = f2bf(ldIn(a.W_rel, (long)(k0+kk)*C_ + c, isbf));
        }
        for (int idx = tid; idx < 15*64; idx += 256) {
            sm.TW[97 + (idx>>6)][idx & 63] = 0;
        }
        __syncthreads();
        for (int t = 0; t < 4; t++) {
            int idx = tid + t*256;      // < 896 = 112*8
            if (idx < 896) {
                int c = idx >> 3, kc = idx & 7;
                *(uint4*)(a.WBt + (long)c*KTOT_ + k0 + kc*8) = *(uint4*)&sm.TW[c][kc*8];
            }
        }
    }
}

// ---------------- gather: bx<768 entatt, else ment ----------------
__global__ void gather_kernel(const void* __restrict__ seq, const void* __restrict__ attn,
                              const int* __restrict__ entity_pos,
                              unsigned short* __restrict__ mentb, float* __restrict__ ent_emb,
                              float* __restrict__ ent_att, const int* __restrict__ dtf) {
    int isbf = dtf[0];
    if (blockIdx.x < 768) {
        int beh = blockIdx.x;
        int h = beh % H_;
        int be = beh / H_;
        int b = be >> 5;
        int pos[M_];
        for (int m = 0; m < M_; m++) pos[m] = entity_pos[be*M_+m] + 1;
        for (int l = threadIdx.x; l < L_; l += 256) {
            float s = 0.f;
            for (int m = 0; m < M_; m++)
                s += ldIn(attn, (((long)(b*H_ + h))*L_ + pos[m])*L_ + l, isbf);
            ent_att[(long)beh*L_ + l] = 0.25f * s;
        }
    } else {
        int be = blockIdx.x - 768;     // 0..63
        int b = be >> 5;
        int pos[M_];
        for (int m = 0; m < M_; m++) pos[m] = entity_pos[be*M_+m] + 1;
        for (int d = threadIdx.x; d < D_; d += 256) {
            float x[M_];
            for (int m = 0; m < M_; m++) {
                x[m] = ldIn(seq, ((long)b*L_ + pos[m])*D_ + d, isbf);
                mentb[((long)be*M_ + m)*D_ + d] = f2bf(x[m]);
            }
            float mx = fmaxf(fmaxf(x[0],x[1]), fmaxf(x[2],x[3]));
            float s = expf(x[0]-mx)+expf(x[1]-mx)+expf(x[2]-mx)+expf(x[3]-mx);
            ent_emb[(long)be*D_ + d] = mx + logf(s);
        }
    }
}

// ---------------- K3: ht_att (bf16) = normalize_L( mean_H(ha*ta) ) ----------------
__global__ void htatt_kernel(const float* __restrict__ ent_att, const int* __restrict__ hts,
                             unsigned short* __restrict__ htb) {
    int bp = blockIdx.x;            // 512 blocks
    int b = bp >> 8;
    int h_e = hts[bp*2+0], t_e = hts[bp*2+1];
    const float* ea_h = ent_att + (long)((b*E_ + h_e)*H_)*L_;
    const float* ea_t = ent_att + (long)((b*E_ + t_e)*H_)*L_;
    __shared__ float red[256];
    float v[2];
    for (int t = 0; t < 2; t++) {
        int l = threadIdx.x + t*256;
        float s = 0.f;
        for (int h = 0; h < H_; h++) s += ea_h[h*L_+l] * ea_t[h*L_+l];
        v[t] = s * (1.0f/H_);
    }
    red[threadIdx.x] = v[0] + v[1];
    __syncthreads();
    for (int off = 128; off > 0; off >>= 1) {
        if (threadIdx.x < off) red[threadIdx.x] += red[threadIdx.x+off];
        __syncthreads();
    }
    float inv = 1.0f / (red[0] + 1e-5f);
    for (int t = 0; t < 2; t++) {
        int l = threadIdx.x + t*256;
        htb[(long)bp*L_ + l] = f2bf(v[t] * inv);
    }
}

// ---------------- catb: hcatb=[hs,rs], tcatb=[ts,rs] in bf16 ----------------
__global__ void catb_kernel(const float* __restrict__ ent_emb, const float* __restrict__ rs,
                            const int* __restrict__ hts,
                            unsigned short* __restrict__ hcatb, unsigned short* __restrict__ tcatb) {
    int n = blockIdx.x;             // 512
    int b = n >> 8;
    int h_e = hts[n*2+0], t_e = hts[n*2+1];
    const float* eh = ent_emb + (long)(b*E_ + h_e)*D_;
    const float* et = ent_emb + (long)(b*E_ + t_e)*D_;
    const float* r  = rs + (long)n*D_;
    for (int k = threadIdx.x; k < D_; k += 256) {
        hcatb[(long)n*1536 + k] = f2bf(eh[k]);
        tcatb[(long)n*1536 + k] = f2bf(et[k]);
        unsigned short rb = f2bf(r[k]);
        hcatb[(long)n*1536 + 768 + k] = rb;
        tcatb[(long)n*1536 + 768 + k] = rb;
    }
}

// ---------------- Generic MFMA GEMM (double-buffered): per-z jobs ----------------
struct MfmaJob {
    const unsigned short* A[4];
    const unsigned short* Bt[4];
    const void* bias[4];
    void* C[4];
    int K[4];
    int ldc[4];
    int act[4];
    int obf[4];
};

__global__ void mfma_nt2_kernel(MfmaJob args, const int* __restrict__ dtf) {
    int z = blockIdx.z;
    const unsigned short* A  = args.A[z];
    const unsigned short* Bt = args.Bt[z];
    const void* bias = args.bias[z];
    void* C = args.C[z];
    int K = args.K[z], ldc = args.ldc[z], act = args.act[z], obf = args.obf[z];
    __shared__ unsigned short Al[2][64][72];
    __shared__ unsigned short Btl[2][64][72];
    int m0 = blockIdx.x*64, n0 = blockIdx.y*64;
    int tid = threadIdx.x, wave = tid>>6, lane = tid&63;
    int lm = lane&15, lq = lane>>4;
    int rr = tid >> 3;                // 0..31
    int kc = (tid & 7) * 8;           // col offset in ushorts
    uint4 ra0, ra1, rb0, rb1;

    ra0 = *(const uint4*)(A  + (long)(m0+rr)*K + kc);
    ra1 = *(const uint4*)(A  + (long)(m0+32+rr)*K + kc);
    rb0 = *(const uint4*)(Bt + (long)(n0+rr)*K + kc);
    rb1 = *(const uint4*)(Bt + (long)(n0+32+rr)*K + kc);
    *(uint4*)&Al[0][rr][kc]     = ra0;
    *(uint4*)&Al[0][32+rr][kc]  = ra1;
    *(uint4*)&Btl[0][rr][kc]    = rb0;
    *(uint4*)&Btl[0][32+rr][kc] = rb1;

    int nst = K >> 6;
    f32x4 acc[4] = {};
    for (int ks = 0; ks < nst; ks++) {
        __syncthreads();
        if (ks+1 < nst) {
            int k0 = (ks+1) << 6;
            ra0 = *(const uint4*)(A  + (long)(m0+rr)*K + k0 + kc);
            ra1 = *(const uint4*)(A  + (long)(m0+32+rr)*K + k0 + kc);
            rb0 = *(const uint4*)(Bt + (long)(n0+rr)*K + k0 + kc);
            rb1 = *(const uint4*)(Bt + (long)(n0+32+rr)*K + k0 + kc);
        }
        int cb = ks & 1;
        for (int half = 0; half < 2; half++) {
            bf16x8 af = *(bf16x8*)&Al[cb][wave*16+lm][half*32+lq*8];
            #pragma unroll
            for (int ct = 0; ct < 4; ct++) {
                bf16x8 bfr = *(bf16x8*)&Btl[cb][ct*16+lm][half*32+lq*8];
                acc[ct] = __builtin_amdgcn_mfma_f32_16x16x32_bf16(af, bfr, acc[ct], 0, 0, 0);
            }
        }
        if (ks+1 < nst) {
            int nb = (ks+1) & 1;
            *(uint4*)&Al[nb][rr][kc]     = ra0;
            *(uint4*)&Al[nb][32+rr][kc]  = ra1;
            *(uint4*)&Btl[nb][rr][kc]    = rb0;
            *(uint4*)&Btl[nb][32+rr][kc] = rb1;
        }
    }
    int isbf = dtf[0];
    for (int ct = 0; ct < 4; ct++) {
        int n = n0 + ct*16 + lm;
        float bia = bias ? ldIn(bias, n, isbf) : 0.f;
        for (int r = 0; r < 4; r++) {
            int m = m0 + wave*16 + lq*4 + r;
            float v = acc[ct][r] + bia;
            if (act == 1) v = tanhf(v);
            if (obf) ((unsigned short*)C)[(long)m*ldc + n] = f2bf(v);
            else     ((float*)C)[(long)m*ldc + n] = v;
        }
    }
}

// ================= r1 via MFMA, on-the-fly A, double-buffered B =================
// grid (KSPLIT_, 8): kz fastest -> all blocks sharing a kz slice land on one XCD
// partial layout: [n][kz][c]
__global__ void r1_mfma_kernel(const float* __restrict__ hz, const float* __restrict__ tz,
                               const unsigned short* __restrict__ WBt,
                               float* __restrict__ partial) {
    __shared__ float hzL[64][13];
    __shared__ unsigned short tzbL[64][136];
    __shared__ unsigned short Btl[2][CPAD_][72];
    int kz = blockIdx.x;
    int n0 = blockIdx.y * 64;
    int kbase = kz * KCHUNK_;
    int gi0 = kbase >> 6;
    int g0 = kbase >> 12;
    int g1 = min(g0 + 1, EMB_/64 - 1);
    int tid = threadIdx.x;
    int wave = tid >> 6, lane = tid & 63;
    int lm = lane & 15, lq = lane >> 4;

    for (int t = 0; t < 4; t++) {
        int id = tid + t*256;
        int n = id >> 4, q = id & 15;
        if (q < 12) hzL[n][q] = hz[(long)(n0+n)*EMB_ + gi0 + q];
    }
    for (int t = 0; t < 8; t++) {
        int id = tid + t*256;
        int n = id >> 5, c4 = (id & 31) * 4;
        int gcol = (c4 < 64) ? (g0*64 + c4) : (g1*64 + c4 - 64);
        float4 v = *(const float4*)(tz + (long)(n0+n)*EMB_ + gcol);
        unsigned short o[4] = {f2bf(v.x), f2bf(v.y), f2bf(v.z), f2bf(v.w)};
        *(uint2*)&tzbL[n][c4] = *(uint2*)o;
    }
    uint4 rb[4];
    #pragma unroll
    for (int t = 0; t < 4; t++) {
        int idx = tid + t*256;
        if (idx < 896) {
            int c = idx >> 3, k8 = (idx & 7)*8;
            rb[t] = *(const uint4*)(WBt + (long)c*KTOT_ + kbase + k8);
        }
    }
    #pragma unroll
    for (int t = 0; t < 4; t++) {
        int idx = tid + t*256;
        if (idx < 896) {
            int c = idx >> 3, k8 = (idx & 7)*8;
            *(uint4*)&Btl[0][c][k8] = rb[t];
        }
    }

    f32x4 acc[7] = {};
    for (int ks = 0; ks < KCHUNK_/64; ks++) {
        __syncthreads();
        if (ks+1 < KCHUNK_/64) {
            int k0 = kbase + (ks+1)*64;
            #pragma unroll
            for (int t = 0; t < 4; t++) {
                int idx = tid + t*256;
                if (idx < 896) {
                    int c = idx >> 3, k8 = (idx & 7)*8;
                    rb[t] = *(const uint4*)(WBt + (long)c*KTOT_ + k0 + k8);
                }
            }
        }
        int cb = ks & 1;
        int k0 = kbase + ks*64;
        int gsel = ((k0 >> 12) > g0) ? 64 : 0;
        float hv = hzL[wave*16 + lm][ks];
        for (int half = 0; half < 2; half++) {
            bf16x8 tzf = *(bf16x8*)&tzbL[wave*16 + lm][gsel + half*32 + lq*8];
            unsigned short o[8];
            #pragma unroll
            for (int e = 0; e < 8; e++)
                o[e] = f2bf(bf2f(((unsigned short*)&tzf)[e]) * hv);
            bf16x8 afrag = *(bf16x8*)o;
            #pragma unroll
            for (int ct = 0; ct < 7; ct++) {
                bf16x8 bfrag = *(bf16x8*)&Btl[cb][ct*16 + lm][half*32 + lq*8];
                acc[ct] = __builtin_amdgcn_mfma_f32_16x16x32_bf16(afrag, bfrag, acc[ct], 0, 0, 0);
            }
        }
        if (ks+1 < KCHUNK_/64) {
            int nb = (ks+1) & 1;
            #pragma unroll
            for (int t = 0; t < 4; t++) {
                int idx = tid + t*256;
                if (idx < 896) {
                    int c = idx >> 3, k8 = (idx & 7)*8;
                    *(uint4*)&Btl[nb][c][k8] = rb[t];
                }
            }
        }
    }
    for (int ct = 0; ct < 7; ct++) {
        int c = ct*16 + lm;
        for (int r = 0; r < 4; r++) {
            int nl = wave*16 + lq*4 + r;
            partial[((long)(n0+nl)*KSPLIT_ + kz)*CPAD_ + c] = acc[ct][r];
        }
    }
}

// ---------------- fused: r1 streaming reduce + r2/r3 LSE + final projection ----------------
__global__ void r23out_kernel(const float* __restrict__ partial, const void* __restrict__ b_rel,
                              const float* __restrict__ mu, const float* __restrict__ c23,
                              const int* __restrict__ hts, const int* __restrict__ mention_idx,
                              const float* __restrict__ W_bilF, const void* __restrict__ b_bil,
                              void* __restrict__ out, const int* __restrict__ dtf) {
    int bp = blockIdx.x;
    int b = bp >> 8;
    int c = threadIdx.x;
    int isbf = dtf[0];
    __shared__ float row[292];
    if (c < C_) {
        const float* pr = partial + (long)bp*KSPLIT_*CPAD_;
        float r1v = 0.f;
        #pragma unroll 8
        for (int kz = 0; kz < KSPLIT_; kz++)
            r1v += pr[kz*CPAD_ + c];
        r1v += ldIn(b_rel, c, isbf);
        int h_e = hts[bp*2+0], t_e = hts[bp*2+1];
        const float* mu2h = mu;
        const float* mu2t = mu + 32768;
        const float* mu3h = mu + 65536;
        const float* mu3t = mu + 98304;
        float ah2[4], at2[4], ah3[4], at3[4];
        for (int m = 0; m < 4; m++) {
            int emh = mention_idx[(b*E_ + h_e)*M_ + m];
            int emt = mention_idx[(b*E_ + t_e)*M_ + m];
            ah2[m] = mu2h[(long)(b*128 + emh)*128 + c];
            ah3[m] = mu3h[(long)(b*128 + emh)*128 + c];
            at2[m] = mu2t[(long)(b*128 + emt)*128 + c];
            at3[m] = mu3t[(long)(b*128 + emt)*128 + c];
        }
        float c2 = c23[c], c3 = c23[C_ + c];
        float v2[16], v3[16];
        int q = 0;
        for (int i = 0; i < 4; i++) {
            for (int j = 0; j < 4; j++, q++) {
                float x2 = ah2[i] + at2[j] + c2;
                v2[q] = tanhf(x2);
                float x3 = ah3[i] + at3[j] + c3;
                float t = tanhf(0.7978845608028654f * (x3 + 0.044715f*x3*x3*x3));
                v3[q] = 0.5f * x3 * (1.0f + t);
            }
        }
        float m2 = v2[0], m3 = v3[0];
        for (q = 1; q < 16; q++) { m2 = fmaxf(m2, v2[q]); m3 = fmaxf(m3, v3[q]); }
        float s2 = 0.f, s3 = 0.f;
        for (q = 0; q < 16; q++) { s2 += expf(v2[q]-m2); s3 += expf(v3[q]-m3); }
        row[c]        = r1v;
        row[C_ + c]   = m2 + logf(s2);
        row[2*C_ + c] = m3 + logf(s3);
    }
    __syncthreads();
    if (c >= C_) return;
    float a0 = 0.f, a1 = 0.f, a2 = 0.f, a3 = 0.f;
    #pragma unroll 4
    for (int k = 0; k < 288; k += 4) {
        a0 += row[k+0] * W_bilF[(k+0)*C_ + c];
        a1 += row[k+1] * W_bilF[(k+1)*C_ + c];
        a2 += row[k+2] * W_bilF[(k+2)*C_ + c];
        a3 += row[k+3] * W_bilF[(k+3)*C_ + c];
    }
    a0 += row[288] * W_bilF[288*C_ + c];
    a1 += row[289] * W_bilF[289*C_ + c];
    a2 += row[290] * W_bilF[290*C_ + c];
    float v = a0 + a1 + a2 + a3 + ldIn(b_bil, c, isbf);
    if (isbf) ((bf16*)out)[(long)bp*C_ + c] = (bf16)v;
    else      ((float*)out)[(long)bp*C_ + c] = v;
}

extern "C" void kernel_launch(void* const* d_in, const int* in_sizes, int n_in,
                              void* d_out, int out_size, void* d_ws, size_t ws_size,
                              hipStream_t stream) {
    const void* seq        = d_in[0];
    const void* attn       = d_in[1];
    const int*  entity_pos = (const int*)d_in[2];
    const int*  hts        = (const int*)d_in[3];
    const int*  mention_idx= (const int*)d_in[4];
    const void* W_head     = d_in[5];
    const void* b_head     = d_in[6];
    const void* W_tail     = d_in[7];
    const void* b_tail     = d_in[8];
    const void* W_rel      = d_in[9];
    const void* b_rel      = d_in[10];
    const void* W_fh       = d_in[11];
    const void* W_ft       = d_in[12];
    const void* b_f        = d_in[13];
    const void* W_unet     = d_in[14];
    const void* b_unet     = d_in[15];
    const void* W_mlp      = d_in[16];
    const void* b_mlp      = d_in[17];
    const void* W_bil      = d_in[18];
    const void* b_bil      = d_in[19];

    float* w = (float*)d_ws;
    int*   dtf      = (int*)w;                               // 64
    unsigned short* mentb = (unsigned short*)(w + 64);       // 98304 fl
    float* ent_emb  = w + 98368;                             // 49152
    float* ent_att  = w + 147520;                            // 393216
    unsigned short* htb = (unsigned short*)(w + 540736);     // 131072 fl
    float* rs       = w + 671808;                            // 393216
    float* hz       = w + 1065024;                           // 393216
    float* tz       = w + 1458240;                           // 393216
    float* mu       = w + 1851456;                           // 131072
    float* c23      = w + 1982528;                           // 256
    unsigned short* seqT  = (unsigned short*)(w + 1982784);  // 393216 fl
    unsigned short* WhT   = (unsigned short*)(w + 2376000);  // 589824 fl
    unsigned short* WtT   = (unsigned short*)(w + 2965824);  // 589824 fl
    unsigned short* WfhT  = (unsigned short*)(w + 3555648);  // 294912 fl
    unsigned short* WftT  = (unsigned short*)(w + 3850560);  // 294912 fl
    unsigned short* WunetT= (unsigned short*)(w + 4145472);  // 49152 fl
    unsigned short* WmlpT = (unsigned short*)(w + 4194624);  // 49152 fl
    unsigned short* Tbh   = (unsigned short*)(w + 4243776);  // 98304 fl
    unsigned short* Tbt   = (unsigned short*)(w + 4342080);  // 98304 fl
    unsigned short* hcatb = (unsigned short*)(w + 4440384);  // 393216 fl
    unsigned short* tcatb = (unsigned short*)(w + 4833600);  // 393216 fl
    unsigned short* WBt   = (unsigned short*)(w + 5226816);  // 2752512 fl
    float* partial  = w + 7979328;                           // 3670016 fl
    float* W_bilF   = w + 11649344;                          // 28227 fl

    // 0. dtype detection + c23 init
    dtype_detect<<<1, 256, 0, stream>>>(seq, dtf, c23);
    // 1. prep: transposes + W_bilF + c23 + W_rel conv
    {
        PrepArgs a = {};
        const void* srcs[8] = {W_head, W_tail, W_fh, W_ft, W_unet, W_mlp, seq, seq};
        long offs[8]   = {0,0,0,0,0,0,0,393216};
        int Ks[8]      = {1536,1536,768,768,768,768,512,512};
        int Ncols8[8]  = {768,768,768,768,97,97,768,768};
        int Npads[8]   = {768,768,768,768,128,128,768,768};
        unsigned short* dsts[8] = {WhT, WtT, WfhT, WftT, WunetT, WmlpT, seqT, seqT+393216};
        for (int z = 0; z < 8; z++) {
            a.src[z]=srcs[z]; a.off[z]=offs[z]; a.K[z]=Ks[z];
            a.Ncols[z]=Ncols8[z]; a.Npad[z]=Npads[z]; a.dst[z]=dsts[z];
        }
        a.W_bil = W_bil; a.W_bilF = W_bilF;
        a.b_f = b_f; a.W_unet = W_unet; a.b_unet = b_unet;
        a.W_mlp = W_mlp; a.b_mlp = b_mlp; a.c23 = c23;
        a.W_rel = W_rel; a.WBt = WBt;
        prep_kernel<<<dim3(48, 16, 11), 256, 0, stream>>>(a, dtf);
    }
    // 2. gather: entatt + ment
    gather_kernel<<<768 + 64, 256, 0, stream>>>(seq, attn, entity_pos, mentb, ent_emb, ent_att, dtf);
    // 3. ht attention (normalized, bf16)
    htatt_kernel<<<N_, 256, 0, stream>>>(ent_att, hts, htb);
    // 4. gemmA: rs (z=0,1) + T_{h,t} (z=2,3)
    {
        MfmaJob ga = {};
        for (int z = 0; z < 2; z++) {
            ga.A[z] = htb + (long)z*256*512; ga.Bt[z] = seqT + (long)z*393216;
            ga.bias[z] = nullptr; ga.C[z] = rs + (long)z*256*768;
            ga.K[z] = 512; ga.ldc[z] = 768; ga.act[z] = 0; ga.obf[z] = 0;
        }
        ga.A[2] = mentb; ga.Bt[2] = WfhT; ga.bias[2] = nullptr; ga.C[2] = Tbh;
        ga.K[2] = 768; ga.ldc[2] = 768; ga.act[2] = 0; ga.obf[2] = 1;
        ga.A[3] = mentb; ga.Bt[3] = WftT; ga.bias[3] = nullptr; ga.C[3] = Tbt;
        ga.K[3] = 768; ga.ldc[3] = 768; ga.act[3] = 0; ga.obf[3] = 1;
        mfma_nt2_kernel<<<dim3(4, 12, 4), 256, 0, stream>>>(ga, dtf);
    }
    // 5. concatenated inputs (bf16)
    catb_kernel<<<N_, 256, 0, stream>>>(ent_emb, rs, hts, hcatb, tcatb);
    // 6. gemmB: hz/tz = tanh(cat @ W + b)
    {
        MfmaJob ga = {};
        ga.A[0] = hcatb; ga.Bt[0] = WhT; ga.bias[0] = b_head; ga.C[0] = hz;
        ga.A[1] = tcatb; ga.Bt[1] = WtT; ga.bias[1] = b_tail; ga.C[1] = tz;
        for (int z = 0; z < 2; z++) { ga.K[z] = 1536; ga.ldc[z] = 768; ga.act[z] = 1; ga.obf[z] = 0; }
        mfma_nt2_kernel<<<dim3(8, 12, 2), 256, 0, stream>>>(ga, dtf);
    }
    // 7. gemmC: mu_q = T @ W_{unet,mlp}
    {
        MfmaJob ga = {};
        const unsigned short* As[4] = {Tbh, Tbt, Tbh, Tbt};
        const unsigned short* Bs[4] = {WunetT, WunetT, WmlpT, WmlpT};
        for (int q = 0; q < 4; q++) {
            ga.A[q] = As[q]; ga.Bt[q] = Bs[q]; ga.bias[q] = nullptr;
            ga.C[q] = mu + q*32768;
            ga.K[q] = 768; ga.ldc[q] = 128; ga.act[q] = 0; ga.obf[q] = 0;
        }
        mfma_nt2_kernel<<<dim3(4, 2, 4), 256, 0, stream>>>(ga, dtf);
    }
    // 8. r1 partials via MFMA (kz-fastest grid for XCD slice affinity)
    r1_mfma_kernel<<<dim3(KSPLIT_, 8), 256, 0, stream>>>(hz, tz, WBt, partial);
    // 9. fused reduce + r2/r3 + final projection
    r23out_kernel<<<N_, 128, 0, stream>>>(partial, b_rel, mu, c23, hts, mention_idx,
                                          W_bilF, b_bil, d_out, dtf);
}